// Round 3
// baseline (1663.369 us; speedup 1.0000x reference)
//
#include <hip/hip_runtime.h>

typedef unsigned short u16;
typedef u16 u16x8 __attribute__((ext_vector_type(8)));
typedef __bf16 bf16x8 __attribute__((ext_vector_type(8)));
typedef float f32x4 __attribute__((ext_vector_type(4)));

__device__ __forceinline__ float bf2f(u16 v) {
  unsigned u = ((unsigned)v) << 16;
  return __builtin_bit_cast(float, u);
}
__device__ __forceinline__ u16 f2bf(float f) {
  unsigned u = __builtin_bit_cast(unsigned, f);
  u += 0x7FFFu + ((u >> 16) & 1u);
  return (u16)(u >> 16);
}
__device__ __forceinline__ float hsw(float v) {
  return v * fminf(fmaxf(v + 3.f, 0.f), 6.f) * (1.f / 6.f);
}
__device__ __forceinline__ f32x4 mfma16(u16x8 a, u16x8 b, f32x4 c) {
  return __builtin_amdgcn_mfma_f32_16x16x32_bf16(
      __builtin_bit_cast(bf16x8, a), __builtin_bit_cast(bf16x8, b), c, 0, 0, 0);
}

#define LR 40  // padded LDS row stride in u16 (80 B), breaks pow2 bank stride

// ---------------------------------------------------------------------------
// K0: feature NCHW fp32 -> NHWC bf16 hi + lo planes
// ---------------------------------------------------------------------------
__global__ __launch_bounds__(256) void k_tobf(const float* __restrict__ f,
                                              u16* __restrict__ fbh,
                                              u16* __restrict__ fbl) {
  __shared__ float tl[64 * 65];
  const int t = threadIdx.x;
  const int bid = blockIdx.x;
  const int ict = bid & 7, xt = (bid >> 3) & 1, y = (bid >> 4) & 127, n = bid >> 11;
  const int x0 = xt * 64, ic0 = ict * 64;
#pragma unroll
  for (int i = 0; i < 16; ++i) {
    const int e = t + i * 256;
    const int icl = e >> 6, xl = e & 63;
    tl[icl * 65 + xl] = f[((n * 512 + ic0 + icl) * 128 + y) * 128 + x0 + xl];
  }
  __syncthreads();
#pragma unroll
  for (int i = 0; i < 16; ++i) {
    const int e = t + i * 256;
    const int xl = e >> 6, icl = e & 63;
    const float v = tl[icl * 65 + xl];
    const u16 h = f2bf(v);
    const size_t idx = ((size_t)((n * 128 + y) * 128 + x0 + xl) << 9) + ic0 + icl;
    fbh[idx] = h;
    fbl[idx] = f2bf(v - bf2f(h));
  }
}

// ---------------------------------------------------------------------------
// Weight prepacks: [tap][icc][oc][ic32] bf16 hi/lo
// ---------------------------------------------------------------------------
__global__ __launch_bounds__(256) void k_pack1(const float* __restrict__ w,
                                               u16* __restrict__ bph,
                                               u16* __restrict__ bpl) {
  const int e = blockIdx.x * 256 + threadIdx.x;  // < 9*16*192*32
  const int ici = e & 31;
  const int rest = e >> 5;
  const int oc = rest % 192;
  const int kc = rest / 192;
  const int icc = kc & 15, tap = kc >> 4;
  const int ic = icc * 32 + ici;
  const float v = w[(oc * 512 + ic) * 9 + tap];
  const u16 h = f2bf(v);
  bph[e] = h;
  bpl[e] = f2bf(v - bf2f(h));
}

__global__ __launch_bounds__(256) void k_pack2(const float* __restrict__ w,
                                               u16* __restrict__ bph,
                                               u16* __restrict__ bpl) {
  const int e = blockIdx.x * 256 + threadIdx.x;  // < 9*6*192*32
  const int ici = e & 31;
  const int rest = e >> 5;
  const int oc = rest % 192;
  const int kc = rest / 192;
  const int icc = kc % 6, tap = kc / 6;
  const int ic = icc * 32 + ici;
  const float v = w[(oc * 192 + ic) * 9 + tap];
  const u16 h = f2bf(v);
  bph[e] = h;
  bpl[e] = f2bf(v - bf2f(h));
}

__global__ __launch_bounds__(256) void k_pack5(const float* __restrict__ rgw,
                                               const float* __restrict__ hmw,
                                               u16* __restrict__ bph,
                                               u16* __restrict__ bpl) {
  const int e = blockIdx.x * 256 + threadIdx.x;  // < 9*16*48*32
  const int ici = e & 31;
  const int rest = e >> 5;
  const int oc = rest % 48;
  const int sic = rest / 48;
  const int icc = sic & 15, slot = sic >> 4;
  const int ic = icc * 32 + ici;
  const int kytab[9] = {1, 1, 1, 2, 0, 2, 2, 0, 0};
  const int kxtab[9] = {1, 2, 0, 1, 1, 2, 0, 2, 0};
  const int ky = kytab[slot], kx = kxtab[slot];
  float v = 0.f;
  if (oc < 32)
    v = rgw[((ic * 32 + oc) * 3 + ky) * 3 + kx];
  else if (oc < 40)
    v = hmw[((ic * 8 + (oc - 32)) * 3 + ky) * 3 + kx];
  const u16 h = f2bf(v);
  bph[e] = h;
  bpl[e] = f2bf(v - bf2f(h));
}

// ---------------------------------------------------------------------------
// K1: conv1 3x3 s2 p1, 512->192, split-bf16 (3x MFMA). y1 fp32 NHWC.
// ---------------------------------------------------------------------------
__global__ __launch_bounds__(256) void k_conv1(const u16* __restrict__ fbh,
                                               const u16* __restrict__ fbl,
                                               const u16* __restrict__ bph,
                                               const u16* __restrict__ bpl,
                                               const float* __restrict__ bias,
                                               float* __restrict__ y1) {
  __shared__ u16 AlH[64 * LR], AlL[64 * LR];
  __shared__ u16 BlH[192 * LR], BlL[192 * LR];
  __shared__ float bl[192];
  const int t = threadIdx.x;
  const int n = blockIdx.x >> 6, oy = blockIdx.x & 63;
  if (t < 192) bl[t] = bias[t];
  const int lane = t & 63, wv = t >> 6;
  const int row = lane & 15, g = lane >> 4;
  const int oxs = t >> 2, icq = t & 3;
  const f32x4 z4 = {0.f, 0.f, 0.f, 0.f};
  f32x4 acc[4][3];
#pragma unroll
  for (int i = 0; i < 4; ++i)
#pragma unroll
    for (int j = 0; j < 3; ++j) acc[i][j] = z4;

  for (int kc = 0; kc < 144; ++kc) {
    const int tap = kc >> 4, icc = kc & 15;
    const int ky = tap / 3, kx = tap - ky * 3;
    const int iy = 2 * oy - 1 + ky;
    const int ix = 2 * oxs - 1 + kx;
    u16x8 avh = {0, 0, 0, 0, 0, 0, 0, 0};
    u16x8 avl = {0, 0, 0, 0, 0, 0, 0, 0};
    if ((unsigned)iy < 128u && (unsigned)ix < 128u) {
      const size_t idx =
          ((size_t)((n * 128 + iy) * 128 + ix) << 9) + icc * 32 + icq * 8;
      avh = *(const u16x8*)&fbh[idx];
      avl = *(const u16x8*)&fbl[idx];
    }
    u16x8 bvh[3], bvl[3];
    const size_t bbase = (size_t)(tap * 16 + icc) * (192 * 32);
#pragma unroll
    for (int i = 0; i < 3; ++i) {
      const int e = t + i * 256;
      const size_t off = bbase + (e >> 2) * 32 + (e & 3) * 8;
      bvh[i] = *(const u16x8*)&bph[off];
      bvl[i] = *(const u16x8*)&bpl[off];
    }
    __syncthreads();
    *(u16x8*)&AlH[oxs * LR + icq * 8] = avh;
    *(u16x8*)&AlL[oxs * LR + icq * 8] = avl;
#pragma unroll
    for (int i = 0; i < 3; ++i) {
      const int e = t + i * 256;
      *(u16x8*)&BlH[(e >> 2) * LR + (e & 3) * 8] = bvh[i];
      *(u16x8*)&BlL[(e >> 2) * LR + (e & 3) * 8] = bvl[i];
    }
    __syncthreads();
    u16x8 afh[4], afl[4], bfh[3], bfl[3];
#pragma unroll
    for (int mf = 0; mf < 4; ++mf) {
      afh[mf] = *(const u16x8*)&AlH[(mf * 16 + row) * LR + g * 8];
      afl[mf] = *(const u16x8*)&AlL[(mf * 16 + row) * LR + g * 8];
    }
#pragma unroll
    for (int nf = 0; nf < 3; ++nf) {
      bfh[nf] = *(const u16x8*)&BlH[(wv * 48 + nf * 16 + row) * LR + g * 8];
      bfl[nf] = *(const u16x8*)&BlL[(wv * 48 + nf * 16 + row) * LR + g * 8];
    }
#pragma unroll
    for (int mf = 0; mf < 4; ++mf)
#pragma unroll
      for (int nf = 0; nf < 3; ++nf) {
        acc[mf][nf] = mfma16(afh[mf], bfh[nf], acc[mf][nf]);
        acc[mf][nf] = mfma16(afh[mf], bfl[nf], acc[mf][nf]);
        acc[mf][nf] = mfma16(afl[mf], bfh[nf], acc[mf][nf]);
      }
  }
#pragma unroll
  for (int mf = 0; mf < 4; ++mf)
#pragma unroll
    for (int nf = 0; nf < 3; ++nf)
#pragma unroll
      for (int r = 0; r < 4; ++r) {
        const int m = mf * 16 + g * 4 + r;
        const int oc = wv * 48 + nf * 16 + row;
        y1[((n * 64 + oy) * 64 + m) * 192 + oc] = acc[mf][nf][r] + bl[oc];
      }
}

// ---------------------------------------------------------------------------
// K2: conv2 3x3 s2 p1, 192->192 on bn1(y1 fp32), split-bf16. y2 fp32 NHWC.
// ---------------------------------------------------------------------------
__global__ __launch_bounds__(256) void k_conv2(const float* __restrict__ y1,
                                               const u16* __restrict__ bph,
                                               const u16* __restrict__ bpl,
                                               const float* __restrict__ bias,
                                               const float* __restrict__ sc,
                                               const float* __restrict__ sh,
                                               float* __restrict__ y2) {
  __shared__ u16 AlH[64 * LR], AlL[64 * LR];
  __shared__ u16 BlH[192 * LR], BlL[192 * LR];
  __shared__ float bl[192], scl[192], shl[192];
  const int t = threadIdx.x;
  const int n = blockIdx.x >> 4, oyp = blockIdx.x & 15;
  if (t < 192) {
    bl[t] = bias[t];
    scl[t] = sc[t];
    shl[t] = sh[t];
  }
  __syncthreads();
  const int lane = t & 63, wv = t >> 6;
  const int row = lane & 15, g = lane >> 4;
  const int ms = t >> 2, icq = t & 3;
  const int ryr = ms >> 5, oxs = ms & 31;
  const f32x4 z4 = {0.f, 0.f, 0.f, 0.f};
  f32x4 acc[4][3];
#pragma unroll
  for (int i = 0; i < 4; ++i)
#pragma unroll
    for (int j = 0; j < 3; ++j) acc[i][j] = z4;

  for (int kc = 0; kc < 54; ++kc) {
    const int tap = kc / 6, icc = kc - tap * 6;
    const int ky = tap / 3, kx = tap - ky * 3;
    const int iy = 2 * (oyp * 2 + ryr) - 1 + ky;
    const int ix = 2 * oxs - 1 + kx;
    u16x8 avh = {0, 0, 0, 0, 0, 0, 0, 0};
    u16x8 avl = {0, 0, 0, 0, 0, 0, 0, 0};
    if ((unsigned)iy < 64u && (unsigned)ix < 64u) {
      const int icb = icc * 32 + icq * 8;
      const float* base = &y1[((n * 64 + iy) * 64 + ix) * 192 + icb];
      const f32x4 r0 = *(const f32x4*)base;
      const f32x4 r1 = *(const f32x4*)(base + 4);
#pragma unroll
      for (int j = 0; j < 8; ++j) {
        const float r = (j < 4) ? r0[j & 3] : r1[j & 3];
        const float v = r * scl[icb + j] + shl[icb + j];
        const u16 h = f2bf(v);
        avh[j] = h;
        avl[j] = f2bf(v - bf2f(h));
      }
    }
    u16x8 bvh[3], bvl[3];
    const size_t bbase = (size_t)(tap * 6 + icc) * (192 * 32);
#pragma unroll
    for (int i = 0; i < 3; ++i) {
      const int e = t + i * 256;
      const size_t off = bbase + (e >> 2) * 32 + (e & 3) * 8;
      bvh[i] = *(const u16x8*)&bph[off];
      bvl[i] = *(const u16x8*)&bpl[off];
    }
    __syncthreads();
    *(u16x8*)&AlH[ms * LR + icq * 8] = avh;
    *(u16x8*)&AlL[ms * LR + icq * 8] = avl;
#pragma unroll
    for (int i = 0; i < 3; ++i) {
      const int e = t + i * 256;
      *(u16x8*)&BlH[(e >> 2) * LR + (e & 3) * 8] = bvh[i];
      *(u16x8*)&BlL[(e >> 2) * LR + (e & 3) * 8] = bvl[i];
    }
    __syncthreads();
    u16x8 afh[4], afl[4], bfh[3], bfl[3];
#pragma unroll
    for (int mf = 0; mf < 4; ++mf) {
      afh[mf] = *(const u16x8*)&AlH[(mf * 16 + row) * LR + g * 8];
      afl[mf] = *(const u16x8*)&AlL[(mf * 16 + row) * LR + g * 8];
    }
#pragma unroll
    for (int nf = 0; nf < 3; ++nf) {
      bfh[nf] = *(const u16x8*)&BlH[(wv * 48 + nf * 16 + row) * LR + g * 8];
      bfl[nf] = *(const u16x8*)&BlL[(wv * 48 + nf * 16 + row) * LR + g * 8];
    }
#pragma unroll
    for (int mf = 0; mf < 4; ++mf)
#pragma unroll
      for (int nf = 0; nf < 3; ++nf) {
        acc[mf][nf] = mfma16(afh[mf], bfh[nf], acc[mf][nf]);
        acc[mf][nf] = mfma16(afh[mf], bfl[nf], acc[mf][nf]);
        acc[mf][nf] = mfma16(afl[mf], bfh[nf], acc[mf][nf]);
      }
  }
#pragma unroll
  for (int mf = 0; mf < 4; ++mf)
#pragma unroll
    for (int nf = 0; nf < 3; ++nf)
#pragma unroll
      for (int r = 0; r < 4; ++r) {
        const int m = mf * 16 + g * 4 + r;
        const int oy = oyp * 2 + (m >> 5), ox = m & 31;
        const int oc = wv * 48 + nf * 16 + row;
        y2[((n * 32 + oy) * 32 + ox) * 192 + oc] = acc[mf][nf][r] + bl[oc];
      }
}

// ---------------------------------------------------------------------------
// K5: fused ConvT (rg 512->32 single-bf16 + hm 512->8 split-bf16)
// ---------------------------------------------------------------------------
__global__ __launch_bounds__(256) void k_convt(const u16* __restrict__ fbh,
                                               const u16* __restrict__ fbl,
                                               const u16* __restrict__ bph,
                                               const u16* __restrict__ bpl,
                                               const float* __restrict__ rgb,
                                               const float* __restrict__ hmb,
                                               u16* __restrict__ rr,
                                               float* __restrict__ hm) {
  __shared__ u16 AlH[128 * LR], AlL[128 * LR];
  __shared__ u16 BlH[48 * LR], BlL[48 * LR];
  __shared__ float bl[48];
  const int t = threadIdx.x;
  const int n = blockIdx.x >> 9;
  const int oy = (blockIdx.x >> 1) & 255;
  const int xp = blockIdx.x & 1;
  if (t < 48) bl[t] = (t < 32) ? rgb[t] : ((t < 40) ? hmb[t - 32] : 0.f);
  const int cls = ((oy & 1) << 1) | xp;
  const int base_tab[4] = {0, 1, 3, 5};
  const int ntap_tab[4] = {1, 2, 2, 4};
  const int ntap = ntap_tab[cls];
  const int sbase = base_tab[cls];
  const int iyb = oy >> 1;
  const int lane = t & 63, wv = t >> 6;
  const int row = lane & 15, g = lane >> 4;
  const int ms = t >> 2, icq = t & 3;
  const f32x4 z4 = {0.f, 0.f, 0.f, 0.f};
  f32x4 acc[2][3];
#pragma unroll
  for (int i = 0; i < 2; ++i)
#pragma unroll
    for (int j = 0; j < 3; ++j) acc[i][j] = z4;

  const int nkc = ntap * 16;
  for (int kc = 0; kc < nkc; ++kc) {
    const int tp = kc >> 4, icc = kc & 15;
    int diy, dix;
    if (cls == 0) { diy = 0; dix = 0; }
    else if (cls == 1) { diy = 0; dix = tp; }
    else if (cls == 2) { diy = tp; dix = 0; }
    else { diy = tp >> 1; dix = tp & 1; }
    const int slot = sbase + tp;
    const int iy = iyb + diy;
    const bool yok = iy < 128;
    u16x8 avh[2], avl[2];
#pragma unroll
    for (int i = 0; i < 2; ++i) {
      const int m = ms + i * 64;
      const int ix = m + dix;
      u16x8 vh = {0, 0, 0, 0, 0, 0, 0, 0};
      u16x8 vl = {0, 0, 0, 0, 0, 0, 0, 0};
      if (yok && ix < 128) {
        const size_t idx =
            ((size_t)((n * 128 + iy) * 128 + ix) << 9) + icc * 32 + icq * 8;
        vh = *(const u16x8*)&fbh[idx];
        vl = *(const u16x8*)&fbl[idx];
      }
      avh[i] = vh;
      avl[i] = vl;
    }
    u16x8 bvh = {0, 0, 0, 0, 0, 0, 0, 0};
    u16x8 bvl = {0, 0, 0, 0, 0, 0, 0, 0};
    if (t < 192) {
      const size_t off = (((size_t)(slot * 16 + icc) * 48 + (t >> 2)) << 5) + (t & 3) * 8;
      bvh = *(const u16x8*)&bph[off];
      bvl = *(const u16x8*)&bpl[off];
    }
    __syncthreads();
#pragma unroll
    for (int i = 0; i < 2; ++i) {
      *(u16x8*)&AlH[(ms + i * 64) * LR + icq * 8] = avh[i];
      *(u16x8*)&AlL[(ms + i * 64) * LR + icq * 8] = avl[i];
    }
    if (t < 192) {
      *(u16x8*)&BlH[(t >> 2) * LR + (t & 3) * 8] = bvh;
      *(u16x8*)&BlL[(t >> 2) * LR + (t & 3) * 8] = bvl;
    }
    __syncthreads();
    u16x8 afh[2], afl[2], bfh[3], bfl2;
#pragma unroll
    for (int mf = 0; mf < 2; ++mf) {
      afh[mf] = *(const u16x8*)&AlH[(wv * 32 + mf * 16 + row) * LR + g * 8];
      afl[mf] = *(const u16x8*)&AlL[(wv * 32 + mf * 16 + row) * LR + g * 8];
    }
#pragma unroll
    for (int nf = 0; nf < 3; ++nf)
      bfh[nf] = *(const u16x8*)&BlH[(nf * 16 + row) * LR + g * 8];
    bfl2 = *(const u16x8*)&BlL[(2 * 16 + row) * LR + g * 8];
#pragma unroll
    for (int mf = 0; mf < 2; ++mf) {
      acc[mf][0] = mfma16(afh[mf], bfh[0], acc[mf][0]);
      acc[mf][1] = mfma16(afh[mf], bfh[1], acc[mf][1]);
      acc[mf][2] = mfma16(afh[mf], bfh[2], acc[mf][2]);
      acc[mf][2] = mfma16(afh[mf], bfl2, acc[mf][2]);
      acc[mf][2] = mfma16(afl[mf], bfh[2], acc[mf][2]);
    }
  }
#pragma unroll
  for (int mf = 0; mf < 2; ++mf)
#pragma unroll
    for (int nf = 0; nf < 3; ++nf)
#pragma unroll
      for (int r = 0; r < 4; ++r) {
        const int m = wv * 32 + mf * 16 + g * 4 + r;
        const int ox = xp + 2 * m;
        const int oc = nf * 16 + row;
        const float v = acc[mf][nf][r] + bl[oc];
        if (oc < 32)
          rr[((n * 256 + oy) * 256 + ox) * 32 + oc] = f2bf(v);
        else if (oc < 40)
          hm[(n * 8 + (oc - 32)) * 65536 + oy * 256 + ox] = v;
      }
}

// ---------------------------------------------------------------------------
// Generic per-channel sum/sumsq over [M][C] (C = CG*32)
// ---------------------------------------------------------------------------
template <int CG, bool BF16>
__global__ __launch_bounds__(256) void k_stats(const void* __restrict__ in_, int M,
                                               int PB, float* __restrict__ gsum,
                                               float* __restrict__ gsq) {
  const int C = CG * 32;
  __shared__ float red[8][CG * 32];
  const int t = threadIdx.x;
  const int pg = t >> 5, ln = t & 31;
  float s[CG], q[CG];
#pragma unroll
  for (int c = 0; c < CG; ++c) { s[c] = 0.f; q[c] = 0.f; }
  const int p0 = blockIdx.x * PB;
  const int pend = min(p0 + PB, M);
  for (int p = p0 + pg; p < pend; p += 8) {
#pragma unroll
    for (int c = 0; c < CG; ++c) {
      float v;
      if (BF16)
        v = bf2f(((const u16*)in_)[(size_t)p * C + c * 32 + ln]);
      else
        v = ((const float*)in_)[(size_t)p * C + c * 32 + ln];
      s[c] += v;
      q[c] += v * v;
    }
  }
#pragma unroll
  for (int c = 0; c < CG; ++c) red[pg][c * 32 + ln] = s[c];
  __syncthreads();
  if (t < C) {
    float tot = 0.f;
#pragma unroll
    for (int k = 0; k < 8; ++k) tot += red[k][t];
    atomicAdd(&gsum[t], tot);
  }
  __syncthreads();
#pragma unroll
  for (int c = 0; c < CG; ++c) red[pg][c * 32 + ln] = q[c];
  __syncthreads();
  if (t < C) {
    float tot = 0.f;
#pragma unroll
    for (int k = 0; k < 8; ++k) tot += red[k][t];
    atomicAdd(&gsq[t], tot);
  }
}

__global__ void k_bnfin(const float* __restrict__ gsum, const float* __restrict__ gsq,
                        const float* __restrict__ g, const float* __restrict__ be,
                        float invM, int C, float* __restrict__ sc,
                        float* __restrict__ sh) {
  const int t = threadIdx.x;
  if (t < C) {
    const float m = gsum[t] * invM;
    const float var = gsq[t] * invM - m * m;
    const float inv = rsqrtf(var + 1e-5f);
    const float s = g[t] * inv;
    sc[t] = s;
    sh[t] = be[t] - m * s;
  }
}

// ---------------------------------------------------------------------------
// K3: conv3 1x1 192->32 on bn(y2 fp32). y3 fp32 [8192][32].
// ---------------------------------------------------------------------------
__global__ __launch_bounds__(256) void k_conv3(const float* __restrict__ y2,
                                               const float* __restrict__ w3,
                                               const float* __restrict__ b3,
                                               const float* __restrict__ sc,
                                               const float* __restrict__ sh,
                                               float* __restrict__ y3) {
  __shared__ float wl[32 * 192];
  __shared__ float scl[192], shl[192];
  const int t = threadIdx.x;
  for (int e = t; e < 6144; e += 256) wl[e] = w3[e];
  if (t < 192) {
    scl[t] = sc[t];
    shl[t] = sh[t];
  }
  __syncthreads();
  const int px = blockIdx.x * 256 + t;
  float acc[32];
#pragma unroll
  for (int oc = 0; oc < 32; ++oc) acc[oc] = 0.f;
  const float* base = &y2[(size_t)px * 192];
  for (int icb = 0; icb < 192; icb += 8) {
    const f32x4 r0 = *(const f32x4*)&base[icb];
    const f32x4 r1 = *(const f32x4*)&base[icb + 4];
    float v[8];
#pragma unroll
    for (int j = 0; j < 8; ++j) {
      const float r = (j < 4) ? r0[j & 3] : r1[j & 3];
      v[j] = r * scl[icb + j] + shl[icb + j];
    }
#pragma unroll
    for (int oc = 0; oc < 32; ++oc) {
      const f32x4 w0 = *(const f32x4*)&wl[oc * 192 + icb];
      const f32x4 w1 = *(const f32x4*)&wl[oc * 192 + icb + 4];
      acc[oc] += v[0] * w0[0] + v[1] * w0[1] + v[2] * w0[2] + v[3] * w0[3] +
                 v[4] * w1[0] + v[5] * w1[1] + v[6] * w1[2] + v[7] * w1[3];
    }
  }
#pragma unroll
  for (int oc = 0; oc < 32; ++oc) y3[(size_t)px * 32 + oc] = acc[oc] + b3[oc];
}

// ---------------------------------------------------------------------------
// K4: classify conv 3x3 p1, 32->32 on hsw(bn2(y3))
// ---------------------------------------------------------------------------
__global__ __launch_bounds__(256) void k_clsconv1(const float* __restrict__ y3,
                                                  const float* __restrict__ w1,
                                                  const float* __restrict__ b1,
                                                  const float* __restrict__ sc,
                                                  const float* __restrict__ sh,
                                                  float* __restrict__ c1) {
  __shared__ float wl[9216];  // [ic][tap][oc]
  __shared__ float scl[32], shl[32];
  const int t = threadIdx.x;
  for (int e = t; e < 9216; e += 256) {
    const int oc = e & 31;
    const int tmp = e >> 5;
    const int tap = tmp % 9, ic = tmp / 9;
    wl[e] = w1[(oc * 32 + ic) * 9 + tap];
  }
  if (t < 32) {
    scl[t] = sc[t];
    shl[t] = sh[t];
  }
  __syncthreads();
  const int px = blockIdx.x * 64 + (t & 63);
  const int ocg = t >> 6;
  const int n = px >> 10, y0 = (px >> 5) & 31, x0 = px & 31;
  float acc[8];
#pragma unroll
  for (int j = 0; j < 8; ++j) acc[j] = 0.f;
  for (int tap = 0; tap < 9; ++tap) {
    const int dy = tap / 3 - 1, dx = tap % 3 - 1;
    const int yy = y0 + dy, xx = x0 + dx;
    if ((unsigned)yy < 32u && (unsigned)xx < 32u) {
      const float* ib = &y3[((n << 10) + yy * 32 + xx) * 32];
      for (int ic = 0; ic < 32; ++ic) {
        const float v = hsw(ib[ic] * scl[ic] + shl[ic]);
        const float* wp = &wl[(ic * 9 + tap) * 32 + ocg * 8];
#pragma unroll
        for (int j = 0; j < 8; ++j) acc[j] += v * wp[j];
      }
    }
  }
#pragma unroll
  for (int j = 0; j < 8; ++j) c1[px * 32 + ocg * 8 + j] = acc[j] + b1[ocg * 8 + j];
}

// ---------------------------------------------------------------------------
// K4c: c2 = conv3x3(hsw(bn(c1))) 32->1, then cls[n,k] = c2 . dw[k] + db[k]
// ---------------------------------------------------------------------------
__global__ __launch_bounds__(256) void k_cls(const float* __restrict__ c1,
                                             const float* __restrict__ w2,
                                             const float* __restrict__ b2,
                                             const float* __restrict__ dw,
                                             const float* __restrict__ db,
                                             const float* __restrict__ sc,
                                             const float* __restrict__ sh,
                                             float* __restrict__ cls) {
  __shared__ float wl[288];
  __shared__ float scl[32], shl[32];
  __shared__ float red0[256], red1[256];
  const int t = threadIdx.x;
  const int n = blockIdx.x;
  // FIX (R2 post-mortem): 288 > blockDim(256); old `if (t<288)` left
  // wl[256..287] as stale LDS garbage -> cls corrupted -> validity flips.
  for (int e = t; e < 288; e += 256) wl[e] = w2[e];
  if (t < 32) {
    scl[t] = sc[t];
    shl[t] = sh[t];
  }
  __syncthreads();
  float s0 = 0.f, s1 = 0.f;
  for (int i = 0; i < 4; ++i) {
    const int px = i * 256 + t;
    const int y0 = px >> 5, x0 = px & 31;
    float c2 = b2[0];
    for (int tap = 0; tap < 9; ++tap) {
      const int dy = tap / 3 - 1, dx = tap % 3 - 1;
      const int yy = y0 + dy, xx = x0 + dx;
      if ((unsigned)yy < 32u && (unsigned)xx < 32u) {
        const float* ib = &c1[((n << 10) + yy * 32 + xx) * 32];
        for (int ic = 0; ic < 32; ++ic)
          c2 += hsw(ib[ic] * scl[ic] + shl[ic]) * wl[ic * 9 + tap];
      }
    }
    s0 += c2 * dw[px];
    s1 += c2 * dw[1024 + px];
  }
  red0[t] = s0;
  red1[t] = s1;
  __syncthreads();
  for (int s = 128; s; s >>= 1) {
    if (t < s) {
      red0[t] += red0[t + s];
      red1[t] += red1[t + s];
    }
    __syncthreads();
  }
  if (t == 0) {
    cls[n * 2 + 0] = red0[0] + db[0];
    cls[n * 2 + 1] = red1[0] + db[1];
  }
}

// ---------------------------------------------------------------------------
// K6: reg = conv3x3 p1 (hsw(bn(rr))) 32->2, fp32 NCHW [8,2,256,256]
// ---------------------------------------------------------------------------
__global__ __launch_bounds__(256) void k_regconv(const u16* __restrict__ rr,
                                                 const float* __restrict__ w,
                                                 const float* __restrict__ b,
                                                 const float* __restrict__ sc,
                                                 const float* __restrict__ sh,
                                                 float* __restrict__ reg) {
  __shared__ u16 rl[3 * 258 * 33];
  __shared__ float wl[576];
  __shared__ float scl[32], shl[32];
  const int t = threadIdx.x;
  const int n = blockIdx.x >> 8, oy = blockIdx.x & 255;
  for (int e = t; e < 576; e += 256) wl[e] = w[e];
  if (t < 32) {
    scl[t] = sc[t];
    shl[t] = sh[t];
  }
  if (t < 192) {
    const int ry = t / 64, side = (t >> 5) & 1, ic = t & 31;
    rl[(ry * 258 + side * 257) * 33 + ic] = 0;
  }
  __syncthreads();
  for (int e = t; e < 3072; e += 256) {
    const int icq8 = e & 3;
    const int pxx = (e >> 2) & 255;
    const int ry = e >> 10;
    const int rowi = oy - 1 + ry;
    u16x8 raw = {0, 0, 0, 0, 0, 0, 0, 0};
    bool ok = (unsigned)rowi < 256u;
    if (ok)
      raw = *(const u16x8*)&rr[((size_t)((n * 256 + rowi) * 256 + pxx)) * 32 + icq8 * 8];
#pragma unroll
    for (int j = 0; j < 8; ++j) {
      const int ic = icq8 * 8 + j;
      float v = 0.f;
      if (ok) v = hsw(bf2f(raw[j]) * scl[ic] + shl[ic]);
      rl[(ry * 258 + pxx + 1) * 33 + ic] = f2bf(v);
    }
  }
  __syncthreads();
  const int px = t;
  float a0 = b[0], a1 = b[1];
#pragma unroll
  for (int ry = 0; ry < 3; ++ry)
#pragma unroll
    for (int kx = 0; kx < 3; ++kx) {
      const u16* ib = &rl[(ry * 258 + px + kx) * 33];
      for (int ic = 0; ic < 32; ++ic) {
        const float v = bf2f(ib[ic]);
        a0 += v * wl[ic * 9 + ry * 3 + kx];
        a1 += v * wl[288 + ic * 9 + ry * 3 + kx];
      }
    }
  reg[(n * 2 + 0) * 65536 + oy * 256 + px] = a0;
  reg[(n * 2 + 1) * 65536 + oy * 256 + px] = a1;
}

// ---------------------------------------------------------------------------
// K7: per (n, ch) spatial argmax, lowest-index tie-break
// ---------------------------------------------------------------------------
__global__ __launch_bounds__(256) void k_argmax(const float* __restrict__ hm,
                                                int* __restrict__ idx) {
  __shared__ float bv[256];
  __shared__ int bi[256];
  const int t = threadIdx.x;
  const float* base = &hm[(size_t)blockIdx.x * 65536];
  float best = -3.402823466e38f;
  int bidx = 2147483647;
  for (int i = t; i < 65536; i += 256) {
    const float v = base[i];
    if (v > best) {
      best = v;
      bidx = i;
    }
  }
  bv[t] = best;
  bi[t] = bidx;
  __syncthreads();
  for (int s = 128; s; s >>= 1) {
    if (t < s) {
      if (bv[t + s] > bv[t] || (bv[t + s] == bv[t] && bi[t + s] < bi[t])) {
        bv[t] = bv[t + s];
        bi[t] = bi[t + s];
      }
    }
    __syncthreads();
  }
  if (t == 0) idx[blockIdx.x] = bi[0];
}

// ---------------------------------------------------------------------------
// K8: decode -> out [8,2,9]
// ---------------------------------------------------------------------------
__global__ void k_final(const float* __restrict__ cls, const int* __restrict__ idx,
                        const float* __restrict__ reg, float* __restrict__ out) {
  const int t = threadIdx.x;
  if (t >= 16) return;
  const int n = t >> 1, p = t & 1;
  const float cv = cls[n * 2 + p];
  float* o = &out[(n * 2 + p) * 9];
  if (!(cv > 0.6f)) {
    for (int i = 0; i < 9; ++i) o[i] = -1.f;
    return;
  }
  o[0] = (float)p;
  for (int c = 0; c < 4; ++c) {
    const int id = idx[n * 8 + p * 4 + c];
    const int yi = id >> 8, xi = id & 255;
    const float ox_ = reg[(n * 2 + 0) * 65536 + id];
    const float oy_ = reg[(n * 2 + 1) * 65536 + id];
    o[1 + c] = fminf(fmaxf((ox_ + (float)xi) * (1.f / 256.f), 0.f), 1.f);
    o[5 + c] = fminf(fmaxf((oy_ + (float)yi) * (1.f / 256.f), 0.f), 1.f);
  }
}

// ---------------------------------------------------------------------------
extern "C" void kernel_launch(void* const* d_in, const int* in_sizes, int n_in,
                              void* d_out, int out_size, void* d_ws, size_t ws_size,
                              hipStream_t stream) {
  const float* feature = (const float*)d_in[0];
  const float* ch_w1 = (const float*)d_in[1];
  const float* ch_b1 = (const float*)d_in[2];
  const float* ch_w2 = (const float*)d_in[3];
  const float* ch_b2 = (const float*)d_in[4];
  const float* ch_w3 = (const float*)d_in[5];
  const float* ch_b3 = (const float*)d_in[6];
  const float* ch_g1 = (const float*)d_in[7];
  const float* ch_be1 = (const float*)d_in[8];
  const float* ch_g2 = (const float*)d_in[9];
  const float* ch_be2 = (const float*)d_in[10];
  const float* cl_w1 = (const float*)d_in[11];
  const float* cl_b1 = (const float*)d_in[12];
  const float* cl_w2 = (const float*)d_in[13];
  const float* cl_b2 = (const float*)d_in[14];
  const float* cl_g = (const float*)d_in[15];
  const float* cl_be = (const float*)d_in[16];
  const float* cl_dw = (const float*)d_in[17];
  const float* cl_db = (const float*)d_in[18];
  const float* rg_tw = (const float*)d_in[19];
  const float* rg_tb = (const float*)d_in[20];
  const float* rg_g = (const float*)d_in[21];
  const float* rg_be = (const float*)d_in[22];
  const float* rg_w = (const float*)d_in[23];
  const float* rg_b = (const float*)d_in[24];
  const float* hm_tw = (const float*)d_in[25];
  const float* hm_tb = (const float*)d_in[26];
  float* out = (float*)d_out;

  char* w = (char*)d_ws;
  const size_t OFF_FB = 0;                  // 134217728
  const size_t OFF_FBL = 134217728;         // 134217728
  const size_t OFF_BP1H = 268435456;        // 1769472
  const size_t OFF_BP1L = 270204928;        // 1769472
  const size_t OFF_BP2H = 271974400;        // 663552
  const size_t OFF_BP2L = 272637952;        // 663552
  const size_t OFF_BP5H = 273301504;        // 442368
  const size_t OFF_BP5L = 273743872;        // 442368
  const size_t OFF_Y1 = 274186240;          // 25165824 (fp32)
  const size_t OFF_Y2 = 299352064;          // 6291456  (fp32)
  const size_t OFF_Y3 = 305643520;          // 1048576
  const size_t OFF_C1 = 306692096;          // 1048576
  const size_t OFF_RR = 307740672;          // 33554432
  const size_t OFF_HM = 341295104;          // 16777216
  const size_t OFF_REG = 358072320;         // 4194304
  const size_t OFF_STATS = 362266624;       // 3840
  const size_t OFF_PARAMS = 362270464;      // 3840
  const size_t OFF_CLS = 362274304;         // 64
  const size_t OFF_IDX = 362274368;         // 256
  const size_t WS_NEED = 362274624;
  if (ws_size < WS_NEED) return;

  u16* FB = (u16*)(w + OFF_FB);
  u16* FBL = (u16*)(w + OFF_FBL);
  u16* BP1H = (u16*)(w + OFF_BP1H);
  u16* BP1L = (u16*)(w + OFF_BP1L);
  u16* BP2H = (u16*)(w + OFF_BP2H);
  u16* BP2L = (u16*)(w + OFF_BP2L);
  u16* BP5H = (u16*)(w + OFF_BP5H);
  u16* BP5L = (u16*)(w + OFF_BP5L);
  float* Y1 = (float*)(w + OFF_Y1);
  float* Y2 = (float*)(w + OFF_Y2);
  float* Y3 = (float*)(w + OFF_Y3);
  float* C1 = (float*)(w + OFF_C1);
  u16* RR = (u16*)(w + OFF_RR);
  float* HM = (float*)(w + OFF_HM);
  float* REG = (float*)(w + OFF_REG);
  float* GSUM = (float*)(w + OFF_STATS);
  float* GSQ = GSUM + 480;
  float* SC = (float*)(w + OFF_PARAMS);
  float* SH = SC + 480;
  float* CLS = (float*)(w + OFF_CLS);
  int* IDX = (int*)(w + OFF_IDX);

  (void)hipMemsetAsync(w + OFF_STATS, 0, 3840, stream);

  k_tobf<<<16384, 256, 0, stream>>>(feature, FB, FBL);
  k_pack1<<<3456, 256, 0, stream>>>(ch_w1, BP1H, BP1L);
  k_pack2<<<1296, 256, 0, stream>>>(ch_w2, BP2H, BP2L);
  k_pack5<<<864, 256, 0, stream>>>(rg_tw, hm_tw, BP5H, BP5L);

  // CommonHead
  k_conv1<<<512, 256, 0, stream>>>(FB, FBL, BP1H, BP1L, ch_b1, Y1);
  k_stats<6, false><<<128, 256, 0, stream>>>(Y1, 32768, 256, GSUM + 0, GSQ + 0);
  k_bnfin<<<1, 256, 0, stream>>>(GSUM + 0, GSQ + 0, ch_g1, ch_be1, 1.f / 32768.f, 192,
                                 SC + 0, SH + 0);
  k_conv2<<<128, 256, 0, stream>>>(Y1, BP2H, BP2L, ch_b2, SC + 0, SH + 0, Y2);
  k_stats<6, false><<<32, 256, 0, stream>>>(Y2, 8192, 256, GSUM + 192, GSQ + 192);
  k_bnfin<<<1, 256, 0, stream>>>(GSUM + 192, GSQ + 192, ch_g1, ch_be1, 1.f / 8192.f,
                                 192, SC + 192, SH + 192);
  k_conv3<<<32, 256, 0, stream>>>(Y2, ch_w3, ch_b3, SC + 192, SH + 192, Y3);
  k_stats<1, false><<<8, 256, 0, stream>>>(Y3, 8192, 1024, GSUM + 384, GSQ + 384);
  k_bnfin<<<1, 256, 0, stream>>>(GSUM + 384, GSQ + 384, ch_g2, ch_be2, 1.f / 8192.f,
                                 32, SC + 384, SH + 384);
  // Classify head
  k_clsconv1<<<128, 256, 0, stream>>>(Y3, cl_w1, cl_b1, SC + 384, SH + 384, C1);
  k_stats<1, false><<<8, 256, 0, stream>>>(C1, 8192, 1024, GSUM + 416, GSQ + 416);
  k_bnfin<<<1, 256, 0, stream>>>(GSUM + 416, GSQ + 416, cl_g, cl_be, 1.f / 8192.f, 32,
                                 SC + 416, SH + 416);
  k_cls<<<8, 256, 0, stream>>>(C1, cl_w2, cl_b2, cl_dw, cl_db, SC + 416, SH + 416,
                               CLS);
  // Regression + heatmap (fused convT, hm split-precision)
  k_convt<<<4096, 256, 0, stream>>>(FB, FBL, BP5H, BP5L, rg_tb, hm_tb, RR, HM);
  k_stats<1, true><<<256, 256, 0, stream>>>(RR, 524288, 2048, GSUM + 448, GSQ + 448);
  k_bnfin<<<1, 256, 0, stream>>>(GSUM + 448, GSQ + 448, rg_g, rg_be, 1.f / 524288.f,
                                 32, SC + 448, SH + 448);
  k_regconv<<<2048, 256, 0, stream>>>(RR, rg_w, rg_b, SC + 448, SH + 448, REG);
  // Decode
  k_argmax<<<64, 256, 0, stream>>>(HM, IDX);
  k_final<<<1, 64, 0, stream>>>(CLS, IDX, REG, out);
}

// Round 4
// 1302.585 us; speedup vs baseline: 1.2770x; 1.2770x over previous
//
#include <hip/hip_runtime.h>

typedef unsigned short u16;
typedef u16 u16x8 __attribute__((ext_vector_type(8)));
typedef __bf16 bf16x8 __attribute__((ext_vector_type(8)));
typedef float f32x4 __attribute__((ext_vector_type(4)));

__device__ __forceinline__ float bf2f(u16 v) {
  unsigned u = ((unsigned)v) << 16;
  return __builtin_bit_cast(float, u);
}
__device__ __forceinline__ u16 f2bf(float f) {
  unsigned u = __builtin_bit_cast(unsigned, f);
  u += 0x7FFFu + ((u >> 16) & 1u);
  return (u16)(u >> 16);
}
__device__ __forceinline__ float hsw(float v) {
  return v * fminf(fmaxf(v + 3.f, 0.f), 6.f) * (1.f / 6.f);
}
__device__ __forceinline__ f32x4 mfma16(u16x8 a, u16x8 b, f32x4 c) {
  return __builtin_amdgcn_mfma_f32_16x16x32_bf16(
      __builtin_bit_cast(bf16x8, a), __builtin_bit_cast(bf16x8, b), c, 0, 0, 0);
}

#define LR 40  // padded LDS row stride in u16 (80 B), breaks pow2 bank stride

// ---------------------------------------------------------------------------
// K0: feature NCHW fp32 -> NHWC bf16 hi + lo planes
// ---------------------------------------------------------------------------
__global__ __launch_bounds__(256) void k_tobf(const float* __restrict__ f,
                                              u16* __restrict__ fbh,
                                              u16* __restrict__ fbl) {
  __shared__ float tl[64 * 65];
  const int t = threadIdx.x;
  const int bid = blockIdx.x;
  const int ict = bid & 7, xt = (bid >> 3) & 1, y = (bid >> 4) & 127, n = bid >> 11;
  const int x0 = xt * 64, ic0 = ict * 64;
#pragma unroll
  for (int i = 0; i < 16; ++i) {
    const int e = t + i * 256;
    const int icl = e >> 6, xl = e & 63;
    tl[icl * 65 + xl] = f[((n * 512 + ic0 + icl) * 128 + y) * 128 + x0 + xl];
  }
  __syncthreads();
#pragma unroll
  for (int i = 0; i < 16; ++i) {
    const int e = t + i * 256;
    const int xl = e >> 6, icl = e & 63;
    const float v = tl[icl * 65 + xl];
    const u16 h = f2bf(v);
    const size_t idx = ((size_t)((n * 128 + y) * 128 + x0 + xl) << 9) + ic0 + icl;
    fbh[idx] = h;
    fbl[idx] = f2bf(v - bf2f(h));
  }
}

// ---------------------------------------------------------------------------
// Weight prepacks: [tap][icc][oc][ic32] bf16 hi/lo
// ---------------------------------------------------------------------------
__global__ __launch_bounds__(256) void k_pack1(const float* __restrict__ w,
                                               u16* __restrict__ bph,
                                               u16* __restrict__ bpl) {
  const int e = blockIdx.x * 256 + threadIdx.x;  // < 9*16*192*32
  const int ici = e & 31;
  const int rest = e >> 5;
  const int oc = rest % 192;
  const int kc = rest / 192;
  const int icc = kc & 15, tap = kc >> 4;
  const int ic = icc * 32 + ici;
  const float v = w[(oc * 512 + ic) * 9 + tap];
  const u16 h = f2bf(v);
  bph[e] = h;
  bpl[e] = f2bf(v - bf2f(h));
}

__global__ __launch_bounds__(256) void k_pack2(const float* __restrict__ w,
                                               u16* __restrict__ bph,
                                               u16* __restrict__ bpl) {
  const int e = blockIdx.x * 256 + threadIdx.x;  // < 9*6*192*32
  const int ici = e & 31;
  const int rest = e >> 5;
  const int oc = rest % 192;
  const int kc = rest / 192;
  const int icc = kc % 6, tap = kc / 6;
  const int ic = icc * 32 + ici;
  const float v = w[(oc * 192 + ic) * 9 + tap];
  const u16 h = f2bf(v);
  bph[e] = h;
  bpl[e] = f2bf(v - bf2f(h));
}

__global__ __launch_bounds__(256) void k_pack5(const float* __restrict__ rgw,
                                               const float* __restrict__ hmw,
                                               u16* __restrict__ bph,
                                               u16* __restrict__ bpl) {
  const int e = blockIdx.x * 256 + threadIdx.x;  // < 9*16*48*32
  const int ici = e & 31;
  const int rest = e >> 5;
  const int oc = rest % 48;
  const int sic = rest / 48;
  const int icc = sic & 15, slot = sic >> 4;
  const int ic = icc * 32 + ici;
  const int kytab[9] = {1, 1, 1, 2, 0, 2, 2, 0, 0};
  const int kxtab[9] = {1, 2, 0, 1, 1, 2, 0, 2, 0};
  const int ky = kytab[slot], kx = kxtab[slot];
  float v = 0.f;
  if (oc < 32)
    v = rgw[((ic * 32 + oc) * 3 + ky) * 3 + kx];
  else if (oc < 40)
    v = hmw[((ic * 8 + (oc - 32)) * 3 + ky) * 3 + kx];
  const u16 h = f2bf(v);
  bph[e] = h;
  bpl[e] = f2bf(v - bf2f(h));
}

// ---------------------------------------------------------------------------
// K1: conv1 3x3 s2 p1, 512->192, split-bf16 (3x MFMA). y1 fp32 NHWC.
// ---------------------------------------------------------------------------
__global__ __launch_bounds__(256) void k_conv1(const u16* __restrict__ fbh,
                                               const u16* __restrict__ fbl,
                                               const u16* __restrict__ bph,
                                               const u16* __restrict__ bpl,
                                               const float* __restrict__ bias,
                                               float* __restrict__ y1) {
  __shared__ u16 AlH[64 * LR], AlL[64 * LR];
  __shared__ u16 BlH[192 * LR], BlL[192 * LR];
  __shared__ float bl[192];
  const int t = threadIdx.x;
  const int n = blockIdx.x >> 6, oy = blockIdx.x & 63;
  if (t < 192) bl[t] = bias[t];
  const int lane = t & 63, wv = t >> 6;
  const int row = lane & 15, g = lane >> 4;
  const int oxs = t >> 2, icq = t & 3;
  const f32x4 z4 = {0.f, 0.f, 0.f, 0.f};
  f32x4 acc[4][3];
#pragma unroll
  for (int i = 0; i < 4; ++i)
#pragma unroll
    for (int j = 0; j < 3; ++j) acc[i][j] = z4;

  for (int kc = 0; kc < 144; ++kc) {
    const int tap = kc >> 4, icc = kc & 15;
    const int ky = tap / 3, kx = tap - ky * 3;
    const int iy = 2 * oy - 1 + ky;
    const int ix = 2 * oxs - 1 + kx;
    u16x8 avh = {0, 0, 0, 0, 0, 0, 0, 0};
    u16x8 avl = {0, 0, 0, 0, 0, 0, 0, 0};
    if ((unsigned)iy < 128u && (unsigned)ix < 128u) {
      const size_t idx =
          ((size_t)((n * 128 + iy) * 128 + ix) << 9) + icc * 32 + icq * 8;
      avh = *(const u16x8*)&fbh[idx];
      avl = *(const u16x8*)&fbl[idx];
    }
    u16x8 bvh[3], bvl[3];
    const size_t bbase = (size_t)(tap * 16 + icc) * (192 * 32);
#pragma unroll
    for (int i = 0; i < 3; ++i) {
      const int e = t + i * 256;
      const size_t off = bbase + (e >> 2) * 32 + (e & 3) * 8;
      bvh[i] = *(const u16x8*)&bph[off];
      bvl[i] = *(const u16x8*)&bpl[off];
    }
    __syncthreads();
    *(u16x8*)&AlH[oxs * LR + icq * 8] = avh;
    *(u16x8*)&AlL[oxs * LR + icq * 8] = avl;
#pragma unroll
    for (int i = 0; i < 3; ++i) {
      const int e = t + i * 256;
      *(u16x8*)&BlH[(e >> 2) * LR + (e & 3) * 8] = bvh[i];
      *(u16x8*)&BlL[(e >> 2) * LR + (e & 3) * 8] = bvl[i];
    }
    __syncthreads();
    u16x8 afh[4], afl[4], bfh[3], bfl[3];
#pragma unroll
    for (int mf = 0; mf < 4; ++mf) {
      afh[mf] = *(const u16x8*)&AlH[(mf * 16 + row) * LR + g * 8];
      afl[mf] = *(const u16x8*)&AlL[(mf * 16 + row) * LR + g * 8];
    }
#pragma unroll
    for (int nf = 0; nf < 3; ++nf) {
      bfh[nf] = *(const u16x8*)&BlH[(wv * 48 + nf * 16 + row) * LR + g * 8];
      bfl[nf] = *(const u16x8*)&BlL[(wv * 48 + nf * 16 + row) * LR + g * 8];
    }
#pragma unroll
    for (int mf = 0; mf < 4; ++mf)
#pragma unroll
      for (int nf = 0; nf < 3; ++nf) {
        acc[mf][nf] = mfma16(afh[mf], bfh[nf], acc[mf][nf]);
        acc[mf][nf] = mfma16(afh[mf], bfl[nf], acc[mf][nf]);
        acc[mf][nf] = mfma16(afl[mf], bfh[nf], acc[mf][nf]);
      }
  }
#pragma unroll
  for (int mf = 0; mf < 4; ++mf)
#pragma unroll
    for (int nf = 0; nf < 3; ++nf)
#pragma unroll
      for (int r = 0; r < 4; ++r) {
        const int m = mf * 16 + g * 4 + r;
        const int oc = wv * 48 + nf * 16 + row;
        y1[((n * 64 + oy) * 64 + m) * 192 + oc] = acc[mf][nf][r] + bl[oc];
      }
}

// ---------------------------------------------------------------------------
// K2: conv2 3x3 s2 p1, 192->192 on bn1(y1 fp32), split-bf16. y2 fp32 NHWC.
// ---------------------------------------------------------------------------
__global__ __launch_bounds__(256) void k_conv2(const float* __restrict__ y1,
                                               const u16* __restrict__ bph,
                                               const u16* __restrict__ bpl,
                                               const float* __restrict__ bias,
                                               const float* __restrict__ sc,
                                               const float* __restrict__ sh,
                                               float* __restrict__ y2) {
  __shared__ u16 AlH[64 * LR], AlL[64 * LR];
  __shared__ u16 BlH[192 * LR], BlL[192 * LR];
  __shared__ float bl[192], scl[192], shl[192];
  const int t = threadIdx.x;
  const int n = blockIdx.x >> 4, oyp = blockIdx.x & 15;
  if (t < 192) {
    bl[t] = bias[t];
    scl[t] = sc[t];
    shl[t] = sh[t];
  }
  __syncthreads();
  const int lane = t & 63, wv = t >> 6;
  const int row = lane & 15, g = lane >> 4;
  const int ms = t >> 2, icq = t & 3;
  const int ryr = ms >> 5, oxs = ms & 31;
  const f32x4 z4 = {0.f, 0.f, 0.f, 0.f};
  f32x4 acc[4][3];
#pragma unroll
  for (int i = 0; i < 4; ++i)
#pragma unroll
    for (int j = 0; j < 3; ++j) acc[i][j] = z4;

  for (int kc = 0; kc < 54; ++kc) {
    const int tap = kc / 6, icc = kc - tap * 6;
    const int ky = tap / 3, kx = tap - ky * 3;
    const int iy = 2 * (oyp * 2 + ryr) - 1 + ky;
    const int ix = 2 * oxs - 1 + kx;
    u16x8 avh = {0, 0, 0, 0, 0, 0, 0, 0};
    u16x8 avl = {0, 0, 0, 0, 0, 0, 0, 0};
    if ((unsigned)iy < 64u && (unsigned)ix < 64u) {
      const int icb = icc * 32 + icq * 8;
      const float* base = &y1[((n * 64 + iy) * 64 + ix) * 192 + icb];
      const f32x4 r0 = *(const f32x4*)base;
      const f32x4 r1 = *(const f32x4*)(base + 4);
#pragma unroll
      for (int j = 0; j < 8; ++j) {
        const float r = (j < 4) ? r0[j & 3] : r1[j & 3];
        const float v = r * scl[icb + j] + shl[icb + j];
        const u16 h = f2bf(v);
        avh[j] = h;
        avl[j] = f2bf(v - bf2f(h));
      }
    }
    u16x8 bvh[3], bvl[3];
    const size_t bbase = (size_t)(tap * 6 + icc) * (192 * 32);
#pragma unroll
    for (int i = 0; i < 3; ++i) {
      const int e = t + i * 256;
      const size_t off = bbase + (e >> 2) * 32 + (e & 3) * 8;
      bvh[i] = *(const u16x8*)&bph[off];
      bvl[i] = *(const u16x8*)&bpl[off];
    }
    __syncthreads();
    *(u16x8*)&AlH[ms * LR + icq * 8] = avh;
    *(u16x8*)&AlL[ms * LR + icq * 8] = avl;
#pragma unroll
    for (int i = 0; i < 3; ++i) {
      const int e = t + i * 256;
      *(u16x8*)&BlH[(e >> 2) * LR + (e & 3) * 8] = bvh[i];
      *(u16x8*)&BlL[(e >> 2) * LR + (e & 3) * 8] = bvl[i];
    }
    __syncthreads();
    u16x8 afh[4], afl[4], bfh[3], bfl[3];
#pragma unroll
    for (int mf = 0; mf < 4; ++mf) {
      afh[mf] = *(const u16x8*)&AlH[(mf * 16 + row) * LR + g * 8];
      afl[mf] = *(const u16x8*)&AlL[(mf * 16 + row) * LR + g * 8];
    }
#pragma unroll
    for (int nf = 0; nf < 3; ++nf) {
      bfh[nf] = *(const u16x8*)&BlH[(wv * 48 + nf * 16 + row) * LR + g * 8];
      bfl[nf] = *(const u16x8*)&BlL[(wv * 48 + nf * 16 + row) * LR + g * 8];
    }
#pragma unroll
    for (int mf = 0; mf < 4; ++mf)
#pragma unroll
      for (int nf = 0; nf < 3; ++nf) {
        acc[mf][nf] = mfma16(afh[mf], bfh[nf], acc[mf][nf]);
        acc[mf][nf] = mfma16(afh[mf], bfl[nf], acc[mf][nf]);
        acc[mf][nf] = mfma16(afl[mf], bfh[nf], acc[mf][nf]);
      }
  }
#pragma unroll
  for (int mf = 0; mf < 4; ++mf)
#pragma unroll
    for (int nf = 0; nf < 3; ++nf)
#pragma unroll
      for (int r = 0; r < 4; ++r) {
        const int m = mf * 16 + g * 4 + r;
        const int oy = oyp * 2 + (m >> 5), ox = m & 31;
        const int oc = wv * 48 + nf * 16 + row;
        y2[((n * 32 + oy) * 32 + ox) * 192 + oc] = acc[mf][nf][r] + bl[oc];
      }
}

// ---------------------------------------------------------------------------
// K5 (rewritten): fused ConvT. Block = (n, input row pair iyb). Computes ALL
// 4 parity classes (output rows 2*iyb, 2*iyb+1; both x parities), K-loop over
// 16 ic-chunks only; all 9 taps are shifted reads of one staged A row-pair.
// A-hi staged in LDS; A-lo direct-to-reg (only needed for hm split); B frags
// read directly from global (L2-resident, coalesced).
// ---------------------------------------------------------------------------
#define AST 40           // px stride in u16 (80 B)
#define ARS (130 * 40)   // per-row plane stride in u16
__global__ __launch_bounds__(256) void k_convt(const u16* __restrict__ fbh,
                                               const u16* __restrict__ fbl,
                                               const u16* __restrict__ bph,
                                               const u16* __restrict__ bpl,
                                               const float* __restrict__ rgb,
                                               const float* __restrict__ hmb,
                                               u16* __restrict__ rr,
                                               float* __restrict__ hm) {
  __shared__ u16 AH[2 * ARS];  // 20.8 KB
  const int t = threadIdx.x;
  const int n = blockIdx.x >> 7, iyb = blockIdx.x & 127;
  const int lane = t & 63, wv = t >> 6;
  const int row = lane & 15, g = lane >> 4;

  // zero the px=128 halo column (never rewritten)
  if (t < 10) {
    const int r = t / 5, j = t % 5;
    const u16x8 z = {0, 0, 0, 0, 0, 0, 0, 0};
    *(u16x8*)&AH[r * ARS + 128 * AST + j * 8] = z;
  }

  // per-lane bias for the 3 N-fragments (oc = nf*16 + row)
  float bias3[3];
#pragma unroll
  for (int nf = 0; nf < 3; ++nf) {
    const int oc = nf * 16 + row;
    bias3[nf] = (oc < 32) ? rgb[oc] : ((oc < 40) ? hmb[oc - 32] : 0.f);
  }

  // slot -> (class, diy, dix); class 0: oy even/ox even ... 3: odd/odd
  const int SCt[9] = {0, 1, 1, 2, 2, 3, 3, 3, 3};
  const int SDt[9] = {0, 0, 0, 0, 1, 0, 0, 1, 1};
  const int SXt[9] = {0, 0, 1, 0, 0, 0, 1, 0, 1};

  const f32x4 z4 = {0.f, 0.f, 0.f, 0.f};
  f32x4 acc[4][2][3];
#pragma unroll
  for (int c = 0; c < 4; ++c)
#pragma unroll
    for (int m = 0; m < 2; ++m)
#pragma unroll
      for (int j = 0; j < 3; ++j) acc[c][m][j] = z4;

  for (int icc = 0; icc < 16; ++icc) {
    // ---- A-hi staging loads (2 rows x 128 px x 32 ch) ----
    u16x8 ah[4];
    int rr_[4], px_[4], iq_[4];
#pragma unroll
    for (int i = 0; i < 4; ++i) {
      const int u = t + i * 256;
      const int r = u >> 9, px = (u >> 2) & 127, icq = u & 3;
      rr_[i] = r; px_[i] = px; iq_[i] = icq;
      const int iy = iyb + r;
      u16x8 v = {0, 0, 0, 0, 0, 0, 0, 0};
      if (iy < 128)
        v = *(const u16x8*)&fbh[((size_t)((n * 128 + iy) * 128 + px) << 9) +
                                icc * 32 + icq * 8];
      ah[i] = v;
    }
    // ---- A-lo fragments direct to registers ----
    u16x8 lo[2][2][2];  // [diy][mfl][dix]
#pragma unroll
    for (int diy = 0; diy < 2; ++diy) {
      const int iy = iyb + diy;
      const bool ok = iy < 128;
#pragma unroll
      for (int mfl = 0; mfl < 2; ++mfl)
#pragma unroll
        for (int dix = 0; dix < 2; ++dix) {
          const int px = (wv * 2 + mfl) * 16 + row + dix;
          u16x8 v = {0, 0, 0, 0, 0, 0, 0, 0};
          if (ok && px < 128)
            v = *(const u16x8*)&fbl[((size_t)((n * 128 + iy) * 128 + px) << 9) +
                                    icc * 32 + g * 8];
          lo[diy][mfl][dix] = v;
        }
    }
    __syncthreads();
#pragma unroll
    for (int i = 0; i < 4; ++i)
      *(u16x8*)&AH[rr_[i] * ARS + px_[i] * AST + iq_[i] * 8] = ah[i];
    __syncthreads();

    // ---- 9 taps x 2 M-frags per wave; B frags from global (L2) ----
#pragma unroll
    for (int slot = 0; slot < 9; ++slot) {
      const int cls = SCt[slot], diy = SDt[slot], dix = SXt[slot];
      const u16* bb = &bph[(size_t)((slot * 16 + icc) * 48) * 32];
      const u16x8 bfh0 = *(const u16x8*)&bb[(0 * 16 + row) * 32 + g * 8];
      const u16x8 bfh1 = *(const u16x8*)&bb[(1 * 16 + row) * 32 + g * 8];
      const u16x8 bfh2 = *(const u16x8*)&bb[(2 * 16 + row) * 32 + g * 8];
      const u16x8 bfl2 = *(const u16x8*)&bpl[(size_t)((slot * 16 + icc) * 48 +
                                                      32 + row) * 32 + g * 8];
#pragma unroll
      for (int mfl = 0; mfl < 2; ++mfl) {
        const int mf = wv * 2 + mfl;
        const u16x8 afh =
            *(const u16x8*)&AH[diy * ARS + (mf * 16 + row + dix) * AST + g * 8];
        const u16x8 afl = lo[diy][mfl][dix];
        acc[cls][mfl][0] = mfma16(afh, bfh0, acc[cls][mfl][0]);
        acc[cls][mfl][1] = mfma16(afh, bfh1, acc[cls][mfl][1]);
        acc[cls][mfl][2] = mfma16(afh, bfh2, acc[cls][mfl][2]);
        acc[cls][mfl][2] = mfma16(afh, bfl2, acc[cls][mfl][2]);
        acc[cls][mfl][2] = mfma16(afl, bfh2, acc[cls][mfl][2]);
      }
    }
  }

  // ---- epilogue ----
#pragma unroll
  for (int cls = 0; cls < 4; ++cls) {
    const int oy = 2 * iyb + (cls >> 1);
    const int xp = cls & 1;
#pragma unroll
    for (int mfl = 0; mfl < 2; ++mfl)
#pragma unroll
      for (int nf = 0; nf < 3; ++nf)
#pragma unroll
        for (int r = 0; r < 4; ++r) {
          const int m = (wv * 2 + mfl) * 16 + g * 4 + r;
          const int ox = 2 * m + xp;
          const int oc = nf * 16 + row;
          const float v = acc[cls][mfl][nf][r] + bias3[nf];
          if (oc < 32)
            rr[((size_t)((n * 256 + oy) * 256 + ox)) * 32 + oc] = f2bf(v);
          else if (oc < 40)
            hm[(size_t)(n * 8 + (oc - 32)) * 65536 + oy * 256 + ox] = v;
        }
  }
}

// ---------------------------------------------------------------------------
// Generic per-channel sum/sumsq over [M][C] (C = CG*32)
// ---------------------------------------------------------------------------
template <int CG, bool BF16>
__global__ __launch_bounds__(256) void k_stats(const void* __restrict__ in_, int M,
                                               int PB, float* __restrict__ gsum,
                                               float* __restrict__ gsq) {
  const int C = CG * 32;
  __shared__ float red[8][CG * 32];
  const int t = threadIdx.x;
  const int pg = t >> 5, ln = t & 31;
  float s[CG], q[CG];
#pragma unroll
  for (int c = 0; c < CG; ++c) { s[c] = 0.f; q[c] = 0.f; }
  const int p0 = blockIdx.x * PB;
  const int pend = min(p0 + PB, M);
  for (int p = p0 + pg; p < pend; p += 8) {
#pragma unroll
    for (int c = 0; c < CG; ++c) {
      float v;
      if (BF16)
        v = bf2f(((const u16*)in_)[(size_t)p * C + c * 32 + ln]);
      else
        v = ((const float*)in_)[(size_t)p * C + c * 32 + ln];
      s[c] += v;
      q[c] += v * v;
    }
  }
#pragma unroll
  for (int c = 0; c < CG; ++c) red[pg][c * 32 + ln] = s[c];
  __syncthreads();
  if (t < C) {
    float tot = 0.f;
#pragma unroll
    for (int k = 0; k < 8; ++k) tot += red[k][t];
    atomicAdd(&gsum[t], tot);
  }
  __syncthreads();
#pragma unroll
  for (int c = 0; c < CG; ++c) red[pg][c * 32 + ln] = q[c];
  __syncthreads();
  if (t < C) {
    float tot = 0.f;
#pragma unroll
    for (int k = 0; k < 8; ++k) tot += red[k][t];
    atomicAdd(&gsq[t], tot);
  }
}

__global__ void k_bnfin(const float* __restrict__ gsum, const float* __restrict__ gsq,
                        const float* __restrict__ g, const float* __restrict__ be,
                        float invM, int C, float* __restrict__ sc,
                        float* __restrict__ sh) {
  const int t = threadIdx.x;
  if (t < C) {
    const float m = gsum[t] * invM;
    const float var = gsq[t] * invM - m * m;
    const float inv = rsqrtf(var + 1e-5f);
    const float s = g[t] * inv;
    sc[t] = s;
    sh[t] = be[t] - m * s;
  }
}

// ---------------------------------------------------------------------------
// K3: conv3 1x1 192->32 on bn(y2 fp32). y3 fp32 [8192][32].
// ---------------------------------------------------------------------------
__global__ __launch_bounds__(256) void k_conv3(const float* __restrict__ y2,
                                               const float* __restrict__ w3,
                                               const float* __restrict__ b3,
                                               const float* __restrict__ sc,
                                               const float* __restrict__ sh,
                                               float* __restrict__ y3) {
  __shared__ float wl[32 * 192];
  __shared__ float scl[192], shl[192];
  const int t = threadIdx.x;
  for (int e = t; e < 6144; e += 256) wl[e] = w3[e];
  if (t < 192) {
    scl[t] = sc[t];
    shl[t] = sh[t];
  }
  __syncthreads();
  const int px = blockIdx.x * 256 + t;
  float acc[32];
#pragma unroll
  for (int oc = 0; oc < 32; ++oc) acc[oc] = 0.f;
  const float* base = &y2[(size_t)px * 192];
  for (int icb = 0; icb < 192; icb += 8) {
    const f32x4 r0 = *(const f32x4*)&base[icb];
    const f32x4 r1 = *(const f32x4*)&base[icb + 4];
    float v[8];
#pragma unroll
    for (int j = 0; j < 8; ++j) {
      const float r = (j < 4) ? r0[j & 3] : r1[j & 3];
      v[j] = r * scl[icb + j] + shl[icb + j];
    }
#pragma unroll
    for (int oc = 0; oc < 32; ++oc) {
      const f32x4 w0 = *(const f32x4*)&wl[oc * 192 + icb];
      const f32x4 w1 = *(const f32x4*)&wl[oc * 192 + icb + 4];
      acc[oc] += v[0] * w0[0] + v[1] * w0[1] + v[2] * w0[2] + v[3] * w0[3] +
                 v[4] * w1[0] + v[5] * w1[1] + v[6] * w1[2] + v[7] * w1[3];
    }
  }
#pragma unroll
  for (int oc = 0; oc < 32; ++oc) y3[(size_t)px * 32 + oc] = acc[oc] + b3[oc];
}

// ---------------------------------------------------------------------------
// K4: classify conv 3x3 p1, 32->32 on hsw(bn2(y3))
// ---------------------------------------------------------------------------
__global__ __launch_bounds__(256) void k_clsconv1(const float* __restrict__ y3,
                                                  const float* __restrict__ w1,
                                                  const float* __restrict__ b1,
                                                  const float* __restrict__ sc,
                                                  const float* __restrict__ sh,
                                                  float* __restrict__ c1) {
  __shared__ float wl[9216];  // [ic][tap][oc]
  __shared__ float scl[32], shl[32];
  const int t = threadIdx.x;
  for (int e = t; e < 9216; e += 256) {
    const int oc = e & 31;
    const int tmp = e >> 5;
    const int tap = tmp % 9, ic = tmp / 9;
    wl[e] = w1[(oc * 32 + ic) * 9 + tap];
  }
  if (t < 32) {
    scl[t] = sc[t];
    shl[t] = sh[t];
  }
  __syncthreads();
  const int px = blockIdx.x * 64 + (t & 63);
  const int ocg = t >> 6;
  const int n = px >> 10, y0 = (px >> 5) & 31, x0 = px & 31;
  float acc[8];
#pragma unroll
  for (int j = 0; j < 8; ++j) acc[j] = 0.f;
  for (int tap = 0; tap < 9; ++tap) {
    const int dy = tap / 3 - 1, dx = tap % 3 - 1;
    const int yy = y0 + dy, xx = x0 + dx;
    if ((unsigned)yy < 32u && (unsigned)xx < 32u) {
      const float* ib = &y3[((n << 10) + yy * 32 + xx) * 32];
      for (int ic = 0; ic < 32; ++ic) {
        const float v = hsw(ib[ic] * scl[ic] + shl[ic]);
        const float* wp = &wl[(ic * 9 + tap) * 32 + ocg * 8];
#pragma unroll
        for (int j = 0; j < 8; ++j) acc[j] += v * wp[j];
      }
    }
  }
#pragma unroll
  for (int j = 0; j < 8; ++j) c1[px * 32 + ocg * 8 + j] = acc[j] + b1[ocg * 8 + j];
}

// ---------------------------------------------------------------------------
// K4c: c2 = conv3x3(hsw(bn(c1))) 32->1, then cls[n,k] = c2 . dw[k] + db[k]
// ---------------------------------------------------------------------------
__global__ __launch_bounds__(256) void k_cls(const float* __restrict__ c1,
                                             const float* __restrict__ w2,
                                             const float* __restrict__ b2,
                                             const float* __restrict__ dw,
                                             const float* __restrict__ db,
                                             const float* __restrict__ sc,
                                             const float* __restrict__ sh,
                                             float* __restrict__ cls) {
  __shared__ float wl[288];
  __shared__ float scl[32], shl[32];
  __shared__ float red0[256], red1[256];
  const int t = threadIdx.x;
  const int n = blockIdx.x;
  for (int e = t; e < 288; e += 256) wl[e] = w2[e];
  if (t < 32) {
    scl[t] = sc[t];
    shl[t] = sh[t];
  }
  __syncthreads();
  float s0 = 0.f, s1 = 0.f;
  for (int i = 0; i < 4; ++i) {
    const int px = i * 256 + t;
    const int y0 = px >> 5, x0 = px & 31;
    float c2 = b2[0];
    for (int tap = 0; tap < 9; ++tap) {
      const int dy = tap / 3 - 1, dx = tap % 3 - 1;
      const int yy = y0 + dy, xx = x0 + dx;
      if ((unsigned)yy < 32u && (unsigned)xx < 32u) {
        const float* ib = &c1[((n << 10) + yy * 32 + xx) * 32];
        for (int ic = 0; ic < 32; ++ic)
          c2 += hsw(ib[ic] * scl[ic] + shl[ic]) * wl[ic * 9 + tap];
      }
    }
    s0 += c2 * dw[px];
    s1 += c2 * dw[1024 + px];
  }
  red0[t] = s0;
  red1[t] = s1;
  __syncthreads();
  for (int s = 128; s; s >>= 1) {
    if (t < s) {
      red0[t] += red0[t + s];
      red1[t] += red1[t + s];
    }
    __syncthreads();
  }
  if (t == 0) {
    cls[n * 2 + 0] = red0[0] + db[0];
    cls[n * 2 + 1] = red1[0] + db[1];
  }
}

// ---------------------------------------------------------------------------
// K6: reg = conv3x3 p1 (hsw(bn(rr))) 32->2, fp32 NCHW [8,2,256,256]
// ---------------------------------------------------------------------------
__global__ __launch_bounds__(256) void k_regconv(const u16* __restrict__ rr,
                                                 const float* __restrict__ w,
                                                 const float* __restrict__ b,
                                                 const float* __restrict__ sc,
                                                 const float* __restrict__ sh,
                                                 float* __restrict__ reg) {
  __shared__ u16 rl[3 * 258 * 33];
  __shared__ float wl[576];
  __shared__ float scl[32], shl[32];
  const int t = threadIdx.x;
  const int n = blockIdx.x >> 8, oy = blockIdx.x & 255;
  for (int e = t; e < 576; e += 256) wl[e] = w[e];
  if (t < 32) {
    scl[t] = sc[t];
    shl[t] = sh[t];
  }
  if (t < 192) {
    const int ry = t / 64, side = (t >> 5) & 1, ic = t & 31;
    rl[(ry * 258 + side * 257) * 33 + ic] = 0;
  }
  __syncthreads();
  for (int e = t; e < 3072; e += 256) {
    const int icq8 = e & 3;
    const int pxx = (e >> 2) & 255;
    const int ry = e >> 10;
    const int rowi = oy - 1 + ry;
    u16x8 raw = {0, 0, 0, 0, 0, 0, 0, 0};
    bool ok = (unsigned)rowi < 256u;
    if (ok)
      raw = *(const u16x8*)&rr[((size_t)((n * 256 + rowi) * 256 + pxx)) * 32 + icq8 * 8];
#pragma unroll
    for (int j = 0; j < 8; ++j) {
      const int ic = icq8 * 8 + j;
      float v = 0.f;
      if (ok) v = hsw(bf2f(raw[j]) * scl[ic] + shl[ic]);
      rl[(ry * 258 + pxx + 1) * 33 + ic] = f2bf(v);
    }
  }
  __syncthreads();
  const int px = t;
  float a0 = b[0], a1 = b[1];
#pragma unroll
  for (int ry = 0; ry < 3; ++ry)
#pragma unroll
    for (int kx = 0; kx < 3; ++kx) {
      const u16* ib = &rl[(ry * 258 + px + kx) * 33];
      for (int ic = 0; ic < 32; ++ic) {
        const float v = bf2f(ib[ic]);
        a0 += v * wl[ic * 9 + ry * 3 + kx];
        a1 += v * wl[288 + ic * 9 + ry * 3 + kx];
      }
    }
  reg[(n * 2 + 0) * 65536 + oy * 256 + px] = a0;
  reg[(n * 2 + 1) * 65536 + oy * 256 + px] = a1;
}

// ---------------------------------------------------------------------------
// K7: per (n, ch) spatial argmax, lowest-index tie-break
// ---------------------------------------------------------------------------
__global__ __launch_bounds__(256) void k_argmax(const float* __restrict__ hm,
                                                int* __restrict__ idx) {
  __shared__ float bv[256];
  __shared__ int bi[256];
  const int t = threadIdx.x;
  const float* base = &hm[(size_t)blockIdx.x * 65536];
  float best = -3.402823466e38f;
  int bidx = 2147483647;
  for (int i = t; i < 65536; i += 256) {
    const float v = base[i];
    if (v > best) {
      best = v;
      bidx = i;
    }
  }
  bv[t] = best;
  bi[t] = bidx;
  __syncthreads();
  for (int s = 128; s; s >>= 1) {
    if (t < s) {
      if (bv[t + s] > bv[t] || (bv[t + s] == bv[t] && bi[t + s] < bi[t])) {
        bv[t] = bv[t + s];
        bi[t] = bi[t + s];
      }
    }
    __syncthreads();
  }
  if (t == 0) idx[blockIdx.x] = bi[0];
}

// ---------------------------------------------------------------------------
// K8: decode -> out [8,2,9]
// ---------------------------------------------------------------------------
__global__ void k_final(const float* __restrict__ cls, const int* __restrict__ idx,
                        const float* __restrict__ reg, float* __restrict__ out) {
  const int t = threadIdx.x;
  if (t >= 16) return;
  const int n = t >> 1, p = t & 1;
  const float cv = cls[n * 2 + p];
  float* o = &out[(n * 2 + p) * 9];
  if (!(cv > 0.6f)) {
    for (int i = 0; i < 9; ++i) o[i] = -1.f;
    return;
  }
  o[0] = (float)p;
  for (int c = 0; c < 4; ++c) {
    const int id = idx[n * 8 + p * 4 + c];
    const int yi = id >> 8, xi = id & 255;
    const float ox_ = reg[(n * 2 + 0) * 65536 + id];
    const float oy_ = reg[(n * 2 + 1) * 65536 + id];
    o[1 + c] = fminf(fmaxf((ox_ + (float)xi) * (1.f / 256.f), 0.f), 1.f);
    o[5 + c] = fminf(fmaxf((oy_ + (float)yi) * (1.f / 256.f), 0.f), 1.f);
  }
}

// ---------------------------------------------------------------------------
extern "C" void kernel_launch(void* const* d_in, const int* in_sizes, int n_in,
                              void* d_out, int out_size, void* d_ws, size_t ws_size,
                              hipStream_t stream) {
  const float* feature = (const float*)d_in[0];
  const float* ch_w1 = (const float*)d_in[1];
  const float* ch_b1 = (const float*)d_in[2];
  const float* ch_w2 = (const float*)d_in[3];
  const float* ch_b2 = (const float*)d_in[4];
  const float* ch_w3 = (const float*)d_in[5];
  const float* ch_b3 = (const float*)d_in[6];
  const float* ch_g1 = (const float*)d_in[7];
  const float* ch_be1 = (const float*)d_in[8];
  const float* ch_g2 = (const float*)d_in[9];
  const float* ch_be2 = (const float*)d_in[10];
  const float* cl_w1 = (const float*)d_in[11];
  const float* cl_b1 = (const float*)d_in[12];
  const float* cl_w2 = (const float*)d_in[13];
  const float* cl_b2 = (const float*)d_in[14];
  const float* cl_g = (const float*)d_in[15];
  const float* cl_be = (const float*)d_in[16];
  const float* cl_dw = (const float*)d_in[17];
  const float* cl_db = (const float*)d_in[18];
  const float* rg_tw = (const float*)d_in[19];
  const float* rg_tb = (const float*)d_in[20];
  const float* rg_g = (const float*)d_in[21];
  const float* rg_be = (const float*)d_in[22];
  const float* rg_w = (const float*)d_in[23];
  const float* rg_b = (const float*)d_in[24];
  const float* hm_tw = (const float*)d_in[25];
  const float* hm_tb = (const float*)d_in[26];
  float* out = (float*)d_out;

  char* w = (char*)d_ws;
  const size_t OFF_FB = 0;                  // 134217728
  const size_t OFF_FBL = 134217728;         // 134217728
  const size_t OFF_BP1H = 268435456;        // 1769472
  const size_t OFF_BP1L = 270204928;        // 1769472
  const size_t OFF_BP2H = 271974400;        // 663552
  const size_t OFF_BP2L = 272637952;        // 663552
  const size_t OFF_BP5H = 273301504;        // 442368
  const size_t OFF_BP5L = 273743872;        // 442368
  const size_t OFF_Y1 = 274186240;          // 25165824 (fp32)
  const size_t OFF_Y2 = 299352064;          // 6291456  (fp32)
  const size_t OFF_Y3 = 305643520;          // 1048576
  const size_t OFF_C1 = 306692096;          // 1048576
  const size_t OFF_RR = 307740672;          // 33554432
  const size_t OFF_HM = 341295104;          // 16777216
  const size_t OFF_REG = 358072320;         // 4194304
  const size_t OFF_STATS = 362266624;       // 3840
  const size_t OFF_PARAMS = 362270464;      // 3840
  const size_t OFF_CLS = 362274304;         // 64
  const size_t OFF_IDX = 362274368;         // 256
  const size_t WS_NEED = 362274624;
  if (ws_size < WS_NEED) return;

  u16* FB = (u16*)(w + OFF_FB);
  u16* FBL = (u16*)(w + OFF_FBL);
  u16* BP1H = (u16*)(w + OFF_BP1H);
  u16* BP1L = (u16*)(w + OFF_BP1L);
  u16* BP2H = (u16*)(w + OFF_BP2H);
  u16* BP2L = (u16*)(w + OFF_BP2L);
  u16* BP5H = (u16*)(w + OFF_BP5H);
  u16* BP5L = (u16*)(w + OFF_BP5L);
  float* Y1 = (float*)(w + OFF_Y1);
  float* Y2 = (float*)(w + OFF_Y2);
  float* Y3 = (float*)(w + OFF_Y3);
  float* C1 = (float*)(w + OFF_C1);
  u16* RR = (u16*)(w + OFF_RR);
  float* HM = (float*)(w + OFF_HM);
  float* REG = (float*)(w + OFF_REG);
  float* GSUM = (float*)(w + OFF_STATS);
  float* GSQ = GSUM + 480;
  float* SC = (float*)(w + OFF_PARAMS);
  float* SH = SC + 480;
  float* CLS = (float*)(w + OFF_CLS);
  int* IDX = (int*)(w + OFF_IDX);

  (void)hipMemsetAsync(w + OFF_STATS, 0, 3840, stream);

  k_tobf<<<16384, 256, 0, stream>>>(feature, FB, FBL);
  k_pack1<<<3456, 256, 0, stream>>>(ch_w1, BP1H, BP1L);
  k_pack2<<<1296, 256, 0, stream>>>(ch_w2, BP2H, BP2L);
  k_pack5<<<864, 256, 0, stream>>>(rg_tw, hm_tw, BP5H, BP5L);

  // CommonHead
  k_conv1<<<512, 256, 0, stream>>>(FB, FBL, BP1H, BP1L, ch_b1, Y1);
  k_stats<6, false><<<128, 256, 0, stream>>>(Y1, 32768, 256, GSUM + 0, GSQ + 0);
  k_bnfin<<<1, 256, 0, stream>>>(GSUM + 0, GSQ + 0, ch_g1, ch_be1, 1.f / 32768.f, 192,
                                 SC + 0, SH + 0);
  k_conv2<<<128, 256, 0, stream>>>(Y1, BP2H, BP2L, ch_b2, SC + 0, SH + 0, Y2);
  k_stats<6, false><<<32, 256, 0, stream>>>(Y2, 8192, 256, GSUM + 192, GSQ + 192);
  k_bnfin<<<1, 256, 0, stream>>>(GSUM + 192, GSQ + 192, ch_g1, ch_be1, 1.f / 8192.f,
                                 192, SC + 192, SH + 192);
  k_conv3<<<32, 256, 0, stream>>>(Y2, ch_w3, ch_b3, SC + 192, SH + 192, Y3);
  k_stats<1, false><<<8, 256, 0, stream>>>(Y3, 8192, 1024, GSUM + 384, GSQ + 384);
  k_bnfin<<<1, 256, 0, stream>>>(GSUM + 384, GSQ + 384, ch_g2, ch_be2, 1.f / 8192.f,
                                 32, SC + 384, SH + 384);
  // Classify head
  k_clsconv1<<<128, 256, 0, stream>>>(Y3, cl_w1, cl_b1, SC + 384, SH + 384, C1);
  k_stats<1, false><<<8, 256, 0, stream>>>(C1, 8192, 1024, GSUM + 416, GSQ + 416);
  k_bnfin<<<1, 256, 0, stream>>>(GSUM + 416, GSQ + 416, cl_g, cl_be, 1.f / 8192.f, 32,
                                 SC + 416, SH + 416);
  k_cls<<<8, 256, 0, stream>>>(C1, cl_w2, cl_b2, cl_dw, cl_db, SC + 416, SH + 416,
                               CLS);
  // Regression + heatmap (fused convT, 4-class row-pair blocks)
  k_convt<<<1024, 256, 0, stream>>>(FB, FBL, BP5H, BP5L, rg_tb, hm_tb, RR, HM);
  k_stats<1, true><<<256, 256, 0, stream>>>(RR, 524288, 2048, GSUM + 448, GSQ + 448);
  k_bnfin<<<1, 256, 0, stream>>>(GSUM + 448, GSQ + 448, rg_g, rg_be, 1.f / 524288.f,
                                 32, SC + 448, SH + 448);
  k_regconv<<<2048, 256, 0, stream>>>(RR, rg_w, rg_b, SC + 448, SH + 448, REG);
  // Decode
  k_argmax<<<64, 256, 0, stream>>>(HM, IDX);
  k_final<<<1, 64, 0, stream>>>(CLS, IDX, REG, out);
}

// Round 5
// 1269.119 us; speedup vs baseline: 1.3106x; 1.0264x over previous
//
#include <hip/hip_runtime.h>

typedef unsigned short u16;
typedef u16 u16x8 __attribute__((ext_vector_type(8)));
typedef __bf16 bf16x8 __attribute__((ext_vector_type(8)));
typedef float f32x4 __attribute__((ext_vector_type(4)));

__device__ __forceinline__ float bf2f(u16 v) {
  unsigned u = ((unsigned)v) << 16;
  return __builtin_bit_cast(float, u);
}
__device__ __forceinline__ u16 f2bf(float f) {
  unsigned u = __builtin_bit_cast(unsigned, f);
  u += 0x7FFFu + ((u >> 16) & 1u);
  return (u16)(u >> 16);
}
__device__ __forceinline__ float hsw(float v) {
  return v * fminf(fmaxf(v + 3.f, 0.f), 6.f) * (1.f / 6.f);
}
__device__ __forceinline__ f32x4 mfma16(u16x8 a, u16x8 b, f32x4 c) {
  return __builtin_amdgcn_mfma_f32_16x16x32_bf16(
      __builtin_bit_cast(bf16x8, a), __builtin_bit_cast(bf16x8, b), c, 0, 0, 0);
}

#define LR 40  // padded LDS row stride in u16 (80 B), breaks pow2 bank stride

// ---------------------------------------------------------------------------
// K0: feature NCHW fp32 -> NHWC bf16 hi + lo planes
// ---------------------------------------------------------------------------
__global__ __launch_bounds__(256) void k_tobf(const float* __restrict__ f,
                                              u16* __restrict__ fbh,
                                              u16* __restrict__ fbl) {
  __shared__ float tl[64 * 65];
  const int t = threadIdx.x;
  const int bid = blockIdx.x;
  const int ict = bid & 7, xt = (bid >> 3) & 1, y = (bid >> 4) & 127, n = bid >> 11;
  const int x0 = xt * 64, ic0 = ict * 64;
#pragma unroll
  for (int i = 0; i < 16; ++i) {
    const int e = t + i * 256;
    const int icl = e >> 6, xl = e & 63;
    tl[icl * 65 + xl] = f[((n * 512 + ic0 + icl) * 128 + y) * 128 + x0 + xl];
  }
  __syncthreads();
#pragma unroll
  for (int i = 0; i < 16; ++i) {
    const int e = t + i * 256;
    const int xl = e >> 6, icl = e & 63;
    const float v = tl[icl * 65 + xl];
    const u16 h = f2bf(v);
    const size_t idx = ((size_t)((n * 128 + y) * 128 + x0 + xl) << 9) + ic0 + icl;
    fbh[idx] = h;
    fbl[idx] = f2bf(v - bf2f(h));
  }
}

// ---------------------------------------------------------------------------
// Weight prepacks: [tap][icc][oc][ic32] bf16 hi/lo
// ---------------------------------------------------------------------------
__global__ __launch_bounds__(256) void k_pack1(const float* __restrict__ w,
                                               u16* __restrict__ bph,
                                               u16* __restrict__ bpl) {
  const int e = blockIdx.x * 256 + threadIdx.x;  // < 9*16*192*32
  const int ici = e & 31;
  const int rest = e >> 5;
  const int oc = rest % 192;
  const int kc = rest / 192;
  const int icc = kc & 15, tap = kc >> 4;
  const int ic = icc * 32 + ici;
  const float v = w[(oc * 512 + ic) * 9 + tap];
  const u16 h = f2bf(v);
  bph[e] = h;
  bpl[e] = f2bf(v - bf2f(h));
}

__global__ __launch_bounds__(256) void k_pack2(const float* __restrict__ w,
                                               u16* __restrict__ bph,
                                               u16* __restrict__ bpl) {
  const int e = blockIdx.x * 256 + threadIdx.x;  // < 9*6*192*32
  const int ici = e & 31;
  const int rest = e >> 5;
  const int oc = rest % 192;
  const int kc = rest / 192;
  const int icc = kc % 6, tap = kc / 6;
  const int ic = icc * 32 + ici;
  const float v = w[(oc * 192 + ic) * 9 + tap];
  const u16 h = f2bf(v);
  bph[e] = h;
  bpl[e] = f2bf(v - bf2f(h));
}

__global__ __launch_bounds__(256) void k_pack5(const float* __restrict__ rgw,
                                               const float* __restrict__ hmw,
                                               u16* __restrict__ bph,
                                               u16* __restrict__ bpl) {
  const int e = blockIdx.x * 256 + threadIdx.x;  // < 9*16*48*32
  const int ici = e & 31;
  const int rest = e >> 5;
  const int oc = rest % 48;
  const int sic = rest / 48;
  const int icc = sic & 15, slot = sic >> 4;
  const int ic = icc * 32 + ici;
  const int kytab[9] = {1, 1, 1, 2, 0, 2, 2, 0, 0};
  const int kxtab[9] = {1, 2, 0, 1, 1, 2, 0, 2, 0};
  const int ky = kytab[slot], kx = kxtab[slot];
  float v = 0.f;
  if (oc < 32)
    v = rgw[((ic * 32 + oc) * 3 + ky) * 3 + kx];
  else if (oc < 40)
    v = hmw[((ic * 8 + (oc - 32)) * 3 + ky) * 3 + kx];
  const u16 h = f2bf(v);
  bph[e] = h;
  bpl[e] = f2bf(v - bf2f(h));
}

// ---------------------------------------------------------------------------
// K1: conv1 3x3 s2 p1, 512->192, split-bf16 (3x MFMA). y1 fp32 NHWC.
// ---------------------------------------------------------------------------
__global__ __launch_bounds__(256) void k_conv1(const u16* __restrict__ fbh,
                                               const u16* __restrict__ fbl,
                                               const u16* __restrict__ bph,
                                               const u16* __restrict__ bpl,
                                               const float* __restrict__ bias,
                                               float* __restrict__ y1) {
  __shared__ u16 AlH[64 * LR], AlL[64 * LR];
  __shared__ u16 BlH[192 * LR], BlL[192 * LR];
  __shared__ float bl[192];
  const int t = threadIdx.x;
  const int n = blockIdx.x >> 6, oy = blockIdx.x & 63;
  if (t < 192) bl[t] = bias[t];
  const int lane = t & 63, wv = t >> 6;
  const int row = lane & 15, g = lane >> 4;
  const int oxs = t >> 2, icq = t & 3;
  const f32x4 z4 = {0.f, 0.f, 0.f, 0.f};
  f32x4 acc[4][3];
#pragma unroll
  for (int i = 0; i < 4; ++i)
#pragma unroll
    for (int j = 0; j < 3; ++j) acc[i][j] = z4;

  for (int kc = 0; kc < 144; ++kc) {
    const int tap = kc >> 4, icc = kc & 15;
    const int ky = tap / 3, kx = tap - ky * 3;
    const int iy = 2 * oy - 1 + ky;
    const int ix = 2 * oxs - 1 + kx;
    u16x8 avh = {0, 0, 0, 0, 0, 0, 0, 0};
    u16x8 avl = {0, 0, 0, 0, 0, 0, 0, 0};
    if ((unsigned)iy < 128u && (unsigned)ix < 128u) {
      const size_t idx =
          ((size_t)((n * 128 + iy) * 128 + ix) << 9) + icc * 32 + icq * 8;
      avh = *(const u16x8*)&fbh[idx];
      avl = *(const u16x8*)&fbl[idx];
    }
    u16x8 bvh[3], bvl[3];
    const size_t bbase = (size_t)(tap * 16 + icc) * (192 * 32);
#pragma unroll
    for (int i = 0; i < 3; ++i) {
      const int e = t + i * 256;
      const size_t off = bbase + (e >> 2) * 32 + (e & 3) * 8;
      bvh[i] = *(const u16x8*)&bph[off];
      bvl[i] = *(const u16x8*)&bpl[off];
    }
    __syncthreads();
    *(u16x8*)&AlH[oxs * LR + icq * 8] = avh;
    *(u16x8*)&AlL[oxs * LR + icq * 8] = avl;
#pragma unroll
    for (int i = 0; i < 3; ++i) {
      const int e = t + i * 256;
      *(u16x8*)&BlH[(e >> 2) * LR + (e & 3) * 8] = bvh[i];
      *(u16x8*)&BlL[(e >> 2) * LR + (e & 3) * 8] = bvl[i];
    }
    __syncthreads();
    u16x8 afh[4], afl[4], bfh[3], bfl[3];
#pragma unroll
    for (int mf = 0; mf < 4; ++mf) {
      afh[mf] = *(const u16x8*)&AlH[(mf * 16 + row) * LR + g * 8];
      afl[mf] = *(const u16x8*)&AlL[(mf * 16 + row) * LR + g * 8];
    }
#pragma unroll
    for (int nf = 0; nf < 3; ++nf) {
      bfh[nf] = *(const u16x8*)&BlH[(wv * 48 + nf * 16 + row) * LR + g * 8];
      bfl[nf] = *(const u16x8*)&BlL[(wv * 48 + nf * 16 + row) * LR + g * 8];
    }
#pragma unroll
    for (int mf = 0; mf < 4; ++mf)
#pragma unroll
      for (int nf = 0; nf < 3; ++nf) {
        acc[mf][nf] = mfma16(afh[mf], bfh[nf], acc[mf][nf]);
        acc[mf][nf] = mfma16(afh[mf], bfl[nf], acc[mf][nf]);
        acc[mf][nf] = mfma16(afl[mf], bfh[nf], acc[mf][nf]);
      }
  }
#pragma unroll
  for (int mf = 0; mf < 4; ++mf)
#pragma unroll
    for (int nf = 0; nf < 3; ++nf)
#pragma unroll
      for (int r = 0; r < 4; ++r) {
        const int m = mf * 16 + g * 4 + r;
        const int oc = wv * 48 + nf * 16 + row;
        y1[((n * 64 + oy) * 64 + m) * 192 + oc] = acc[mf][nf][r] + bl[oc];
      }
}

// ---------------------------------------------------------------------------
// K2: conv2 3x3 s2 p1, 192->192 on bn1(y1 fp32), split-bf16. y2 fp32 NHWC.
// ---------------------------------------------------------------------------
__global__ __launch_bounds__(256) void k_conv2(const float* __restrict__ y1,
                                               const u16* __restrict__ bph,
                                               const u16* __restrict__ bpl,
                                               const float* __restrict__ bias,
                                               const float* __restrict__ sc,
                                               const float* __restrict__ sh,
                                               float* __restrict__ y2) {
  __shared__ u16 AlH[64 * LR], AlL[64 * LR];
  __shared__ u16 BlH[192 * LR], BlL[192 * LR];
  __shared__ float bl[192], scl[192], shl[192];
  const int t = threadIdx.x;
  const int n = blockIdx.x >> 4, oyp = blockIdx.x & 15;
  if (t < 192) {
    bl[t] = bias[t];
    scl[t] = sc[t];
    shl[t] = sh[t];
  }
  __syncthreads();
  const int lane = t & 63, wv = t >> 6;
  const int row = lane & 15, g = lane >> 4;
  const int ms = t >> 2, icq = t & 3;
  const int ryr = ms >> 5, oxs = ms & 31;
  const f32x4 z4 = {0.f, 0.f, 0.f, 0.f};
  f32x4 acc[4][3];
#pragma unroll
  for (int i = 0; i < 4; ++i)
#pragma unroll
    for (int j = 0; j < 3; ++j) acc[i][j] = z4;

  for (int kc = 0; kc < 54; ++kc) {
    const int tap = kc / 6, icc = kc - tap * 6;
    const int ky = tap / 3, kx = tap - ky * 3;
    const int iy = 2 * (oyp * 2 + ryr) - 1 + ky;
    const int ix = 2 * oxs - 1 + kx;
    u16x8 avh = {0, 0, 0, 0, 0, 0, 0, 0};
    u16x8 avl = {0, 0, 0, 0, 0, 0, 0, 0};
    if ((unsigned)iy < 64u && (unsigned)ix < 64u) {
      const int icb = icc * 32 + icq * 8;
      const float* base = &y1[((n * 64 + iy) * 64 + ix) * 192 + icb];
      const f32x4 r0 = *(const f32x4*)base;
      const f32x4 r1 = *(const f32x4*)(base + 4);
#pragma unroll
      for (int j = 0; j < 8; ++j) {
        const float r = (j < 4) ? r0[j & 3] : r1[j & 3];
        const float v = r * scl[icb + j] + shl[icb + j];
        const u16 h = f2bf(v);
        avh[j] = h;
        avl[j] = f2bf(v - bf2f(h));
      }
    }
    u16x8 bvh[3], bvl[3];
    const size_t bbase = (size_t)(tap * 6 + icc) * (192 * 32);
#pragma unroll
    for (int i = 0; i < 3; ++i) {
      const int e = t + i * 256;
      const size_t off = bbase + (e >> 2) * 32 + (e & 3) * 8;
      bvh[i] = *(const u16x8*)&bph[off];
      bvl[i] = *(const u16x8*)&bpl[off];
    }
    __syncthreads();
    *(u16x8*)&AlH[ms * LR + icq * 8] = avh;
    *(u16x8*)&AlL[ms * LR + icq * 8] = avl;
#pragma unroll
    for (int i = 0; i < 3; ++i) {
      const int e = t + i * 256;
      *(u16x8*)&BlH[(e >> 2) * LR + (e & 3) * 8] = bvh[i];
      *(u16x8*)&BlL[(e >> 2) * LR + (e & 3) * 8] = bvl[i];
    }
    __syncthreads();
    u16x8 afh[4], afl[4], bfh[3], bfl[3];
#pragma unroll
    for (int mf = 0; mf < 4; ++mf) {
      afh[mf] = *(const u16x8*)&AlH[(mf * 16 + row) * LR + g * 8];
      afl[mf] = *(const u16x8*)&AlL[(mf * 16 + row) * LR + g * 8];
    }
#pragma unroll
    for (int nf = 0; nf < 3; ++nf) {
      bfh[nf] = *(const u16x8*)&BlH[(wv * 48 + nf * 16 + row) * LR + g * 8];
      bfl[nf] = *(const u16x8*)&BlL[(wv * 48 + nf * 16 + row) * LR + g * 8];
    }
#pragma unroll
    for (int mf = 0; mf < 4; ++mf)
#pragma unroll
      for (int nf = 0; nf < 3; ++nf) {
        acc[mf][nf] = mfma16(afh[mf], bfh[nf], acc[mf][nf]);
        acc[mf][nf] = mfma16(afh[mf], bfl[nf], acc[mf][nf]);
        acc[mf][nf] = mfma16(afl[mf], bfh[nf], acc[mf][nf]);
      }
  }
#pragma unroll
  for (int mf = 0; mf < 4; ++mf)
#pragma unroll
    for (int nf = 0; nf < 3; ++nf)
#pragma unroll
      for (int r = 0; r < 4; ++r) {
        const int m = mf * 16 + g * 4 + r;
        const int oy = oyp * 2 + (m >> 5), ox = m & 31;
        const int oc = wv * 48 + nf * 16 + row;
        y2[((n * 32 + oy) * 32 + ox) * 192 + oc] = acc[mf][nf][r] + bl[oc];
      }
}

// ---------------------------------------------------------------------------
// K5 v3: fused ConvT. Block = (n, input row pair iyb), all 4 parity classes.
// A-hi, A-lo AND B-hi staged in LDS per ic-chunk (76 KB, 2 blocks/CU);
// inner loop is pure LDS b128 + MFMA (90 MFMA per barrier pair per wave).
// Only bfl2 (hm-split B-lo, 9 coalesced loads/wave/K-step) stays global.
// ---------------------------------------------------------------------------
#define AST 40           // px stride in u16 (80 B)
#define ARS (130 * 40)   // per-row plane stride in u16
#define BST 40           // oc stride in u16
__global__ __launch_bounds__(256) void k_convt(const u16* __restrict__ fbh,
                                               const u16* __restrict__ fbl,
                                               const u16* __restrict__ bph,
                                               const u16* __restrict__ bpl,
                                               const float* __restrict__ rgb,
                                               const float* __restrict__ hmb,
                                               u16* __restrict__ rr,
                                               float* __restrict__ hm) {
  __shared__ u16 AH[2 * ARS];       // 20.8 KB
  __shared__ u16 AL[2 * ARS];       // 20.8 KB
  __shared__ u16 BH[9 * 48 * BST];  // 34.6 KB
  const int t = threadIdx.x;
  const int n = blockIdx.x >> 7, iyb = blockIdx.x & 127;
  const int lane = t & 63, wv = t >> 6;
  const int row = lane & 15, g = lane >> 4;

  // zero the px=128 halo column in both A planes (never rewritten)
  if (t < 16) {
    const int pl = t >> 3, r = (t >> 2) & 1, j = t & 3;
    const u16x8 z = {0, 0, 0, 0, 0, 0, 0, 0};
    u16* P = pl ? AL : AH;
    *(u16x8*)&P[r * ARS + 128 * AST + j * 8] = z;
  }

  // per-lane bias for the 3 N-fragments (oc = nf*16 + row)
  float bias3[3];
#pragma unroll
  for (int nf = 0; nf < 3; ++nf) {
    const int oc = nf * 16 + row;
    bias3[nf] = (oc < 32) ? rgb[oc] : ((oc < 40) ? hmb[oc - 32] : 0.f);
  }

  // slot -> (class, diy, dix); class 0: oy even/ox even ... 3: odd/odd
  const int SCt[9] = {0, 1, 1, 2, 2, 3, 3, 3, 3};
  const int SDt[9] = {0, 0, 0, 0, 1, 0, 0, 1, 1};
  const int SXt[9] = {0, 0, 1, 0, 0, 0, 1, 0, 1};

  const f32x4 z4 = {0.f, 0.f, 0.f, 0.f};
  f32x4 acc[4][2][3];
#pragma unroll
  for (int c = 0; c < 4; ++c)
#pragma unroll
    for (int m = 0; m < 2; ++m)
#pragma unroll
      for (int j = 0; j < 3; ++j) acc[c][m][j] = z4;

  for (int icc = 0; icc < 16; ++icc) {
    // ---- prefetch A-hi/A-lo (4 chunks each) + B-hi (7 chunks) to regs ----
    u16x8 ah[4], al[4], bh[7];
    int rr_[4], px_[4], iq_[4];
#pragma unroll
    for (int i = 0; i < 4; ++i) {
      const int u = t + i * 256;
      const int r = u >> 9, px = (u >> 2) & 127, icq = u & 3;
      rr_[i] = r; px_[i] = px; iq_[i] = icq;
      const int iy = iyb + r;
      u16x8 vh = {0, 0, 0, 0, 0, 0, 0, 0};
      u16x8 vl = {0, 0, 0, 0, 0, 0, 0, 0};
      if (iy < 128) {
        const size_t idx =
            ((size_t)((n * 128 + iy) * 128 + px) << 9) + icc * 32 + icq * 8;
        vh = *(const u16x8*)&fbh[idx];
        vl = *(const u16x8*)&fbl[idx];
      }
      ah[i] = vh;
      al[i] = vl;
    }
#pragma unroll
    for (int i = 0; i < 7; ++i) {
      const int e = t + i * 256;  // < 9*48*4 = 1728
      u16x8 v = {0, 0, 0, 0, 0, 0, 0, 0};
      if (e < 1728) {
        const int slot = e / 192, rem = e % 192;
        const int oc = rem >> 2, icq = rem & 3;
        v = *(const u16x8*)&bph[((size_t)((slot * 16 + icc) * 48 + oc) << 5) +
                                icq * 8];
      }
      bh[i] = v;
    }
    __syncthreads();
#pragma unroll
    for (int i = 0; i < 4; ++i) {
      *(u16x8*)&AH[rr_[i] * ARS + px_[i] * AST + iq_[i] * 8] = ah[i];
      *(u16x8*)&AL[rr_[i] * ARS + px_[i] * AST + iq_[i] * 8] = al[i];
    }
#pragma unroll
    for (int i = 0; i < 7; ++i) {
      const int e = t + i * 256;
      if (e < 1728) {
        const int slot = e / 192, rem = e % 192;
        const int oc = rem >> 2, icq = rem & 3;
        *(u16x8*)&BH[(slot * 48 + oc) * BST + icq * 8] = bh[i];
      }
    }
    __syncthreads();

    // ---- 9 taps x 2 M-frags per wave; all hi operands from LDS ----
#pragma unroll
    for (int slot = 0; slot < 9; ++slot) {
      const int cls = SCt[slot], diy = SDt[slot], dix = SXt[slot];
      const u16x8 bfh0 = *(const u16x8*)&BH[(slot * 48 + row) * BST + g * 8];
      const u16x8 bfh1 = *(const u16x8*)&BH[(slot * 48 + 16 + row) * BST + g * 8];
      const u16x8 bfh2 = *(const u16x8*)&BH[(slot * 48 + 32 + row) * BST + g * 8];
      const u16x8 bfl2 = *(const u16x8*)&bpl[(size_t)((slot * 16 + icc) * 48 +
                                                      32 + row) * 32 + g * 8];
#pragma unroll
      for (int mfl = 0; mfl < 2; ++mfl) {
        const int mf = wv * 2 + mfl;
        const int aoff = diy * ARS + (mf * 16 + row + dix) * AST + g * 8;
        const u16x8 afh = *(const u16x8*)&AH[aoff];
        const u16x8 afl = *(const u16x8*)&AL[aoff];
        acc[cls][mfl][0] = mfma16(afh, bfh0, acc[cls][mfl][0]);
        acc[cls][mfl][1] = mfma16(afh, bfh1, acc[cls][mfl][1]);
        acc[cls][mfl][2] = mfma16(afh, bfh2, acc[cls][mfl][2]);
        acc[cls][mfl][2] = mfma16(afh, bfl2, acc[cls][mfl][2]);
        acc[cls][mfl][2] = mfma16(afl, bfh2, acc[cls][mfl][2]);
      }
    }
  }

  // ---- epilogue ----
#pragma unroll
  for (int cls = 0; cls < 4; ++cls) {
    const int oy = 2 * iyb + (cls >> 1);
    const int xp = cls & 1;
#pragma unroll
    for (int mfl = 0; mfl < 2; ++mfl)
#pragma unroll
      for (int nf = 0; nf < 3; ++nf)
#pragma unroll
        for (int r = 0; r < 4; ++r) {
          const int m = (wv * 2 + mfl) * 16 + g * 4 + r;
          const int ox = 2 * m + xp;
          const int oc = nf * 16 + row;
          const float v = acc[cls][mfl][nf][r] + bias3[nf];
          if (oc < 32)
            rr[((size_t)((n * 256 + oy) * 256 + ox)) * 32 + oc] = f2bf(v);
          else if (oc < 40)
            hm[(size_t)(n * 8 + (oc - 32)) * 65536 + oy * 256 + ox] = v;
        }
  }
}

// ---------------------------------------------------------------------------
// Generic per-channel sum/sumsq over [M][C] (C = CG*32)
// ---------------------------------------------------------------------------
template <int CG, bool BF16>
__global__ __launch_bounds__(256) void k_stats(const void* __restrict__ in_, int M,
                                               int PB, float* __restrict__ gsum,
                                               float* __restrict__ gsq) {
  const int C = CG * 32;
  __shared__ float red[8][CG * 32];
  const int t = threadIdx.x;
  const int pg = t >> 5, ln = t & 31;
  float s[CG], q[CG];
#pragma unroll
  for (int c = 0; c < CG; ++c) { s[c] = 0.f; q[c] = 0.f; }
  const int p0 = blockIdx.x * PB;
  const int pend = min(p0 + PB, M);
  for (int p = p0 + pg; p < pend; p += 8) {
#pragma unroll
    for (int c = 0; c < CG; ++c) {
      float v;
      if (BF16)
        v = bf2f(((const u16*)in_)[(size_t)p * C + c * 32 + ln]);
      else
        v = ((const float*)in_)[(size_t)p * C + c * 32 + ln];
      s[c] += v;
      q[c] += v * v;
    }
  }
#pragma unroll
  for (int c = 0; c < CG; ++c) red[pg][c * 32 + ln] = s[c];
  __syncthreads();
  if (t < C) {
    float tot = 0.f;
#pragma unroll
    for (int k = 0; k < 8; ++k) tot += red[k][t];
    atomicAdd(&gsum[t], tot);
  }
  __syncthreads();
#pragma unroll
  for (int c = 0; c < CG; ++c) red[pg][c * 32 + ln] = q[c];
  __syncthreads();
  if (t < C) {
    float tot = 0.f;
#pragma unroll
    for (int k = 0; k < 8; ++k) tot += red[k][t];
    atomicAdd(&gsq[t], tot);
  }
}

__global__ void k_bnfin(const float* __restrict__ gsum, const float* __restrict__ gsq,
                        const float* __restrict__ g, const float* __restrict__ be,
                        float invM, int C, float* __restrict__ sc,
                        float* __restrict__ sh) {
  const int t = threadIdx.x;
  if (t < C) {
    const float m = gsum[t] * invM;
    const float var = gsq[t] * invM - m * m;
    const float inv = rsqrtf(var + 1e-5f);
    const float s = g[t] * inv;
    sc[t] = s;
    sh[t] = be[t] - m * s;
  }
}

// ---------------------------------------------------------------------------
// K3: conv3 1x1 192->32 on bn(y2 fp32). y3 fp32 [8192][32].
// ---------------------------------------------------------------------------
__global__ __launch_bounds__(256) void k_conv3(const float* __restrict__ y2,
                                               const float* __restrict__ w3,
                                               const float* __restrict__ b3,
                                               const float* __restrict__ sc,
                                               const float* __restrict__ sh,
                                               float* __restrict__ y3) {
  __shared__ float wl[32 * 192];
  __shared__ float scl[192], shl[192];
  const int t = threadIdx.x;
  for (int e = t; e < 6144; e += 256) wl[e] = w3[e];
  if (t < 192) {
    scl[t] = sc[t];
    shl[t] = sh[t];
  }
  __syncthreads();
  const int px = blockIdx.x * 256 + t;
  float acc[32];
#pragma unroll
  for (int oc = 0; oc < 32; ++oc) acc[oc] = 0.f;
  const float* base = &y2[(size_t)px * 192];
  for (int icb = 0; icb < 192; icb += 8) {
    const f32x4 r0 = *(const f32x4*)&base[icb];
    const f32x4 r1 = *(const f32x4*)&base[icb + 4];
    float v[8];
#pragma unroll
    for (int j = 0; j < 8; ++j) {
      const float r = (j < 4) ? r0[j & 3] : r1[j & 3];
      v[j] = r * scl[icb + j] + shl[icb + j];
    }
#pragma unroll
    for (int oc = 0; oc < 32; ++oc) {
      const f32x4 w0 = *(const f32x4*)&wl[oc * 192 + icb];
      const f32x4 w1 = *(const f32x4*)&wl[oc * 192 + icb + 4];
      acc[oc] += v[0] * w0[0] + v[1] * w0[1] + v[2] * w0[2] + v[3] * w0[3] +
                 v[4] * w1[0] + v[5] * w1[1] + v[6] * w1[2] + v[7] * w1[3];
    }
  }
#pragma unroll
  for (int oc = 0; oc < 32; ++oc) y3[(size_t)px * 32 + oc] = acc[oc] + b3[oc];
}

// ---------------------------------------------------------------------------
// K4: classify conv 3x3 p1, 32->32 on hsw(bn2(y3))
// ---------------------------------------------------------------------------
__global__ __launch_bounds__(256) void k_clsconv1(const float* __restrict__ y3,
                                                  const float* __restrict__ w1,
                                                  const float* __restrict__ b1,
                                                  const float* __restrict__ sc,
                                                  const float* __restrict__ sh,
                                                  float* __restrict__ c1) {
  __shared__ float wl[9216];  // [ic][tap][oc]
  __shared__ float scl[32], shl[32];
  const int t = threadIdx.x;
  for (int e = t; e < 9216; e += 256) {
    const int oc = e & 31;
    const int tmp = e >> 5;
    const int tap = tmp % 9, ic = tmp / 9;
    wl[e] = w1[(oc * 32 + ic) * 9 + tap];
  }
  if (t < 32) {
    scl[t] = sc[t];
    shl[t] = sh[t];
  }
  __syncthreads();
  const int px = blockIdx.x * 64 + (t & 63);
  const int ocg = t >> 6;
  const int n = px >> 10, y0 = (px >> 5) & 31, x0 = px & 31;
  float acc[8];
#pragma unroll
  for (int j = 0; j < 8; ++j) acc[j] = 0.f;
  for (int tap = 0; tap < 9; ++tap) {
    const int dy = tap / 3 - 1, dx = tap % 3 - 1;
    const int yy = y0 + dy, xx = x0 + dx;
    if ((unsigned)yy < 32u && (unsigned)xx < 32u) {
      const float* ib = &y3[((n << 10) + yy * 32 + xx) * 32];
      for (int ic = 0; ic < 32; ++ic) {
        const float v = hsw(ib[ic] * scl[ic] + shl[ic]);
        const float* wp = &wl[(ic * 9 + tap) * 32 + ocg * 8];
#pragma unroll
        for (int j = 0; j < 8; ++j) acc[j] += v * wp[j];
      }
    }
  }
#pragma unroll
  for (int j = 0; j < 8; ++j) c1[px * 32 + ocg * 8 + j] = acc[j] + b1[ocg * 8 + j];
}

// ---------------------------------------------------------------------------
// K4c: c2 = conv3x3(hsw(bn(c1))) 32->1, then cls[n,k] = c2 . dw[k] + db[k]
// ---------------------------------------------------------------------------
__global__ __launch_bounds__(256) void k_cls(const float* __restrict__ c1,
                                             const float* __restrict__ w2,
                                             const float* __restrict__ b2,
                                             const float* __restrict__ dw,
                                             const float* __restrict__ db,
                                             const float* __restrict__ sc,
                                             const float* __restrict__ sh,
                                             float* __restrict__ cls) {
  __shared__ float wl[288];
  __shared__ float scl[32], shl[32];
  __shared__ float red0[256], red1[256];
  const int t = threadIdx.x;
  const int n = blockIdx.x;
  for (int e = t; e < 288; e += 256) wl[e] = w2[e];
  if (t < 32) {
    scl[t] = sc[t];
    shl[t] = sh[t];
  }
  __syncthreads();
  float s0 = 0.f, s1 = 0.f;
  for (int i = 0; i < 4; ++i) {
    const int px = i * 256 + t;
    const int y0 = px >> 5, x0 = px & 31;
    float c2 = b2[0];
    for (int tap = 0; tap < 9; ++tap) {
      const int dy = tap / 3 - 1, dx = tap % 3 - 1;
      const int yy = y0 + dy, xx = x0 + dx;
      if ((unsigned)yy < 32u && (unsigned)xx < 32u) {
        const float* ib = &c1[((n << 10) + yy * 32 + xx) * 32];
        for (int ic = 0; ic < 32; ++ic)
          c2 += hsw(ib[ic] * scl[ic] + shl[ic]) * wl[ic * 9 + tap];
      }
    }
    s0 += c2 * dw[px];
    s1 += c2 * dw[1024 + px];
  }
  red0[t] = s0;
  red1[t] = s1;
  __syncthreads();
  for (int s = 128; s; s >>= 1) {
    if (t < s) {
      red0[t] += red0[t + s];
      red1[t] += red1[t + s];
    }
    __syncthreads();
  }
  if (t == 0) {
    cls[n * 2 + 0] = red0[0] + db[0];
    cls[n * 2 + 1] = red1[0] + db[1];
  }
}

// ---------------------------------------------------------------------------
// K6: reg = conv3x3 p1 (hsw(bn(rr))) 32->2, fp32 NCHW [8,2,256,256]
// ---------------------------------------------------------------------------
__global__ __launch_bounds__(256) void k_regconv(const u16* __restrict__ rr,
                                                 const float* __restrict__ w,
                                                 const float* __restrict__ b,
                                                 const float* __restrict__ sc,
                                                 const float* __restrict__ sh,
                                                 float* __restrict__ reg) {
  __shared__ u16 rl[3 * 258 * 33];
  __shared__ float wl[576];
  __shared__ float scl[32], shl[32];
  const int t = threadIdx.x;
  const int n = blockIdx.x >> 8, oy = blockIdx.x & 255;
  for (int e = t; e < 576; e += 256) wl[e] = w[e];
  if (t < 32) {
    scl[t] = sc[t];
    shl[t] = sh[t];
  }
  if (t < 192) {
    const int ry = t / 64, side = (t >> 5) & 1, ic = t & 31;
    rl[(ry * 258 + side * 257) * 33 + ic] = 0;
  }
  __syncthreads();
  for (int e = t; e < 3072; e += 256) {
    const int icq8 = e & 3;
    const int pxx = (e >> 2) & 255;
    const int ry = e >> 10;
    const int rowi = oy - 1 + ry;
    u16x8 raw = {0, 0, 0, 0, 0, 0, 0, 0};
    bool ok = (unsigned)rowi < 256u;
    if (ok)
      raw = *(const u16x8*)&rr[((size_t)((n * 256 + rowi) * 256 + pxx)) * 32 + icq8 * 8];
#pragma unroll
    for (int j = 0; j < 8; ++j) {
      const int ic = icq8 * 8 + j;
      float v = 0.f;
      if (ok) v = hsw(bf2f(raw[j]) * scl[ic] + shl[ic]);
      rl[(ry * 258 + pxx + 1) * 33 + ic] = f2bf(v);
    }
  }
  __syncthreads();
  const int px = t;
  float a0 = b[0], a1 = b[1];
#pragma unroll
  for (int ry = 0; ry < 3; ++ry)
#pragma unroll
    for (int kx = 0; kx < 3; ++kx) {
      const u16* ib = &rl[(ry * 258 + px + kx) * 33];
      for (int ic = 0; ic < 32; ++ic) {
        const float v = bf2f(ib[ic]);
        a0 += v * wl[ic * 9 + ry * 3 + kx];
        a1 += v * wl[288 + ic * 9 + ry * 3 + kx];
      }
    }
  reg[(n * 2 + 0) * 65536 + oy * 256 + px] = a0;
  reg[(n * 2 + 1) * 65536 + oy * 256 + px] = a1;
}

// ---------------------------------------------------------------------------
// K7: per (n, ch) spatial argmax, lowest-index tie-break
// ---------------------------------------------------------------------------
__global__ __launch_bounds__(256) void k_argmax(const float* __restrict__ hm,
                                                int* __restrict__ idx) {
  __shared__ float bv[256];
  __shared__ int bi[256];
  const int t = threadIdx.x;
  const float* base = &hm[(size_t)blockIdx.x * 65536];
  float best = -3.402823466e38f;
  int bidx = 2147483647;
  for (int i = t; i < 65536; i += 256) {
    const float v = base[i];
    if (v > best) {
      best = v;
      bidx = i;
    }
  }
  bv[t] = best;
  bi[t] = bidx;
  __syncthreads();
  for (int s = 128; s; s >>= 1) {
    if (t < s) {
      if (bv[t + s] > bv[t] || (bv[t + s] == bv[t] && bi[t + s] < bi[t])) {
        bv[t] = bv[t + s];
        bi[t] = bi[t + s];
      }
    }
    __syncthreads();
  }
  if (t == 0) idx[blockIdx.x] = bi[0];
}

// ---------------------------------------------------------------------------
// K8: decode -> out [8,2,9]
// ---------------------------------------------------------------------------
__global__ void k_final(const float* __restrict__ cls, const int* __restrict__ idx,
                        const float* __restrict__ reg, float* __restrict__ out) {
  const int t = threadIdx.x;
  if (t >= 16) return;
  const int n = t >> 1, p = t & 1;
  const float cv = cls[n * 2 + p];
  float* o = &out[(n * 2 + p) * 9];
  if (!(cv > 0.6f)) {
    for (int i = 0; i < 9; ++i) o[i] = -1.f;
    return;
  }
  o[0] = (float)p;
  for (int c = 0; c < 4; ++c) {
    const int id = idx[n * 8 + p * 4 + c];
    const int yi = id >> 8, xi = id & 255;
    const float ox_ = reg[(n * 2 + 0) * 65536 + id];
    const float oy_ = reg[(n * 2 + 1) * 65536 + id];
    o[1 + c] = fminf(fmaxf((ox_ + (float)xi) * (1.f / 256.f), 0.f), 1.f);
    o[5 + c] = fminf(fmaxf((oy_ + (float)yi) * (1.f / 256.f), 0.f), 1.f);
  }
}

// ---------------------------------------------------------------------------
extern "C" void kernel_launch(void* const* d_in, const int* in_sizes, int n_in,
                              void* d_out, int out_size, void* d_ws, size_t ws_size,
                              hipStream_t stream) {
  const float* feature = (const float*)d_in[0];
  const float* ch_w1 = (const float*)d_in[1];
  const float* ch_b1 = (const float*)d_in[2];
  const float* ch_w2 = (const float*)d_in[3];
  const float* ch_b2 = (const float*)d_in[4];
  const float* ch_w3 = (const float*)d_in[5];
  const float* ch_b3 = (const float*)d_in[6];
  const float* ch_g1 = (const float*)d_in[7];
  const float* ch_be1 = (const float*)d_in[8];
  const float* ch_g2 = (const float*)d_in[9];
  const float* ch_be2 = (const float*)d_in[10];
  const float* cl_w1 = (const float*)d_in[11];
  const float* cl_b1 = (const float*)d_in[12];
  const float* cl_w2 = (const float*)d_in[13];
  const float* cl_b2 = (const float*)d_in[14];
  const float* cl_g = (const float*)d_in[15];
  const float* cl_be = (const float*)d_in[16];
  const float* cl_dw = (const float*)d_in[17];
  const float* cl_db = (const float*)d_in[18];
  const float* rg_tw = (const float*)d_in[19];
  const float* rg_tb = (const float*)d_in[20];
  const float* rg_g = (const float*)d_in[21];
  const float* rg_be = (const float*)d_in[22];
  const float* rg_w = (const float*)d_in[23];
  const float* rg_b = (const float*)d_in[24];
  const float* hm_tw = (const float*)d_in[25];
  const float* hm_tb = (const float*)d_in[26];
  float* out = (float*)d_out;

  char* w = (char*)d_ws;
  const size_t OFF_FB = 0;                  // 134217728
  const size_t OFF_FBL = 134217728;         // 134217728
  const size_t OFF_BP1H = 268435456;        // 1769472
  const size_t OFF_BP1L = 270204928;        // 1769472
  const size_t OFF_BP2H = 271974400;        // 663552
  const size_t OFF_BP2L = 272637952;        // 663552
  const size_t OFF_BP5H = 273301504;        // 442368
  const size_t OFF_BP5L = 273743872;        // 442368
  const size_t OFF_Y1 = 274186240;          // 25165824 (fp32)
  const size_t OFF_Y2 = 299352064;          // 6291456  (fp32)
  const size_t OFF_Y3 = 305643520;          // 1048576
  const size_t OFF_C1 = 306692096;          // 1048576
  const size_t OFF_RR = 307740672;          // 33554432
  const size_t OFF_HM = 341295104;          // 16777216
  const size_t OFF_REG = 358072320;         // 4194304
  const size_t OFF_STATS = 362266624;       // 3840
  const size_t OFF_PARAMS = 362270464;      // 3840
  const size_t OFF_CLS = 362274304;         // 64
  const size_t OFF_IDX = 362274368;         // 256
  const size_t WS_NEED = 362274624;
  if (ws_size < WS_NEED) return;

  u16* FB = (u16*)(w + OFF_FB);
  u16* FBL = (u16*)(w + OFF_FBL);
  u16* BP1H = (u16*)(w + OFF_BP1H);
  u16* BP1L = (u16*)(w + OFF_BP1L);
  u16* BP2H = (u16*)(w + OFF_BP2H);
  u16* BP2L = (u16*)(w + OFF_BP2L);
  u16* BP5H = (u16*)(w + OFF_BP5H);
  u16* BP5L = (u16*)(w + OFF_BP5L);
  float* Y1 = (float*)(w + OFF_Y1);
  float* Y2 = (float*)(w + OFF_Y2);
  float* Y3 = (float*)(w + OFF_Y3);
  float* C1 = (float*)(w + OFF_C1);
  u16* RR = (u16*)(w + OFF_RR);
  float* HM = (float*)(w + OFF_HM);
  float* REG = (float*)(w + OFF_REG);
  float* GSUM = (float*)(w + OFF_STATS);
  float* GSQ = GSUM + 480;
  float* SC = (float*)(w + OFF_PARAMS);
  float* SH = SC + 480;
  float* CLS = (float*)(w + OFF_CLS);
  int* IDX = (int*)(w + OFF_IDX);

  (void)hipMemsetAsync(w + OFF_STATS, 0, 3840, stream);

  k_tobf<<<16384, 256, 0, stream>>>(feature, FB, FBL);
  k_pack1<<<3456, 256, 0, stream>>>(ch_w1, BP1H, BP1L);
  k_pack2<<<1296, 256, 0, stream>>>(ch_w2, BP2H, BP2L);
  k_pack5<<<864, 256, 0, stream>>>(rg_tw, hm_tw, BP5H, BP5L);

  // CommonHead
  k_conv1<<<512, 256, 0, stream>>>(FB, FBL, BP1H, BP1L, ch_b1, Y1);
  k_stats<6, false><<<128, 256, 0, stream>>>(Y1, 32768, 256, GSUM + 0, GSQ + 0);
  k_bnfin<<<1, 256, 0, stream>>>(GSUM + 0, GSQ + 0, ch_g1, ch_be1, 1.f / 32768.f, 192,
                                 SC + 0, SH + 0);
  k_conv2<<<128, 256, 0, stream>>>(Y1, BP2H, BP2L, ch_b2, SC + 0, SH + 0, Y2);
  k_stats<6, false><<<32, 256, 0, stream>>>(Y2, 8192, 256, GSUM + 192, GSQ + 192);
  k_bnfin<<<1, 256, 0, stream>>>(GSUM + 192, GSQ + 192, ch_g1, ch_be1, 1.f / 8192.f,
                                 192, SC + 192, SH + 192);
  k_conv3<<<32, 256, 0, stream>>>(Y2, ch_w3, ch_b3, SC + 192, SH + 192, Y3);
  k_stats<1, false><<<8, 256, 0, stream>>>(Y3, 8192, 1024, GSUM + 384, GSQ + 384);
  k_bnfin<<<1, 256, 0, stream>>>(GSUM + 384, GSQ + 384, ch_g2, ch_be2, 1.f / 8192.f,
                                 32, SC + 384, SH + 384);
  // Classify head
  k_clsconv1<<<128, 256, 0, stream>>>(Y3, cl_w1, cl_b1, SC + 384, SH + 384, C1);
  k_stats<1, false><<<8, 256, 0, stream>>>(C1, 8192, 1024, GSUM + 416, GSQ + 416);
  k_bnfin<<<1, 256, 0, stream>>>(GSUM + 416, GSQ + 416, cl_g, cl_be, 1.f / 8192.f, 32,
                                 SC + 416, SH + 416);
  k_cls<<<8, 256, 0, stream>>>(C1, cl_w2, cl_b2, cl_dw, cl_db, SC + 416, SH + 416,
                               CLS);
  // Regression + heatmap (fused convT v3: LDS-staged A+B)
  k_convt<<<1024, 256, 0, stream>>>(FB, FBL, BP5H, BP5L, rg_tb, hm_tb, RR, HM);
  k_stats<1, true><<<256, 256, 0, stream>>>(RR, 524288, 2048, GSUM + 448, GSQ + 448);
  k_bnfin<<<1, 256, 0, stream>>>(GSUM + 448, GSQ + 448, rg_g, rg_be, 1.f / 524288.f,
                                 32, SC + 448, SH + 448);
  k_regconv<<<2048, 256, 0, stream>>>(RR, rg_w, rg_b, SC + 448, SH + 448, REG);
  // Decode
  k_argmax<<<64, 256, 0, stream>>>(HM, IDX);
  k_final<<<1, 64, 0, stream>>>(CLS, IDX, REG, out);
}

// Round 6
// 1237.156 us; speedup vs baseline: 1.3445x; 1.0258x over previous
//
#include <hip/hip_runtime.h>

typedef unsigned short u16;
typedef u16 u16x8 __attribute__((ext_vector_type(8)));
typedef __bf16 bf16x8 __attribute__((ext_vector_type(8)));
typedef float f32x4 __attribute__((ext_vector_type(4)));

__device__ __forceinline__ float bf2f(u16 v) {
  unsigned u = ((unsigned)v) << 16;
  return __builtin_bit_cast(float, u);
}
__device__ __forceinline__ u16 f2bf(float f) {
  unsigned u = __builtin_bit_cast(unsigned, f);
  u += 0x7FFFu + ((u >> 16) & 1u);
  return (u16)(u >> 16);
}
__device__ __forceinline__ float hsw(float v) {
  return v * fminf(fmaxf(v + 3.f, 0.f), 6.f) * (1.f / 6.f);
}
__device__ __forceinline__ f32x4 mfma16(u16x8 a, u16x8 b, f32x4 c) {
  return __builtin_amdgcn_mfma_f32_16x16x32_bf16(
      __builtin_bit_cast(bf16x8, a), __builtin_bit_cast(bf16x8, b), c, 0, 0, 0);
}

#define LR 40  // padded LDS row stride in u16 (80 B), breaks pow2 bank stride

// ---------------------------------------------------------------------------
// K0: feature NCHW fp32 -> NHWC bf16 hi + lo planes
// ---------------------------------------------------------------------------
__global__ __launch_bounds__(256) void k_tobf(const float* __restrict__ f,
                                              u16* __restrict__ fbh,
                                              u16* __restrict__ fbl) {
  __shared__ float tl[64 * 65];
  const int t = threadIdx.x;
  const int bid = blockIdx.x;
  const int ict = bid & 7, xt = (bid >> 3) & 1, y = (bid >> 4) & 127, n = bid >> 11;
  const int x0 = xt * 64, ic0 = ict * 64;
#pragma unroll
  for (int i = 0; i < 16; ++i) {
    const int e = t + i * 256;
    const int icl = e >> 6, xl = e & 63;
    tl[icl * 65 + xl] = f[((n * 512 + ic0 + icl) * 128 + y) * 128 + x0 + xl];
  }
  __syncthreads();
#pragma unroll
  for (int i = 0; i < 16; ++i) {
    const int e = t + i * 256;
    const int xl = e >> 6, icl = e & 63;
    const float v = tl[icl * 65 + xl];
    const u16 h = f2bf(v);
    const size_t idx = ((size_t)((n * 128 + y) * 128 + x0 + xl) << 9) + ic0 + icl;
    fbh[idx] = h;
    fbl[idx] = f2bf(v - bf2f(h));
  }
}

// ---------------------------------------------------------------------------
// Weight prepacks: [tap][icc][oc][ic32] bf16 hi/lo
// ---------------------------------------------------------------------------
__global__ __launch_bounds__(256) void k_pack1(const float* __restrict__ w,
                                               u16* __restrict__ bph,
                                               u16* __restrict__ bpl) {
  const int e = blockIdx.x * 256 + threadIdx.x;  // < 9*16*192*32
  const int ici = e & 31;
  const int rest = e >> 5;
  const int oc = rest % 192;
  const int kc = rest / 192;
  const int icc = kc & 15, tap = kc >> 4;
  const int ic = icc * 32 + ici;
  const float v = w[(oc * 512 + ic) * 9 + tap];
  const u16 h = f2bf(v);
  bph[e] = h;
  bpl[e] = f2bf(v - bf2f(h));
}

__global__ __launch_bounds__(256) void k_pack2(const float* __restrict__ w,
                                               u16* __restrict__ bph,
                                               u16* __restrict__ bpl) {
  const int e = blockIdx.x * 256 + threadIdx.x;  // < 9*6*192*32
  const int ici = e & 31;
  const int rest = e >> 5;
  const int oc = rest % 192;
  const int kc = rest / 192;
  const int icc = kc % 6, tap = kc / 6;
  const int ic = icc * 32 + ici;
  const float v = w[(oc * 192 + ic) * 9 + tap];
  const u16 h = f2bf(v);
  bph[e] = h;
  bpl[e] = f2bf(v - bf2f(h));
}

__global__ __launch_bounds__(256) void k_pack5(const float* __restrict__ rgw,
                                               const float* __restrict__ hmw,
                                               u16* __restrict__ bph,
                                               u16* __restrict__ bpl) {
  const int e = blockIdx.x * 256 + threadIdx.x;  // < 9*16*48*32
  const int ici = e & 31;
  const int rest = e >> 5;
  const int oc = rest % 48;
  const int sic = rest / 48;
  const int icc = sic & 15, slot = sic >> 4;
  const int ic = icc * 32 + ici;
  const int kytab[9] = {1, 1, 1, 2, 0, 2, 2, 0, 0};
  const int kxtab[9] = {1, 2, 0, 1, 1, 2, 0, 2, 0};
  const int ky = kytab[slot], kx = kxtab[slot];
  float v = 0.f;
  if (oc < 32)
    v = rgw[((ic * 32 + oc) * 3 + ky) * 3 + kx];
  else if (oc < 40)
    v = hmw[((ic * 8 + (oc - 32)) * 3 + ky) * 3 + kx];
  const u16 h = f2bf(v);
  bph[e] = h;
  bpl[e] = f2bf(v - bf2f(h));
}

// ---------------------------------------------------------------------------
// K1: conv1 3x3 s2 p1, 512->192, split-bf16 (3x MFMA). y1 fp32 NHWC.
// ---------------------------------------------------------------------------
__global__ __launch_bounds__(256) void k_conv1(const u16* __restrict__ fbh,
                                               const u16* __restrict__ fbl,
                                               const u16* __restrict__ bph,
                                               const u16* __restrict__ bpl,
                                               const float* __restrict__ bias,
                                               float* __restrict__ y1) {
  __shared__ u16 AlH[64 * LR], AlL[64 * LR];
  __shared__ u16 BlH[192 * LR], BlL[192 * LR];
  __shared__ float bl[192];
  const int t = threadIdx.x;
  const int n = blockIdx.x >> 6, oy = blockIdx.x & 63;
  if (t < 192) bl[t] = bias[t];
  const int lane = t & 63, wv = t >> 6;
  const int row = lane & 15, g = lane >> 4;
  const int oxs = t >> 2, icq = t & 3;
  const f32x4 z4 = {0.f, 0.f, 0.f, 0.f};
  f32x4 acc[4][3];
#pragma unroll
  for (int i = 0; i < 4; ++i)
#pragma unroll
    for (int j = 0; j < 3; ++j) acc[i][j] = z4;

  for (int kc = 0; kc < 144; ++kc) {
    const int tap = kc >> 4, icc = kc & 15;
    const int ky = tap / 3, kx = tap - ky * 3;
    const int iy = 2 * oy - 1 + ky;
    const int ix = 2 * oxs - 1 + kx;
    u16x8 avh = {0, 0, 0, 0, 0, 0, 0, 0};
    u16x8 avl = {0, 0, 0, 0, 0, 0, 0, 0};
    if ((unsigned)iy < 128u && (unsigned)ix < 128u) {
      const size_t idx =
          ((size_t)((n * 128 + iy) * 128 + ix) << 9) + icc * 32 + icq * 8;
      avh = *(const u16x8*)&fbh[idx];
      avl = *(const u16x8*)&fbl[idx];
    }
    u16x8 bvh[3], bvl[3];
    const size_t bbase = (size_t)(tap * 16 + icc) * (192 * 32);
#pragma unroll
    for (int i = 0; i < 3; ++i) {
      const int e = t + i * 256;
      const size_t off = bbase + (e >> 2) * 32 + (e & 3) * 8;
      bvh[i] = *(const u16x8*)&bph[off];
      bvl[i] = *(const u16x8*)&bpl[off];
    }
    __syncthreads();
    *(u16x8*)&AlH[oxs * LR + icq * 8] = avh;
    *(u16x8*)&AlL[oxs * LR + icq * 8] = avl;
#pragma unroll
    for (int i = 0; i < 3; ++i) {
      const int e = t + i * 256;
      *(u16x8*)&BlH[(e >> 2) * LR + (e & 3) * 8] = bvh[i];
      *(u16x8*)&BlL[(e >> 2) * LR + (e & 3) * 8] = bvl[i];
    }
    __syncthreads();
    u16x8 afh[4], afl[4], bfh[3], bfl[3];
#pragma unroll
    for (int mf = 0; mf < 4; ++mf) {
      afh[mf] = *(const u16x8*)&AlH[(mf * 16 + row) * LR + g * 8];
      afl[mf] = *(const u16x8*)&AlL[(mf * 16 + row) * LR + g * 8];
    }
#pragma unroll
    for (int nf = 0; nf < 3; ++nf) {
      bfh[nf] = *(const u16x8*)&BlH[(wv * 48 + nf * 16 + row) * LR + g * 8];
      bfl[nf] = *(const u16x8*)&BlL[(wv * 48 + nf * 16 + row) * LR + g * 8];
    }
#pragma unroll
    for (int mf = 0; mf < 4; ++mf)
#pragma unroll
      for (int nf = 0; nf < 3; ++nf) {
        acc[mf][nf] = mfma16(afh[mf], bfh[nf], acc[mf][nf]);
        acc[mf][nf] = mfma16(afh[mf], bfl[nf], acc[mf][nf]);
        acc[mf][nf] = mfma16(afl[mf], bfh[nf], acc[mf][nf]);
      }
  }
#pragma unroll
  for (int mf = 0; mf < 4; ++mf)
#pragma unroll
    for (int nf = 0; nf < 3; ++nf)
#pragma unroll
      for (int r = 0; r < 4; ++r) {
        const int m = mf * 16 + g * 4 + r;
        const int oc = wv * 48 + nf * 16 + row;
        y1[((n * 64 + oy) * 64 + m) * 192 + oc] = acc[mf][nf][r] + bl[oc];
      }
}

// ---------------------------------------------------------------------------
// K2: conv2 3x3 s2 p1, 192->192 on bn1(y1 fp32), split-bf16. y2 fp32 NHWC.
// ---------------------------------------------------------------------------
__global__ __launch_bounds__(256) void k_conv2(const float* __restrict__ y1,
                                               const u16* __restrict__ bph,
                                               const u16* __restrict__ bpl,
                                               const float* __restrict__ bias,
                                               const float* __restrict__ sc,
                                               const float* __restrict__ sh,
                                               float* __restrict__ y2) {
  __shared__ u16 AlH[64 * LR], AlL[64 * LR];
  __shared__ u16 BlH[192 * LR], BlL[192 * LR];
  __shared__ float bl[192], scl[192], shl[192];
  const int t = threadIdx.x;
  const int n = blockIdx.x >> 4, oyp = blockIdx.x & 15;
  if (t < 192) {
    bl[t] = bias[t];
    scl[t] = sc[t];
    shl[t] = sh[t];
  }
  __syncthreads();
  const int lane = t & 63, wv = t >> 6;
  const int row = lane & 15, g = lane >> 4;
  const int ms = t >> 2, icq = t & 3;
  const int ryr = ms >> 5, oxs = ms & 31;
  const f32x4 z4 = {0.f, 0.f, 0.f, 0.f};
  f32x4 acc[4][3];
#pragma unroll
  for (int i = 0; i < 4; ++i)
#pragma unroll
    for (int j = 0; j < 3; ++j) acc[i][j] = z4;

  for (int kc = 0; kc < 54; ++kc) {
    const int tap = kc / 6, icc = kc - tap * 6;
    const int ky = tap / 3, kx = tap - ky * 3;
    const int iy = 2 * (oyp * 2 + ryr) - 1 + ky;
    const int ix = 2 * oxs - 1 + kx;
    u16x8 avh = {0, 0, 0, 0, 0, 0, 0, 0};
    u16x8 avl = {0, 0, 0, 0, 0, 0, 0, 0};
    if ((unsigned)iy < 64u && (unsigned)ix < 64u) {
      const int icb = icc * 32 + icq * 8;
      const float* base = &y1[((n * 64 + iy) * 64 + ix) * 192 + icb];
      const f32x4 r0 = *(const f32x4*)base;
      const f32x4 r1 = *(const f32x4*)(base + 4);
#pragma unroll
      for (int j = 0; j < 8; ++j) {
        const float r = (j < 4) ? r0[j & 3] : r1[j & 3];
        const float v = r * scl[icb + j] + shl[icb + j];
        const u16 h = f2bf(v);
        avh[j] = h;
        avl[j] = f2bf(v - bf2f(h));
      }
    }
    u16x8 bvh[3], bvl[3];
    const size_t bbase = (size_t)(tap * 6 + icc) * (192 * 32);
#pragma unroll
    for (int i = 0; i < 3; ++i) {
      const int e = t + i * 256;
      const size_t off = bbase + (e >> 2) * 32 + (e & 3) * 8;
      bvh[i] = *(const u16x8*)&bph[off];
      bvl[i] = *(const u16x8*)&bpl[off];
    }
    __syncthreads();
    *(u16x8*)&AlH[ms * LR + icq * 8] = avh;
    *(u16x8*)&AlL[ms * LR + icq * 8] = avl;
#pragma unroll
    for (int i = 0; i < 3; ++i) {
      const int e = t + i * 256;
      *(u16x8*)&BlH[(e >> 2) * LR + (e & 3) * 8] = bvh[i];
      *(u16x8*)&BlL[(e >> 2) * LR + (e & 3) * 8] = bvl[i];
    }
    __syncthreads();
    u16x8 afh[4], afl[4], bfh[3], bfl[3];
#pragma unroll
    for (int mf = 0; mf < 4; ++mf) {
      afh[mf] = *(const u16x8*)&AlH[(mf * 16 + row) * LR + g * 8];
      afl[mf] = *(const u16x8*)&AlL[(mf * 16 + row) * LR + g * 8];
    }
#pragma unroll
    for (int nf = 0; nf < 3; ++nf) {
      bfh[nf] = *(const u16x8*)&BlH[(wv * 48 + nf * 16 + row) * LR + g * 8];
      bfl[nf] = *(const u16x8*)&BlL[(wv * 48 + nf * 16 + row) * LR + g * 8];
    }
#pragma unroll
    for (int mf = 0; mf < 4; ++mf)
#pragma unroll
      for (int nf = 0; nf < 3; ++nf) {
        acc[mf][nf] = mfma16(afh[mf], bfh[nf], acc[mf][nf]);
        acc[mf][nf] = mfma16(afh[mf], bfl[nf], acc[mf][nf]);
        acc[mf][nf] = mfma16(afl[mf], bfh[nf], acc[mf][nf]);
      }
  }
#pragma unroll
  for (int mf = 0; mf < 4; ++mf)
#pragma unroll
    for (int nf = 0; nf < 3; ++nf)
#pragma unroll
      for (int r = 0; r < 4; ++r) {
        const int m = mf * 16 + g * 4 + r;
        const int oy = oyp * 2 + (m >> 5), ox = m & 31;
        const int oc = wv * 48 + nf * 16 + row;
        y2[((n * 32 + oy) * 32 + ox) * 192 + oc] = acc[mf][nf][r] + bl[oc];
      }
}

// ---------------------------------------------------------------------------
// K5 v5: fused ConvT, software-pipelined (T14). Block = (n, row pair iyb).
// LDS: A-hi + B-hi only (55.4 KB -> 2 blocks/CU). A-lo per-lane regs.
// Next ic-chunk's global loads are issued right after the LDS-write barrier
// and fly under the 90-MFMA inner loop. Chunked XCD swizzle on blockIdx.
// ---------------------------------------------------------------------------
#define AST 40           // px stride in u16 (80 B)
#define ARS (130 * 40)   // per-row plane stride in u16
#define BST 40           // oc stride in u16
__global__ __launch_bounds__(256) void k_convt(const u16* __restrict__ fbh,
                                               const u16* __restrict__ fbl,
                                               const u16* __restrict__ bph,
                                               const u16* __restrict__ bpl,
                                               const float* __restrict__ rgb,
                                               const float* __restrict__ hmb,
                                               u16* __restrict__ rr,
                                               float* __restrict__ hm) {
  __shared__ u16 AH[2 * ARS];       // 20.8 KB
  __shared__ u16 BH[9 * 48 * BST];  // 34.6 KB
  const int t = threadIdx.x;
  // chunked XCD swizzle: adjacent iyb blocks share an input row -> same XCD L2
  const int bid = (blockIdx.x & 7) * 128 + (blockIdx.x >> 3);
  const int n = bid >> 7, iyb = bid & 127;
  const int lane = t & 63, wv = t >> 6;
  const int row = lane & 15, g = lane >> 4;

  // zero the px=128 halo column (staging never rewrites it)
  if (t < 8) {
    const int r = t >> 2, j = t & 3;
    const u16x8 z = {0, 0, 0, 0, 0, 0, 0, 0};
    *(u16x8*)&AH[r * ARS + 128 * AST + j * 8] = z;
  }

  float bias3[3];
#pragma unroll
  for (int nf = 0; nf < 3; ++nf) {
    const int oc = nf * 16 + row;
    bias3[nf] = (oc < 32) ? rgb[oc] : ((oc < 40) ? hmb[oc - 32] : 0.f);
  }

  const int SCt[9] = {0, 1, 1, 2, 2, 3, 3, 3, 3};
  const int SDt[9] = {0, 0, 0, 0, 1, 0, 0, 1, 1};
  const int SXt[9] = {0, 0, 1, 0, 0, 0, 1, 0, 1};

  // staging geometry (constant across icc)
  int rr_[4], px_[4], iq_[4];
#pragma unroll
  for (int i = 0; i < 4; ++i) {
    const int u = t + i * 256;
    rr_[i] = u >> 9;
    px_[i] = (u >> 2) & 127;
    iq_[i] = u & 3;
  }

  const f32x4 z4 = {0.f, 0.f, 0.f, 0.f};
  f32x4 acc[4][2][3];
#pragma unroll
  for (int c = 0; c < 4; ++c)
#pragma unroll
    for (int m = 0; m < 2; ++m)
#pragma unroll
      for (int j = 0; j < 3; ++j) acc[c][m][j] = z4;

#define LOAD_A(ICC, DST)                                                       \
  _Pragma("unroll") for (int i = 0; i < 4; ++i) {                              \
    const int iy = iyb + rr_[i];                                               \
    u16x8 v = {0, 0, 0, 0, 0, 0, 0, 0};                                        \
    if (iy < 128)                                                              \
      v = *(const u16x8*)&fbh[((size_t)((n * 128 + iy) * 128 + px_[i]) << 9) + \
                              (ICC)*32 + iq_[i] * 8];                          \
    DST[i] = v;                                                                \
  }

#define LOAD_B(ICC, DST)                                                       \
  _Pragma("unroll") for (int i = 0; i < 7; ++i) {                              \
    const int e = t + i * 256;                                                 \
    u16x8 v = {0, 0, 0, 0, 0, 0, 0, 0};                                        \
    if (e < 1728) {                                                            \
      const int slot = e / 192, rem = e % 192;                                 \
      const int oc = rem >> 2, icq = rem & 3;                                  \
      v = *(const u16x8*)&bph[((size_t)((slot * 16 + (ICC)) * 48 + oc) << 5) + \
                              icq * 8];                                        \
    }                                                                          \
    DST[i] = v;                                                                \
  }

  u16x8 ahA[4], bhA[7], ahB[4], bhB[7];
  LOAD_A(0, ahA);
  LOAD_B(0, bhA);

  for (int icc = 0; icc < 16; ++icc) {
    __syncthreads();  // previous inner loop done reading LDS
#pragma unroll
    for (int i = 0; i < 4; ++i)
      *(u16x8*)&AH[rr_[i] * ARS + px_[i] * AST + iq_[i] * 8] = ahA[i];
#pragma unroll
    for (int i = 0; i < 7; ++i) {
      const int e = t + i * 256;
      if (e < 1728) {
        const int slot = e / 192, rem = e % 192;
        const int oc = rem >> 2, icq = rem & 3;
        *(u16x8*)&BH[(slot * 48 + oc) * BST + icq * 8] = bhA[i];
      }
    }
    __syncthreads();

    // current A-lo direct to regs (first use is a few MFMAs in)
    u16x8 lo[2][2][2];
#pragma unroll
    for (int diy = 0; diy < 2; ++diy) {
      const int iy = iyb + diy;
      const bool ok = iy < 128;
#pragma unroll
      for (int mfl = 0; mfl < 2; ++mfl)
#pragma unroll
        for (int dix = 0; dix < 2; ++dix) {
          const int px = (wv * 2 + mfl) * 16 + row + dix;
          u16x8 v = {0, 0, 0, 0, 0, 0, 0, 0};
          if (ok && px < 128)
            v = *(const u16x8*)&fbl[((size_t)((n * 128 + iy) * 128 + px) << 9) +
                                    icc * 32 + g * 8];
          lo[diy][mfl][dix] = v;
        }
    }
    // issue NEXT chunk's staging loads; they fly under the inner loop
    if (icc < 15) {
      LOAD_A(icc + 1, ahB);
      LOAD_B(icc + 1, bhB);
    }

    // inner: 9 taps x 2 M-frags, hi operands from LDS
#pragma unroll
    for (int slot = 0; slot < 9; ++slot) {
      const int cls = SCt[slot], diy = SDt[slot], dix = SXt[slot];
      const u16x8 bfh0 = *(const u16x8*)&BH[(slot * 48 + row) * BST + g * 8];
      const u16x8 bfh1 = *(const u16x8*)&BH[(slot * 48 + 16 + row) * BST + g * 8];
      const u16x8 bfh2 = *(const u16x8*)&BH[(slot * 48 + 32 + row) * BST + g * 8];
      const u16x8 bfl2 = *(const u16x8*)&bpl[(size_t)((slot * 16 + icc) * 48 +
                                                      32 + row) * 32 + g * 8];
#pragma unroll
      for (int mfl = 0; mfl < 2; ++mfl) {
        const int mf = wv * 2 + mfl;
        const int aoff = diy * ARS + (mf * 16 + row + dix) * AST + g * 8;
        const u16x8 afh = *(const u16x8*)&AH[aoff];
        const u16x8 afl = lo[diy][mfl][dix];
        acc[cls][mfl][0] = mfma16(afh, bfh0, acc[cls][mfl][0]);
        acc[cls][mfl][1] = mfma16(afh, bfh1, acc[cls][mfl][1]);
        acc[cls][mfl][2] = mfma16(afh, bfh2, acc[cls][mfl][2]);
        acc[cls][mfl][2] = mfma16(afh, bfl2, acc[cls][mfl][2]);
        acc[cls][mfl][2] = mfma16(afl, bfh2, acc[cls][mfl][2]);
      }
    }

    // rotate double-buffered staging regs
#pragma unroll
    for (int i = 0; i < 4; ++i) ahA[i] = ahB[i];
#pragma unroll
    for (int i = 0; i < 7; ++i) bhA[i] = bhB[i];
  }
#undef LOAD_A
#undef LOAD_B

  // ---- epilogue ----
#pragma unroll
  for (int cls = 0; cls < 4; ++cls) {
    const int oy = 2 * iyb + (cls >> 1);
    const int xp = cls & 1;
#pragma unroll
    for (int mfl = 0; mfl < 2; ++mfl)
#pragma unroll
      for (int nf = 0; nf < 3; ++nf)
#pragma unroll
        for (int r = 0; r < 4; ++r) {
          const int m = (wv * 2 + mfl) * 16 + g * 4 + r;
          const int ox = 2 * m + xp;
          const int oc = nf * 16 + row;
          const float v = acc[cls][mfl][nf][r] + bias3[nf];
          if (oc < 32)
            rr[((size_t)((n * 256 + oy) * 256 + ox)) * 32 + oc] = f2bf(v);
          else if (oc < 40)
            hm[(size_t)(n * 8 + (oc - 32)) * 65536 + oy * 256 + ox] = v;
        }
  }
}

// ---------------------------------------------------------------------------
// Generic per-channel sum/sumsq over [M][C] (C = CG*32)
// ---------------------------------------------------------------------------
template <int CG, bool BF16>
__global__ __launch_bounds__(256) void k_stats(const void* __restrict__ in_, int M,
                                               int PB, float* __restrict__ gsum,
                                               float* __restrict__ gsq) {
  const int C = CG * 32;
  __shared__ float red[8][CG * 32];
  const int t = threadIdx.x;
  const int pg = t >> 5, ln = t & 31;
  float s[CG], q[CG];
#pragma unroll
  for (int c = 0; c < CG; ++c) { s[c] = 0.f; q[c] = 0.f; }
  const int p0 = blockIdx.x * PB;
  const int pend = min(p0 + PB, M);
  for (int p = p0 + pg; p < pend; p += 8) {
#pragma unroll
    for (int c = 0; c < CG; ++c) {
      float v;
      if (BF16)
        v = bf2f(((const u16*)in_)[(size_t)p * C + c * 32 + ln]);
      else
        v = ((const float*)in_)[(size_t)p * C + c * 32 + ln];
      s[c] += v;
      q[c] += v * v;
    }
  }
#pragma unroll
  for (int c = 0; c < CG; ++c) red[pg][c * 32 + ln] = s[c];
  __syncthreads();
  if (t < C) {
    float tot = 0.f;
#pragma unroll
    for (int k = 0; k < 8; ++k) tot += red[k][t];
    atomicAdd(&gsum[t], tot);
  }
  __syncthreads();
#pragma unroll
  for (int c = 0; c < CG; ++c) red[pg][c * 32 + ln] = q[c];
  __syncthreads();
  if (t < C) {
    float tot = 0.f;
#pragma unroll
    for (int k = 0; k < 8; ++k) tot += red[k][t];
    atomicAdd(&gsq[t], tot);
  }
}

__global__ void k_bnfin(const float* __restrict__ gsum, const float* __restrict__ gsq,
                        const float* __restrict__ g, const float* __restrict__ be,
                        float invM, int C, float* __restrict__ sc,
                        float* __restrict__ sh) {
  const int t = threadIdx.x;
  if (t < C) {
    const float m = gsum[t] * invM;
    const float var = gsq[t] * invM - m * m;
    const float inv = rsqrtf(var + 1e-5f);
    const float s = g[t] * inv;
    sc[t] = s;
    sh[t] = be[t] - m * s;
  }
}

// ---------------------------------------------------------------------------
// K3: conv3 1x1 192->32 on bn(y2 fp32). y3 fp32 [8192][32].
// ---------------------------------------------------------------------------
__global__ __launch_bounds__(256) void k_conv3(const float* __restrict__ y2,
                                               const float* __restrict__ w3,
                                               const float* __restrict__ b3,
                                               const float* __restrict__ sc,
                                               const float* __restrict__ sh,
                                               float* __restrict__ y3) {
  __shared__ float wl[32 * 192];
  __shared__ float scl[192], shl[192];
  const int t = threadIdx.x;
  for (int e = t; e < 6144; e += 256) wl[e] = w3[e];
  if (t < 192) {
    scl[t] = sc[t];
    shl[t] = sh[t];
  }
  __syncthreads();
  const int px = blockIdx.x * 256 + t;
  float acc[32];
#pragma unroll
  for (int oc = 0; oc < 32; ++oc) acc[oc] = 0.f;
  const float* base = &y2[(size_t)px * 192];
  for (int icb = 0; icb < 192; icb += 8) {
    const f32x4 r0 = *(const f32x4*)&base[icb];
    const f32x4 r1 = *(const f32x4*)&base[icb + 4];
    float v[8];
#pragma unroll
    for (int j = 0; j < 8; ++j) {
      const float r = (j < 4) ? r0[j & 3] : r1[j & 3];
      v[j] = r * scl[icb + j] + shl[icb + j];
    }
#pragma unroll
    for (int oc = 0; oc < 32; ++oc) {
      const f32x4 w0 = *(const f32x4*)&wl[oc * 192 + icb];
      const f32x4 w1 = *(const f32x4*)&wl[oc * 192 + icb + 4];
      acc[oc] += v[0] * w0[0] + v[1] * w0[1] + v[2] * w0[2] + v[3] * w0[3] +
                 v[4] * w1[0] + v[5] * w1[1] + v[6] * w1[2] + v[7] * w1[3];
    }
  }
#pragma unroll
  for (int oc = 0; oc < 32; ++oc) y3[(size_t)px * 32 + oc] = acc[oc] + b3[oc];
}

// ---------------------------------------------------------------------------
// K4: classify conv 3x3 p1, 32->32 on hsw(bn2(y3))
// ---------------------------------------------------------------------------
__global__ __launch_bounds__(256) void k_clsconv1(const float* __restrict__ y3,
                                                  const float* __restrict__ w1,
                                                  const float* __restrict__ b1,
                                                  const float* __restrict__ sc,
                                                  const float* __restrict__ sh,
                                                  float* __restrict__ c1) {
  __shared__ float wl[9216];  // [ic][tap][oc]
  __shared__ float scl[32], shl[32];
  const int t = threadIdx.x;
  for (int e = t; e < 9216; e += 256) {
    const int oc = e & 31;
    const int tmp = e >> 5;
    const int tap = tmp % 9, ic = tmp / 9;
    wl[e] = w1[(oc * 32 + ic) * 9 + tap];
  }
  if (t < 32) {
    scl[t] = sc[t];
    shl[t] = sh[t];
  }
  __syncthreads();
  const int px = blockIdx.x * 64 + (t & 63);
  const int ocg = t >> 6;
  const int n = px >> 10, y0 = (px >> 5) & 31, x0 = px & 31;
  float acc[8];
#pragma unroll
  for (int j = 0; j < 8; ++j) acc[j] = 0.f;
  for (int tap = 0; tap < 9; ++tap) {
    const int dy = tap / 3 - 1, dx = tap % 3 - 1;
    const int yy = y0 + dy, xx = x0 + dx;
    if ((unsigned)yy < 32u && (unsigned)xx < 32u) {
      const float* ib = &y3[((n << 10) + yy * 32 + xx) * 32];
      for (int ic = 0; ic < 32; ++ic) {
        const float v = hsw(ib[ic] * scl[ic] + shl[ic]);
        const float* wp = &wl[(ic * 9 + tap) * 32 + ocg * 8];
#pragma unroll
        for (int j = 0; j < 8; ++j) acc[j] += v * wp[j];
      }
    }
  }
#pragma unroll
  for (int j = 0; j < 8; ++j) c1[px * 32 + ocg * 8 + j] = acc[j] + b1[ocg * 8 + j];
}

// ---------------------------------------------------------------------------
// K4c: c2 = conv3x3(hsw(bn(c1))) 32->1, then cls[n,k] = c2 . dw[k] + db[k]
// ---------------------------------------------------------------------------
__global__ __launch_bounds__(256) void k_cls(const float* __restrict__ c1,
                                             const float* __restrict__ w2,
                                             const float* __restrict__ b2,
                                             const float* __restrict__ dw,
                                             const float* __restrict__ db,
                                             const float* __restrict__ sc,
                                             const float* __restrict__ sh,
                                             float* __restrict__ cls) {
  __shared__ float wl[288];
  __shared__ float scl[32], shl[32];
  __shared__ float red0[256], red1[256];
  const int t = threadIdx.x;
  const int n = blockIdx.x;
  for (int e = t; e < 288; e += 256) wl[e] = w2[e];
  if (t < 32) {
    scl[t] = sc[t];
    shl[t] = sh[t];
  }
  __syncthreads();
  float s0 = 0.f, s1 = 0.f;
  for (int i = 0; i < 4; ++i) {
    const int px = i * 256 + t;
    const int y0 = px >> 5, x0 = px & 31;
    float c2 = b2[0];
    for (int tap = 0; tap < 9; ++tap) {
      const int dy = tap / 3 - 1, dx = tap % 3 - 1;
      const int yy = y0 + dy, xx = x0 + dx;
      if ((unsigned)yy < 32u && (unsigned)xx < 32u) {
        const float* ib = &c1[((n << 10) + yy * 32 + xx) * 32];
        for (int ic = 0; ic < 32; ++ic)
          c2 += hsw(ib[ic] * scl[ic] + shl[ic]) * wl[ic * 9 + tap];
      }
    }
    s0 += c2 * dw[px];
    s1 += c2 * dw[1024 + px];
  }
  red0[t] = s0;
  red1[t] = s1;
  __syncthreads();
  for (int s = 128; s; s >>= 1) {
    if (t < s) {
      red0[t] += red0[t + s];
      red1[t] += red1[t + s];
    }
    __syncthreads();
  }
  if (t == 0) {
    cls[n * 2 + 0] = red0[0] + db[0];
    cls[n * 2 + 1] = red1[0] + db[1];
  }
}

// ---------------------------------------------------------------------------
// K6: reg = conv3x3 p1 (hsw(bn(rr))) 32->2, fp32 NCHW [8,2,256,256]
// ---------------------------------------------------------------------------
__global__ __launch_bounds__(256) void k_regconv(const u16* __restrict__ rr,
                                                 const float* __restrict__ w,
                                                 const float* __restrict__ b,
                                                 const float* __restrict__ sc,
                                                 const float* __restrict__ sh,
                                                 float* __restrict__ reg) {
  __shared__ u16 rl[3 * 258 * 33];
  __shared__ float wl[576];
  __shared__ float scl[32], shl[32];
  const int t = threadIdx.x;
  const int n = blockIdx.x >> 8, oy = blockIdx.x & 255;
  for (int e = t; e < 576; e += 256) wl[e] = w[e];
  if (t < 32) {
    scl[t] = sc[t];
    shl[t] = sh[t];
  }
  if (t < 192) {
    const int ry = t / 64, side = (t >> 5) & 1, ic = t & 31;
    rl[(ry * 258 + side * 257) * 33 + ic] = 0;
  }
  __syncthreads();
  for (int e = t; e < 3072; e += 256) {
    const int icq8 = e & 3;
    const int pxx = (e >> 2) & 255;
    const int ry = e >> 10;
    const int rowi = oy - 1 + ry;
    u16x8 raw = {0, 0, 0, 0, 0, 0, 0, 0};
    bool ok = (unsigned)rowi < 256u;
    if (ok)
      raw = *(const u16x8*)&rr[((size_t)((n * 256 + rowi) * 256 + pxx)) * 32 + icq8 * 8];
#pragma unroll
    for (int j = 0; j < 8; ++j) {
      const int ic = icq8 * 8 + j;
      float v = 0.f;
      if (ok) v = hsw(bf2f(raw[j]) * scl[ic] + shl[ic]);
      rl[(ry * 258 + pxx + 1) * 33 + ic] = f2bf(v);
    }
  }
  __syncthreads();
  const int px = t;
  float a0 = b[0], a1 = b[1];
#pragma unroll
  for (int ry = 0; ry < 3; ++ry)
#pragma unroll
    for (int kx = 0; kx < 3; ++kx) {
      const u16* ib = &rl[(ry * 258 + px + kx) * 33];
      for (int ic = 0; ic < 32; ++ic) {
        const float v = bf2f(ib[ic]);
        a0 += v * wl[ic * 9 + ry * 3 + kx];
        a1 += v * wl[288 + ic * 9 + ry * 3 + kx];
      }
    }
  reg[(n * 2 + 0) * 65536 + oy * 256 + px] = a0;
  reg[(n * 2 + 1) * 65536 + oy * 256 + px] = a1;
}

// ---------------------------------------------------------------------------
// K7: per (n, ch) spatial argmax, lowest-index tie-break
// ---------------------------------------------------------------------------
__global__ __launch_bounds__(256) void k_argmax(const float* __restrict__ hm,
                                                int* __restrict__ idx) {
  __shared__ float bv[256];
  __shared__ int bi[256];
  const int t = threadIdx.x;
  const float* base = &hm[(size_t)blockIdx.x * 65536];
  float best = -3.402823466e38f;
  int bidx = 2147483647;
  for (int i = t; i < 65536; i += 256) {
    const float v = base[i];
    if (v > best) {
      best = v;
      bidx = i;
    }
  }
  bv[t] = best;
  bi[t] = bidx;
  __syncthreads();
  for (int s = 128; s; s >>= 1) {
    if (t < s) {
      if (bv[t + s] > bv[t] || (bv[t + s] == bv[t] && bi[t + s] < bi[t])) {
        bv[t] = bv[t + s];
        bi[t] = bi[t + s];
      }
    }
    __syncthreads();
  }
  if (t == 0) idx[blockIdx.x] = bi[0];
}

// ---------------------------------------------------------------------------
// K8: decode -> out [8,2,9]
// ---------------------------------------------------------------------------
__global__ void k_final(const float* __restrict__ cls, const int* __restrict__ idx,
                        const float* __restrict__ reg, float* __restrict__ out) {
  const int t = threadIdx.x;
  if (t >= 16) return;
  const int n = t >> 1, p = t & 1;
  const float cv = cls[n * 2 + p];
  float* o = &out[(n * 2 + p) * 9];
  if (!(cv > 0.6f)) {
    for (int i = 0; i < 9; ++i) o[i] = -1.f;
    return;
  }
  o[0] = (float)p;
  for (int c = 0; c < 4; ++c) {
    const int id = idx[n * 8 + p * 4 + c];
    const int yi = id >> 8, xi = id & 255;
    const float ox_ = reg[(n * 2 + 0) * 65536 + id];
    const float oy_ = reg[(n * 2 + 1) * 65536 + id];
    o[1 + c] = fminf(fmaxf((ox_ + (float)xi) * (1.f / 256.f), 0.f), 1.f);
    o[5 + c] = fminf(fmaxf((oy_ + (float)yi) * (1.f / 256.f), 0.f), 1.f);
  }
}

// ---------------------------------------------------------------------------
extern "C" void kernel_launch(void* const* d_in, const int* in_sizes, int n_in,
                              void* d_out, int out_size, void* d_ws, size_t ws_size,
                              hipStream_t stream) {
  const float* feature = (const float*)d_in[0];
  const float* ch_w1 = (const float*)d_in[1];
  const float* ch_b1 = (const float*)d_in[2];
  const float* ch_w2 = (const float*)d_in[3];
  const float* ch_b2 = (const float*)d_in[4];
  const float* ch_w3 = (const float*)d_in[5];
  const float* ch_b3 = (const float*)d_in[6];
  const float* ch_g1 = (const float*)d_in[7];
  const float* ch_be1 = (const float*)d_in[8];
  const float* ch_g2 = (const float*)d_in[9];
  const float* ch_be2 = (const float*)d_in[10];
  const float* cl_w1 = (const float*)d_in[11];
  const float* cl_b1 = (const float*)d_in[12];
  const float* cl_w2 = (const float*)d_in[13];
  const float* cl_b2 = (const float*)d_in[14];
  const float* cl_g = (const float*)d_in[15];
  const float* cl_be = (const float*)d_in[16];
  const float* cl_dw = (const float*)d_in[17];
  const float* cl_db = (const float*)d_in[18];
  const float* rg_tw = (const float*)d_in[19];
  const float* rg_tb = (const float*)d_in[20];
  const float* rg_g = (const float*)d_in[21];
  const float* rg_be = (const float*)d_in[22];
  const float* rg_w = (const float*)d_in[23];
  const float* rg_b = (const float*)d_in[24];
  const float* hm_tw = (const float*)d_in[25];
  const float* hm_tb = (const float*)d_in[26];
  float* out = (float*)d_out;

  char* w = (char*)d_ws;
  const size_t OFF_FB = 0;                  // 134217728
  const size_t OFF_FBL = 134217728;         // 134217728
  const size_t OFF_BP1H = 268435456;        // 1769472
  const size_t OFF_BP1L = 270204928;        // 1769472
  const size_t OFF_BP2H = 271974400;        // 663552
  const size_t OFF_BP2L = 272637952;        // 663552
  const size_t OFF_BP5H = 273301504;        // 442368
  const size_t OFF_BP5L = 273743872;        // 442368
  const size_t OFF_Y1 = 274186240;          // 25165824 (fp32)
  const size_t OFF_Y2 = 299352064;          // 6291456  (fp32)
  const size_t OFF_Y3 = 305643520;          // 1048576
  const size_t OFF_C1 = 306692096;          // 1048576
  const size_t OFF_RR = 307740672;          // 33554432
  const size_t OFF_HM = 341295104;          // 16777216
  const size_t OFF_REG = 358072320;         // 4194304
  const size_t OFF_STATS = 362266624;       // 3840
  const size_t OFF_PARAMS = 362270464;      // 3840
  const size_t OFF_CLS = 362274304;         // 64
  const size_t OFF_IDX = 362274368;         // 256
  const size_t WS_NEED = 362274624;
  if (ws_size < WS_NEED) return;

  u16* FB = (u16*)(w + OFF_FB);
  u16* FBL = (u16*)(w + OFF_FBL);
  u16* BP1H = (u16*)(w + OFF_BP1H);
  u16* BP1L = (u16*)(w + OFF_BP1L);
  u16* BP2H = (u16*)(w + OFF_BP2H);
  u16* BP2L = (u16*)(w + OFF_BP2L);
  u16* BP5H = (u16*)(w + OFF_BP5H);
  u16* BP5L = (u16*)(w + OFF_BP5L);
  float* Y1 = (float*)(w + OFF_Y1);
  float* Y2 = (float*)(w + OFF_Y2);
  float* Y3 = (float*)(w + OFF_Y3);
  float* C1 = (float*)(w + OFF_C1);
  u16* RR = (u16*)(w + OFF_RR);
  float* HM = (float*)(w + OFF_HM);
  float* REG = (float*)(w + OFF_REG);
  float* GSUM = (float*)(w + OFF_STATS);
  float* GSQ = GSUM + 480;
  float* SC = (float*)(w + OFF_PARAMS);
  float* SH = SC + 480;
  float* CLS = (float*)(w + OFF_CLS);
  int* IDX = (int*)(w + OFF_IDX);

  (void)hipMemsetAsync(w + OFF_STATS, 0, 3840, stream);

  k_tobf<<<16384, 256, 0, stream>>>(feature, FB, FBL);
  k_pack1<<<3456, 256, 0, stream>>>(ch_w1, BP1H, BP1L);
  k_pack2<<<1296, 256, 0, stream>>>(ch_w2, BP2H, BP2L);
  k_pack5<<<864, 256, 0, stream>>>(rg_tw, hm_tw, BP5H, BP5L);

  // CommonHead
  k_conv1<<<512, 256, 0, stream>>>(FB, FBL, BP1H, BP1L, ch_b1, Y1);
  k_stats<6, false><<<128, 256, 0, stream>>>(Y1, 32768, 256, GSUM + 0, GSQ + 0);
  k_bnfin<<<1, 256, 0, stream>>>(GSUM + 0, GSQ + 0, ch_g1, ch_be1, 1.f / 32768.f, 192,
                                 SC + 0, SH + 0);
  k_conv2<<<128, 256, 0, stream>>>(Y1, BP2H, BP2L, ch_b2, SC + 0, SH + 0, Y2);
  k_stats<6, false><<<32, 256, 0, stream>>>(Y2, 8192, 256, GSUM + 192, GSQ + 192);
  k_bnfin<<<1, 256, 0, stream>>>(GSUM + 192, GSQ + 192, ch_g1, ch_be1, 1.f / 8192.f,
                                 192, SC + 192, SH + 192);
  k_conv3<<<32, 256, 0, stream>>>(Y2, ch_w3, ch_b3, SC + 192, SH + 192, Y3);
  k_stats<1, false><<<8, 256, 0, stream>>>(Y3, 8192, 1024, GSUM + 384, GSQ + 384);
  k_bnfin<<<1, 256, 0, stream>>>(GSUM + 384, GSQ + 384, ch_g2, ch_be2, 1.f / 8192.f,
                                 32, SC + 384, SH + 384);
  // Classify head
  k_clsconv1<<<128, 256, 0, stream>>>(Y3, cl_w1, cl_b1, SC + 384, SH + 384, C1);
  k_stats<1, false><<<8, 256, 0, stream>>>(C1, 8192, 1024, GSUM + 416, GSQ + 416);
  k_bnfin<<<1, 256, 0, stream>>>(GSUM + 416, GSQ + 416, cl_g, cl_be, 1.f / 8192.f, 32,
                                 SC + 416, SH + 416);
  k_cls<<<8, 256, 0, stream>>>(C1, cl_w2, cl_b2, cl_dw, cl_db, SC + 416, SH + 416,
                               CLS);
  // Regression + heatmap (fused convT v5: pipelined staging, 2 blocks/CU)
  k_convt<<<1024, 256, 0, stream>>>(FB, FBL, BP5H, BP5L, rg_tb, hm_tb, RR, HM);
  k_stats<1, true><<<256, 256, 0, stream>>>(RR, 524288, 2048, GSUM + 448, GSQ + 448);
  k_bnfin<<<1, 256, 0, stream>>>(GSUM + 448, GSQ + 448, rg_g, rg_be, 1.f / 524288.f,
                                 32, SC + 448, SH + 448);
  k_regconv<<<2048, 256, 0, stream>>>(RR, rg_w, rg_b, SC + 448, SH + 448, REG);
  // Decode
  k_argmax<<<64, 256, 0, stream>>>(HM, IDX);
  k_final<<<1, 64, 0, stream>>>(CLS, IDX, REG, out);
}

// Round 7
// 836.323 us; speedup vs baseline: 1.9889x; 1.4793x over previous
//
#include <hip/hip_runtime.h>

typedef unsigned short u16;
typedef u16 u16x8 __attribute__((ext_vector_type(8)));
typedef __bf16 bf16x8 __attribute__((ext_vector_type(8)));
typedef float f32x4 __attribute__((ext_vector_type(4)));

__device__ __forceinline__ float bf2f(u16 v) {
  unsigned u = ((unsigned)v) << 16;
  return __builtin_bit_cast(float, u);
}
__device__ __forceinline__ u16 f2bf(float f) {
  unsigned u = __builtin_bit_cast(unsigned, f);
  u += 0x7FFFu + ((u >> 16) & 1u);
  return (u16)(u >> 16);
}
__device__ __forceinline__ float hsw(float v) {
  return v * fminf(fmaxf(v + 3.f, 0.f), 6.f) * (1.f / 6.f);
}
__device__ __forceinline__ f32x4 mfma16(u16x8 a, u16x8 b, f32x4 c) {
  return __builtin_amdgcn_mfma_f32_16x16x32_bf16(
      __builtin_bit_cast(bf16x8, a), __builtin_bit_cast(bf16x8, b), c, 0, 0, 0);
}

#define LR 40  // padded LDS row stride in u16 (80 B), breaks pow2 bank stride

// ---------------------------------------------------------------------------
// K0: feature NCHW fp32 -> NHWC bf16 (single plane)
// ---------------------------------------------------------------------------
__global__ __launch_bounds__(256) void k_tobf(const float* __restrict__ f,
                                              u16* __restrict__ fbh) {
  __shared__ float tl[64 * 65];
  const int t = threadIdx.x;
  const int bid = blockIdx.x;
  const int ict = bid & 7, xt = (bid >> 3) & 1, y = (bid >> 4) & 127, n = bid >> 11;
  const int x0 = xt * 64, ic0 = ict * 64;
#pragma unroll
  for (int i = 0; i < 16; ++i) {
    const int e = t + i * 256;
    const int icl = e >> 6, xl = e & 63;
    tl[icl * 65 + xl] = f[((n * 512 + ic0 + icl) * 128 + y) * 128 + x0 + xl];
  }
  __syncthreads();
#pragma unroll
  for (int i = 0; i < 16; ++i) {
    const int e = t + i * 256;
    const int xl = e >> 6, icl = e & 63;
    const size_t idx = ((size_t)((n * 128 + y) * 128 + x0 + xl) << 9) + ic0 + icl;
    fbh[idx] = f2bf(tl[icl * 65 + xl]);
  }
}

// ---------------------------------------------------------------------------
// Weight prepacks: [tap][icc][oc][ic32] bf16
// ---------------------------------------------------------------------------
__global__ __launch_bounds__(256) void k_pack1(const float* __restrict__ w,
                                               u16* __restrict__ bph) {
  const int e = blockIdx.x * 256 + threadIdx.x;  // < 9*16*192*32
  const int ici = e & 31;
  const int rest = e >> 5;
  const int oc = rest % 192;
  const int kc = rest / 192;
  const int icc = kc & 15, tap = kc >> 4;
  const int ic = icc * 32 + ici;
  bph[e] = f2bf(w[(oc * 512 + ic) * 9 + tap]);
}

__global__ __launch_bounds__(256) void k_pack2(const float* __restrict__ w,
                                               u16* __restrict__ bph) {
  const int e = blockIdx.x * 256 + threadIdx.x;  // < 9*6*192*32
  const int ici = e & 31;
  const int rest = e >> 5;
  const int oc = rest % 192;
  const int kc = rest / 192;
  const int icc = kc % 6, tap = kc / 6;
  const int ic = icc * 32 + ici;
  bph[e] = f2bf(w[(oc * 192 + ic) * 9 + tap]);
}

__global__ __launch_bounds__(256) void k_pack5(const float* __restrict__ rgw,
                                               const float* __restrict__ hmw,
                                               u16* __restrict__ bph) {
  const int e = blockIdx.x * 256 + threadIdx.x;  // < 9*16*48*32
  const int ici = e & 31;
  const int rest = e >> 5;
  const int oc = rest % 48;
  const int sic = rest / 48;
  const int icc = sic & 15, slot = sic >> 4;
  const int ic = icc * 32 + ici;
  const int kytab[9] = {1, 1, 1, 2, 0, 2, 2, 0, 0};
  const int kxtab[9] = {1, 2, 0, 1, 1, 2, 0, 2, 0};
  const int ky = kytab[slot], kx = kxtab[slot];
  float v = 0.f;
  if (oc < 32)
    v = rgw[((ic * 32 + oc) * 3 + ky) * 3 + kx];
  else if (oc < 40)
    v = hmw[((ic * 8 + (oc - 32)) * 3 + ky) * 3 + kx];
  bph[e] = f2bf(v);
}

// ---------------------------------------------------------------------------
// K1: conv1 3x3 s2 p1, 512->192, single bf16. y1 fp32 NHWC.
// ---------------------------------------------------------------------------
__global__ __launch_bounds__(256) void k_conv1(const u16* __restrict__ fbh,
                                               const u16* __restrict__ bph,
                                               const float* __restrict__ bias,
                                               float* __restrict__ y1) {
  __shared__ u16 Al[64 * LR];
  __shared__ u16 Bl[192 * LR];
  __shared__ float bl[192];
  const int t = threadIdx.x;
  const int n = blockIdx.x >> 6, oy = blockIdx.x & 63;
  if (t < 192) bl[t] = bias[t];
  const int lane = t & 63, wv = t >> 6;
  const int row = lane & 15, g = lane >> 4;
  const int oxs = t >> 2, icq = t & 3;
  const f32x4 z4 = {0.f, 0.f, 0.f, 0.f};
  f32x4 acc[4][3];
#pragma unroll
  for (int i = 0; i < 4; ++i)
#pragma unroll
    for (int j = 0; j < 3; ++j) acc[i][j] = z4;

  for (int kc = 0; kc < 144; ++kc) {
    const int tap = kc >> 4, icc = kc & 15;
    const int ky = tap / 3, kx = tap - ky * 3;
    const int iy = 2 * oy - 1 + ky;
    const int ix = 2 * oxs - 1 + kx;
    u16x8 av = {0, 0, 0, 0, 0, 0, 0, 0};
    if ((unsigned)iy < 128u && (unsigned)ix < 128u)
      av = *(const u16x8*)&fbh[((size_t)((n * 128 + iy) * 128 + ix) << 9) +
                               icc * 32 + icq * 8];
    u16x8 bv[3];
    const size_t bbase = (size_t)(tap * 16 + icc) * (192 * 32);
#pragma unroll
    for (int i = 0; i < 3; ++i) {
      const int e = t + i * 256;
      bv[i] = *(const u16x8*)&bph[bbase + (e >> 2) * 32 + (e & 3) * 8];
    }
    __syncthreads();
    *(u16x8*)&Al[oxs * LR + icq * 8] = av;
#pragma unroll
    for (int i = 0; i < 3; ++i) {
      const int e = t + i * 256;
      *(u16x8*)&Bl[(e >> 2) * LR + (e & 3) * 8] = bv[i];
    }
    __syncthreads();
    u16x8 af[4], bf[3];
#pragma unroll
    for (int mf = 0; mf < 4; ++mf)
      af[mf] = *(const u16x8*)&Al[(mf * 16 + row) * LR + g * 8];
#pragma unroll
    for (int nf = 0; nf < 3; ++nf)
      bf[nf] = *(const u16x8*)&Bl[(wv * 48 + nf * 16 + row) * LR + g * 8];
#pragma unroll
    for (int mf = 0; mf < 4; ++mf)
#pragma unroll
      for (int nf = 0; nf < 3; ++nf) acc[mf][nf] = mfma16(af[mf], bf[nf], acc[mf][nf]);
  }
#pragma unroll
  for (int mf = 0; mf < 4; ++mf)
#pragma unroll
    for (int nf = 0; nf < 3; ++nf)
#pragma unroll
      for (int r = 0; r < 4; ++r) {
        const int m = mf * 16 + g * 4 + r;
        const int oc = wv * 48 + nf * 16 + row;
        y1[((n * 64 + oy) * 64 + m) * 192 + oc] = acc[mf][nf][r] + bl[oc];
      }
}

// ---------------------------------------------------------------------------
// K2: conv2 3x3 s2 p1, 192->192 on bn1(y1 fp32), single bf16. y2 fp32 NHWC.
// ---------------------------------------------------------------------------
__global__ __launch_bounds__(256) void k_conv2(const float* __restrict__ y1,
                                               const u16* __restrict__ bph,
                                               const float* __restrict__ bias,
                                               const float* __restrict__ sc,
                                               const float* __restrict__ sh,
                                               float* __restrict__ y2) {
  __shared__ u16 Al[64 * LR];
  __shared__ u16 Bl[192 * LR];
  __shared__ float bl[192], scl[192], shl[192];
  const int t = threadIdx.x;
  const int n = blockIdx.x >> 4, oyp = blockIdx.x & 15;
  if (t < 192) {
    bl[t] = bias[t];
    scl[t] = sc[t];
    shl[t] = sh[t];
  }
  __syncthreads();
  const int lane = t & 63, wv = t >> 6;
  const int row = lane & 15, g = lane >> 4;
  const int ms = t >> 2, icq = t & 3;
  const int ryr = ms >> 5, oxs = ms & 31;
  const f32x4 z4 = {0.f, 0.f, 0.f, 0.f};
  f32x4 acc[4][3];
#pragma unroll
  for (int i = 0; i < 4; ++i)
#pragma unroll
    for (int j = 0; j < 3; ++j) acc[i][j] = z4;

  for (int kc = 0; kc < 54; ++kc) {
    const int tap = kc / 6, icc = kc - tap * 6;
    const int ky = tap / 3, kx = tap - ky * 3;
    const int iy = 2 * (oyp * 2 + ryr) - 1 + ky;
    const int ix = 2 * oxs - 1 + kx;
    u16x8 av = {0, 0, 0, 0, 0, 0, 0, 0};
    if ((unsigned)iy < 64u && (unsigned)ix < 64u) {
      const int icb = icc * 32 + icq * 8;
      const float* base = &y1[((n * 64 + iy) * 64 + ix) * 192 + icb];
      const f32x4 r0 = *(const f32x4*)base;
      const f32x4 r1 = *(const f32x4*)(base + 4);
#pragma unroll
      for (int j = 0; j < 8; ++j) {
        const float r = (j < 4) ? r0[j & 3] : r1[j & 3];
        av[j] = f2bf(r * scl[icb + j] + shl[icb + j]);
      }
    }
    u16x8 bv[3];
    const size_t bbase = (size_t)(tap * 6 + icc) * (192 * 32);
#pragma unroll
    for (int i = 0; i < 3; ++i) {
      const int e = t + i * 256;
      bv[i] = *(const u16x8*)&bph[bbase + (e >> 2) * 32 + (e & 3) * 8];
    }
    __syncthreads();
    *(u16x8*)&Al[ms * LR + icq * 8] = av;
#pragma unroll
    for (int i = 0; i < 3; ++i) {
      const int e = t + i * 256;
      *(u16x8*)&Bl[(e >> 2) * LR + (e & 3) * 8] = bv[i];
    }
    __syncthreads();
    u16x8 af[4], bf[3];
#pragma unroll
    for (int mf = 0; mf < 4; ++mf)
      af[mf] = *(const u16x8*)&Al[(mf * 16 + row) * LR + g * 8];
#pragma unroll
    for (int nf = 0; nf < 3; ++nf)
      bf[nf] = *(const u16x8*)&Bl[(wv * 48 + nf * 16 + row) * LR + g * 8];
#pragma unroll
    for (int mf = 0; mf < 4; ++mf)
#pragma unroll
      for (int nf = 0; nf < 3; ++nf) acc[mf][nf] = mfma16(af[mf], bf[nf], acc[mf][nf]);
  }
#pragma unroll
  for (int mf = 0; mf < 4; ++mf)
#pragma unroll
    for (int nf = 0; nf < 3; ++nf)
#pragma unroll
      for (int r = 0; r < 4; ++r) {
        const int m = mf * 16 + g * 4 + r;
        const int oy = oyp * 2 + (m >> 5), ox = m & 31;
        const int oc = wv * 48 + nf * 16 + row;
        y2[((n * 32 + oy) * 32 + ox) * 192 + oc] = acc[mf][nf][r] + bl[oc];
      }
}

// ---------------------------------------------------------------------------
// K5 v6: fused ConvT single-bf16, pipelined staging, 4-class row-pair blocks.
// LDS: A (20.8 KB) + B (34.6 KB). 54 MFMA per icc per wave.
// ---------------------------------------------------------------------------
#define AST 40           // px stride in u16 (80 B)
#define ARS (130 * 40)   // per-row plane stride in u16
#define BST 40           // oc stride in u16
__global__ __launch_bounds__(256) void k_convt(const u16* __restrict__ fbh,
                                               const u16* __restrict__ bph,
                                               const float* __restrict__ rgb,
                                               const float* __restrict__ hmb,
                                               u16* __restrict__ rr,
                                               float* __restrict__ hm) {
  __shared__ u16 AH[2 * ARS];       // 20.8 KB
  __shared__ u16 BH[9 * 48 * BST];  // 34.6 KB
  const int t = threadIdx.x;
  // chunked XCD swizzle: adjacent iyb blocks share an input row -> same XCD L2
  const int bid = (blockIdx.x & 7) * 128 + (blockIdx.x >> 3);
  const int n = bid >> 7, iyb = bid & 127;
  const int lane = t & 63, wv = t >> 6;
  const int row = lane & 15, g = lane >> 4;

  // zero the px=128 halo column (staging never rewrites it)
  if (t < 8) {
    const int r = t >> 2, j = t & 3;
    const u16x8 z = {0, 0, 0, 0, 0, 0, 0, 0};
    *(u16x8*)&AH[r * ARS + 128 * AST + j * 8] = z;
  }

  float bias3[3];
#pragma unroll
  for (int nf = 0; nf < 3; ++nf) {
    const int oc = nf * 16 + row;
    bias3[nf] = (oc < 32) ? rgb[oc] : ((oc < 40) ? hmb[oc - 32] : 0.f);
  }

  const int SCt[9] = {0, 1, 1, 2, 2, 3, 3, 3, 3};
  const int SDt[9] = {0, 0, 0, 0, 1, 0, 0, 1, 1};
  const int SXt[9] = {0, 0, 1, 0, 0, 0, 1, 0, 1};

  int rr_[4], px_[4], iq_[4];
#pragma unroll
  for (int i = 0; i < 4; ++i) {
    const int u = t + i * 256;
    rr_[i] = u >> 9;
    px_[i] = (u >> 2) & 127;
    iq_[i] = u & 3;
  }

  const f32x4 z4 = {0.f, 0.f, 0.f, 0.f};
  f32x4 acc[4][2][3];
#pragma unroll
  for (int c = 0; c < 4; ++c)
#pragma unroll
    for (int m = 0; m < 2; ++m)
#pragma unroll
      for (int j = 0; j < 3; ++j) acc[c][m][j] = z4;

#define LOAD_A(ICC, DST)                                                       \
  _Pragma("unroll") for (int i = 0; i < 4; ++i) {                              \
    const int iy = iyb + rr_[i];                                               \
    u16x8 v = {0, 0, 0, 0, 0, 0, 0, 0};                                        \
    if (iy < 128)                                                              \
      v = *(const u16x8*)&fbh[((size_t)((n * 128 + iy) * 128 + px_[i]) << 9) + \
                              (ICC)*32 + iq_[i] * 8];                          \
    DST[i] = v;                                                                \
  }

#define LOAD_B(ICC, DST)                                                       \
  _Pragma("unroll") for (int i = 0; i < 7; ++i) {                              \
    const int e = t + i * 256;                                                 \
    u16x8 v = {0, 0, 0, 0, 0, 0, 0, 0};                                        \
    if (e < 1728) {                                                            \
      const int slot = e / 192, rem = e % 192;                                 \
      const int oc = rem >> 2, icq = rem & 3;                                  \
      v = *(const u16x8*)&bph[((size_t)((slot * 16 + (ICC)) * 48 + oc) << 5) + \
                              icq * 8];                                        \
    }                                                                          \
    DST[i] = v;                                                                \
  }

  u16x8 ahA[4], bhA[7], ahB[4], bhB[7];
  LOAD_A(0, ahA);
  LOAD_B(0, bhA);

  for (int icc = 0; icc < 16; ++icc) {
    __syncthreads();
#pragma unroll
    for (int i = 0; i < 4; ++i)
      *(u16x8*)&AH[rr_[i] * ARS + px_[i] * AST + iq_[i] * 8] = ahA[i];
#pragma unroll
    for (int i = 0; i < 7; ++i) {
      const int e = t + i * 256;
      if (e < 1728) {
        const int slot = e / 192, rem = e % 192;
        const int oc = rem >> 2, icq = rem & 3;
        *(u16x8*)&BH[(slot * 48 + oc) * BST + icq * 8] = bhA[i];
      }
    }
    __syncthreads();

    if (icc < 15) {
      LOAD_A(icc + 1, ahB);
      LOAD_B(icc + 1, bhB);
    }

#pragma unroll
    for (int slot = 0; slot < 9; ++slot) {
      const int cls = SCt[slot], diy = SDt[slot], dix = SXt[slot];
      const u16x8 bf0 = *(const u16x8*)&BH[(slot * 48 + row) * BST + g * 8];
      const u16x8 bf1 = *(const u16x8*)&BH[(slot * 48 + 16 + row) * BST + g * 8];
      const u16x8 bf2 = *(const u16x8*)&BH[(slot * 48 + 32 + row) * BST + g * 8];
#pragma unroll
      for (int mfl = 0; mfl < 2; ++mfl) {
        const int mf = wv * 2 + mfl;
        const u16x8 af =
            *(const u16x8*)&AH[diy * ARS + (mf * 16 + row + dix) * AST + g * 8];
        acc[cls][mfl][0] = mfma16(af, bf0, acc[cls][mfl][0]);
        acc[cls][mfl][1] = mfma16(af, bf1, acc[cls][mfl][1]);
        acc[cls][mfl][2] = mfma16(af, bf2, acc[cls][mfl][2]);
      }
    }

#pragma unroll
    for (int i = 0; i < 4; ++i) ahA[i] = ahB[i];
#pragma unroll
    for (int i = 0; i < 7; ++i) bhA[i] = bhB[i];
  }
#undef LOAD_A
#undef LOAD_B

  // ---- epilogue ----
#pragma unroll
  for (int cls = 0; cls < 4; ++cls) {
    const int oy = 2 * iyb + (cls >> 1);
    const int xp = cls & 1;
#pragma unroll
    for (int mfl = 0; mfl < 2; ++mfl)
#pragma unroll
      for (int nf = 0; nf < 3; ++nf)
#pragma unroll
        for (int r = 0; r < 4; ++r) {
          const int m = (wv * 2 + mfl) * 16 + g * 4 + r;
          const int ox = 2 * m + xp;
          const int oc = nf * 16 + row;
          const float v = acc[cls][mfl][nf][r] + bias3[nf];
          if (oc < 32)
            rr[((size_t)((n * 256 + oy) * 256 + ox)) * 32 + oc] = f2bf(v);
          else if (oc < 40)
            hm[(size_t)(n * 8 + (oc - 32)) * 65536 + oy * 256 + ox] = v;
        }
  }
}

// ---------------------------------------------------------------------------
// Generic per-channel sum/sumsq over [M][C] (C = CG*32)
// ---------------------------------------------------------------------------
template <int CG, bool BF16>
__global__ __launch_bounds__(256) void k_stats(const void* __restrict__ in_, int M,
                                               int PB, float* __restrict__ gsum,
                                               float* __restrict__ gsq) {
  const int C = CG * 32;
  __shared__ float red[8][CG * 32];
  const int t = threadIdx.x;
  const int pg = t >> 5, ln = t & 31;
  float s[CG], q[CG];
#pragma unroll
  for (int c = 0; c < CG; ++c) { s[c] = 0.f; q[c] = 0.f; }
  const int p0 = blockIdx.x * PB;
  const int pend = min(p0 + PB, M);
  for (int p = p0 + pg; p < pend; p += 8) {
#pragma unroll
    for (int c = 0; c < CG; ++c) {
      float v;
      if (BF16)
        v = bf2f(((const u16*)in_)[(size_t)p * C + c * 32 + ln]);
      else
        v = ((const float*)in_)[(size_t)p * C + c * 32 + ln];
      s[c] += v;
      q[c] += v * v;
    }
  }
#pragma unroll
  for (int c = 0; c < CG; ++c) red[pg][c * 32 + ln] = s[c];
  __syncthreads();
  if (t < C) {
    float tot = 0.f;
#pragma unroll
    for (int k = 0; k < 8; ++k) tot += red[k][t];
    atomicAdd(&gsum[t], tot);
  }
  __syncthreads();
#pragma unroll
  for (int c = 0; c < CG; ++c) red[pg][c * 32 + ln] = q[c];
  __syncthreads();
  if (t < C) {
    float tot = 0.f;
#pragma unroll
    for (int k = 0; k < 8; ++k) tot += red[k][t];
    atomicAdd(&gsq[t], tot);
  }
}

__global__ void k_bnfin(const float* __restrict__ gsum, const float* __restrict__ gsq,
                        const float* __restrict__ g, const float* __restrict__ be,
                        float invM, int C, float* __restrict__ sc,
                        float* __restrict__ sh) {
  const int t = threadIdx.x;
  if (t < C) {
    const float m = gsum[t] * invM;
    const float var = gsq[t] * invM - m * m;
    const float inv = rsqrtf(var + 1e-5f);
    const float s = g[t] * inv;
    sc[t] = s;
    sh[t] = be[t] - m * s;
  }
}

// ---------------------------------------------------------------------------
// K3: conv3 1x1 192->32 on bn(y2 fp32). y3 fp32 [8192][32].
// ---------------------------------------------------------------------------
__global__ __launch_bounds__(256) void k_conv3(const float* __restrict__ y2,
                                               const float* __restrict__ w3,
                                               const float* __restrict__ b3,
                                               const float* __restrict__ sc,
                                               const float* __restrict__ sh,
                                               float* __restrict__ y3) {
  __shared__ float wl[32 * 192];
  __shared__ float scl[192], shl[192];
  const int t = threadIdx.x;
  for (int e = t; e < 6144; e += 256) wl[e] = w3[e];
  if (t < 192) {
    scl[t] = sc[t];
    shl[t] = sh[t];
  }
  __syncthreads();
  const int px = blockIdx.x * 256 + t;
  float acc[32];
#pragma unroll
  for (int oc = 0; oc < 32; ++oc) acc[oc] = 0.f;
  const float* base = &y2[(size_t)px * 192];
  for (int icb = 0; icb < 192; icb += 8) {
    const f32x4 r0 = *(const f32x4*)&base[icb];
    const f32x4 r1 = *(const f32x4*)&base[icb + 4];
    float v[8];
#pragma unroll
    for (int j = 0; j < 8; ++j) {
      const float r = (j < 4) ? r0[j & 3] : r1[j & 3];
      v[j] = r * scl[icb + j] + shl[icb + j];
    }
#pragma unroll
    for (int oc = 0; oc < 32; ++oc) {
      const f32x4 w0 = *(const f32x4*)&wl[oc * 192 + icb];
      const f32x4 w1 = *(const f32x4*)&wl[oc * 192 + icb + 4];
      acc[oc] += v[0] * w0[0] + v[1] * w0[1] + v[2] * w0[2] + v[3] * w0[3] +
                 v[4] * w1[0] + v[5] * w1[1] + v[6] * w1[2] + v[7] * w1[3];
    }
  }
#pragma unroll
  for (int oc = 0; oc < 32; ++oc) y3[(size_t)px * 32 + oc] = acc[oc] + b3[oc];
}

// ---------------------------------------------------------------------------
// K4: classify conv 3x3 p1, 32->32 on hsw(bn2(y3))
// ---------------------------------------------------------------------------
__global__ __launch_bounds__(256) void k_clsconv1(const float* __restrict__ y3,
                                                  const float* __restrict__ w1,
                                                  const float* __restrict__ b1,
                                                  const float* __restrict__ sc,
                                                  const float* __restrict__ sh,
                                                  float* __restrict__ c1) {
  __shared__ float wl[9216];  // [ic][tap][oc]
  __shared__ float scl[32], shl[32];
  const int t = threadIdx.x;
  for (int e = t; e < 9216; e += 256) {
    const int oc = e & 31;
    const int tmp = e >> 5;
    const int tap = tmp % 9, ic = tmp / 9;
    wl[e] = w1[(oc * 32 + ic) * 9 + tap];
  }
  if (t < 32) {
    scl[t] = sc[t];
    shl[t] = sh[t];
  }
  __syncthreads();
  const int px = blockIdx.x * 64 + (t & 63);
  const int ocg = t >> 6;
  const int n = px >> 10, y0 = (px >> 5) & 31, x0 = px & 31;
  float acc[8];
#pragma unroll
  for (int j = 0; j < 8; ++j) acc[j] = 0.f;
  for (int tap = 0; tap < 9; ++tap) {
    const int dy = tap / 3 - 1, dx = tap % 3 - 1;
    const int yy = y0 + dy, xx = x0 + dx;
    if ((unsigned)yy < 32u && (unsigned)xx < 32u) {
      const float* ib = &y3[((n << 10) + yy * 32 + xx) * 32];
      for (int ic = 0; ic < 32; ++ic) {
        const float v = hsw(ib[ic] * scl[ic] + shl[ic]);
        const float* wp = &wl[(ic * 9 + tap) * 32 + ocg * 8];
#pragma unroll
        for (int j = 0; j < 8; ++j) acc[j] += v * wp[j];
      }
    }
  }
#pragma unroll
  for (int j = 0; j < 8; ++j) c1[px * 32 + ocg * 8 + j] = acc[j] + b1[ocg * 8 + j];
}

// ---------------------------------------------------------------------------
// K4c: c2 = conv3x3(hsw(bn(c1))) 32->1, then cls[n,k] = c2 . dw[k] + db[k]
// ---------------------------------------------------------------------------
__global__ __launch_bounds__(256) void k_cls(const float* __restrict__ c1,
                                             const float* __restrict__ w2,
                                             const float* __restrict__ b2,
                                             const float* __restrict__ dw,
                                             const float* __restrict__ db,
                                             const float* __restrict__ sc,
                                             const float* __restrict__ sh,
                                             float* __restrict__ cls) {
  __shared__ float wl[288];
  __shared__ float scl[32], shl[32];
  __shared__ float red0[256], red1[256];
  const int t = threadIdx.x;
  const int n = blockIdx.x;
  for (int e = t; e < 288; e += 256) wl[e] = w2[e];
  if (t < 32) {
    scl[t] = sc[t];
    shl[t] = sh[t];
  }
  __syncthreads();
  float s0 = 0.f, s1 = 0.f;
  for (int i = 0; i < 4; ++i) {
    const int px = i * 256 + t;
    const int y0 = px >> 5, x0 = px & 31;
    float c2 = b2[0];
    for (int tap = 0; tap < 9; ++tap) {
      const int dy = tap / 3 - 1, dx = tap % 3 - 1;
      const int yy = y0 + dy, xx = x0 + dx;
      if ((unsigned)yy < 32u && (unsigned)xx < 32u) {
        const float* ib = &c1[((n << 10) + yy * 32 + xx) * 32];
        for (int ic = 0; ic < 32; ++ic)
          c2 += hsw(ib[ic] * scl[ic] + shl[ic]) * wl[ic * 9 + tap];
      }
    }
    s0 += c2 * dw[px];
    s1 += c2 * dw[1024 + px];
  }
  red0[t] = s0;
  red1[t] = s1;
  __syncthreads();
  for (int s = 128; s; s >>= 1) {
    if (t < s) {
      red0[t] += red0[t + s];
      red1[t] += red1[t + s];
    }
    __syncthreads();
  }
  if (t == 0) {
    cls[n * 2 + 0] = red0[0] + db[0];
    cls[n * 2 + 1] = red1[0] + db[1];
  }
}

// ---------------------------------------------------------------------------
// K6: reg = conv3x3 p1 (hsw(bn(rr))) 32->2, fp32 NCHW [8,2,256,256]
// ---------------------------------------------------------------------------
__global__ __launch_bounds__(256) void k_regconv(const u16* __restrict__ rr,
                                                 const float* __restrict__ w,
                                                 const float* __restrict__ b,
                                                 const float* __restrict__ sc,
                                                 const float* __restrict__ sh,
                                                 float* __restrict__ reg) {
  __shared__ u16 rl[3 * 258 * 33];
  __shared__ float wl[576];
  __shared__ float scl[32], shl[32];
  const int t = threadIdx.x;
  const int n = blockIdx.x >> 8, oy = blockIdx.x & 255;
  for (int e = t; e < 576; e += 256) wl[e] = w[e];
  if (t < 32) {
    scl[t] = sc[t];
    shl[t] = sh[t];
  }
  if (t < 192) {
    const int ry = t / 64, side = (t >> 5) & 1, ic = t & 31;
    rl[(ry * 258 + side * 257) * 33 + ic] = 0;
  }
  __syncthreads();
  for (int e = t; e < 3072; e += 256) {
    const int icq8 = e & 3;
    const int pxx = (e >> 2) & 255;
    const int ry = e >> 10;
    const int rowi = oy - 1 + ry;
    u16x8 raw = {0, 0, 0, 0, 0, 0, 0, 0};
    bool ok = (unsigned)rowi < 256u;
    if (ok)
      raw = *(const u16x8*)&rr[((size_t)((n * 256 + rowi) * 256 + pxx)) * 32 + icq8 * 8];
#pragma unroll
    for (int j = 0; j < 8; ++j) {
      const int ic = icq8 * 8 + j;
      float v = 0.f;
      if (ok) v = hsw(bf2f(raw[j]) * scl[ic] + shl[ic]);
      rl[(ry * 258 + pxx + 1) * 33 + ic] = f2bf(v);
    }
  }
  __syncthreads();
  const int px = t;
  float a0 = b[0], a1 = b[1];
#pragma unroll
  for (int ry = 0; ry < 3; ++ry)
#pragma unroll
    for (int kx = 0; kx < 3; ++kx) {
      const u16* ib = &rl[(ry * 258 + px + kx) * 33];
      for (int ic = 0; ic < 32; ++ic) {
        const float v = bf2f(ib[ic]);
        a0 += v * wl[ic * 9 + ry * 3 + kx];
        a1 += v * wl[288 + ic * 9 + ry * 3 + kx];
      }
    }
  reg[(n * 2 + 0) * 65536 + oy * 256 + px] = a0;
  reg[(n * 2 + 1) * 65536 + oy * 256 + px] = a1;
}

// ---------------------------------------------------------------------------
// K7: per (n, ch) spatial argmax, lowest-index tie-break
// ---------------------------------------------------------------------------
__global__ __launch_bounds__(256) void k_argmax(const float* __restrict__ hm,
                                                int* __restrict__ idx) {
  __shared__ float bv[256];
  __shared__ int bi[256];
  const int t = threadIdx.x;
  const float* base = &hm[(size_t)blockIdx.x * 65536];
  float best = -3.402823466e38f;
  int bidx = 2147483647;
  for (int i = t; i < 65536; i += 256) {
    const float v = base[i];
    if (v > best) {
      best = v;
      bidx = i;
    }
  }
  bv[t] = best;
  bi[t] = bidx;
  __syncthreads();
  for (int s = 128; s; s >>= 1) {
    if (t < s) {
      if (bv[t + s] > bv[t] || (bv[t + s] == bv[t] && bi[t + s] < bi[t])) {
        bv[t] = bv[t + s];
        bi[t] = bi[t + s];
      }
    }
    __syncthreads();
  }
  if (t == 0) idx[blockIdx.x] = bi[0];
}

// ---------------------------------------------------------------------------
// K8: decode -> out [8,2,9]
// ---------------------------------------------------------------------------
__global__ void k_final(const float* __restrict__ cls, const int* __restrict__ idx,
                        const float* __restrict__ reg, float* __restrict__ out) {
  const int t = threadIdx.x;
  if (t >= 16) return;
  const int n = t >> 1, p = t & 1;
  const float cv = cls[n * 2 + p];
  float* o = &out[(n * 2 + p) * 9];
  if (!(cv > 0.6f)) {
    for (int i = 0; i < 9; ++i) o[i] = -1.f;
    return;
  }
  o[0] = (float)p;
  for (int c = 0; c < 4; ++c) {
    const int id = idx[n * 8 + p * 4 + c];
    const int yi = id >> 8, xi = id & 255;
    const float ox_ = reg[(n * 2 + 0) * 65536 + id];
    const float oy_ = reg[(n * 2 + 1) * 65536 + id];
    o[1 + c] = fminf(fmaxf((ox_ + (float)xi) * (1.f / 256.f), 0.f), 1.f);
    o[5 + c] = fminf(fmaxf((oy_ + (float)yi) * (1.f / 256.f), 0.f), 1.f);
  }
}

// ---------------------------------------------------------------------------
extern "C" void kernel_launch(void* const* d_in, const int* in_sizes, int n_in,
                              void* d_out, int out_size, void* d_ws, size_t ws_size,
                              hipStream_t stream) {
  const float* feature = (const float*)d_in[0];
  const float* ch_w1 = (const float*)d_in[1];
  const float* ch_b1 = (const float*)d_in[2];
  const float* ch_w2 = (const float*)d_in[3];
  const float* ch_b2 = (const float*)d_in[4];
  const float* ch_w3 = (const float*)d_in[5];
  const float* ch_b3 = (const float*)d_in[6];
  const float* ch_g1 = (const float*)d_in[7];
  const float* ch_be1 = (const float*)d_in[8];
  const float* ch_g2 = (const float*)d_in[9];
  const float* ch_be2 = (const float*)d_in[10];
  const float* cl_w1 = (const float*)d_in[11];
  const float* cl_b1 = (const float*)d_in[12];
  const float* cl_w2 = (const float*)d_in[13];
  const float* cl_b2 = (const float*)d_in[14];
  const float* cl_g = (const float*)d_in[15];
  const float* cl_be = (const float*)d_in[16];
  const float* cl_dw = (const float*)d_in[17];
  const float* cl_db = (const float*)d_in[18];
  const float* rg_tw = (const float*)d_in[19];
  const float* rg_tb = (const float*)d_in[20];
  const float* rg_g = (const float*)d_in[21];
  const float* rg_be = (const float*)d_in[22];
  const float* rg_w = (const float*)d_in[23];
  const float* rg_b = (const float*)d_in[24];
  const float* hm_tw = (const float*)d_in[25];
  const float* hm_tb = (const float*)d_in[26];
  float* out = (float*)d_out;

  char* w = (char*)d_ws;
  const size_t OFF_FB = 0;                  // 134217728
  const size_t OFF_BP1 = 134217728;         // 1769472
  const size_t OFF_BP2 = 135987200;         // 663552
  const size_t OFF_BP5 = 136650752;         // 442368
  const size_t OFF_Y1 = 137093120;          // 25165824 (fp32)
  const size_t OFF_Y2 = 162258944;          // 6291456  (fp32)
  const size_t OFF_Y3 = 168550400;          // 1048576
  const size_t OFF_C1 = 169598976;          // 1048576
  const size_t OFF_RR = 170647552;          // 33554432
  const size_t OFF_HM = 204201984;          // 16777216
  const size_t OFF_REG = 220979200;         // 4194304
  const size_t OFF_STATS = 225173504;       // 3840
  const size_t OFF_PARAMS = 225177344;      // 3840
  const size_t OFF_CLS = 225181184;         // 64
  const size_t OFF_IDX = 225181248;         // 256
  const size_t WS_NEED = 225181504;
  if (ws_size < WS_NEED) return;

  u16* FB = (u16*)(w + OFF_FB);
  u16* BP1 = (u16*)(w + OFF_BP1);
  u16* BP2 = (u16*)(w + OFF_BP2);
  u16* BP5 = (u16*)(w + OFF_BP5);
  float* Y1 = (float*)(w + OFF_Y1);
  float* Y2 = (float*)(w + OFF_Y2);
  float* Y3 = (float*)(w + OFF_Y3);
  float* C1 = (float*)(w + OFF_C1);
  u16* RR = (u16*)(w + OFF_RR);
  float* HM = (float*)(w + OFF_HM);
  float* REG = (float*)(w + OFF_REG);
  float* GSUM = (float*)(w + OFF_STATS);
  float* GSQ = GSUM + 480;
  float* SC = (float*)(w + OFF_PARAMS);
  float* SH = SC + 480;
  float* CLS = (float*)(w + OFF_CLS);
  int* IDX = (int*)(w + OFF_IDX);

  (void)hipMemsetAsync(w + OFF_STATS, 0, 3840, stream);

  k_tobf<<<16384, 256, 0, stream>>>(feature, FB);
  k_pack1<<<3456, 256, 0, stream>>>(ch_w1, BP1);
  k_pack2<<<1296, 256, 0, stream>>>(ch_w2, BP2);
  k_pack5<<<864, 256, 0, stream>>>(rg_tw, hm_tw, BP5);

  // CommonHead
  k_conv1<<<512, 256, 0, stream>>>(FB, BP1, ch_b1, Y1);
  k_stats<6, false><<<128, 256, 0, stream>>>(Y1, 32768, 256, GSUM + 0, GSQ + 0);
  k_bnfin<<<1, 256, 0, stream>>>(GSUM + 0, GSQ + 0, ch_g1, ch_be1, 1.f / 32768.f, 192,
                                 SC + 0, SH + 0);
  k_conv2<<<128, 256, 0, stream>>>(Y1, BP2, ch_b2, SC + 0, SH + 0, Y2);
  k_stats<6, false><<<32, 256, 0, stream>>>(Y2, 8192, 256, GSUM + 192, GSQ + 192);
  k_bnfin<<<1, 256, 0, stream>>>(GSUM + 192, GSQ + 192, ch_g1, ch_be1, 1.f / 8192.f,
                                 192, SC + 192, SH + 192);
  k_conv3<<<32, 256, 0, stream>>>(Y2, ch_w3, ch_b3, SC + 192, SH + 192, Y3);
  k_stats<1, false><<<8, 256, 0, stream>>>(Y3, 8192, 1024, GSUM + 384, GSQ + 384);
  k_bnfin<<<1, 256, 0, stream>>>(GSUM + 384, GSQ + 384, ch_g2, ch_be2, 1.f / 8192.f,
                                 32, SC + 384, SH + 384);
  // Classify head
  k_clsconv1<<<128, 256, 0, stream>>>(Y3, cl_w1, cl_b1, SC + 384, SH + 384, C1);
  k_stats<1, false><<<8, 256, 0, stream>>>(C1, 8192, 1024, GSUM + 416, GSQ + 416);
  k_bnfin<<<1, 256, 0, stream>>>(GSUM + 416, GSQ + 416, cl_g, cl_be, 1.f / 8192.f, 32,
                                 SC + 416, SH + 416);
  k_cls<<<8, 256, 0, stream>>>(C1, cl_w2, cl_b2, cl_dw, cl_db, SC + 416, SH + 416,
                               CLS);
  // Regression + heatmap (fused convT v6: single-bf16, pipelined)
  k_convt<<<1024, 256, 0, stream>>>(FB, BP5, rg_tb, hm_tb, RR, HM);
  k_stats<1, true><<<256, 256, 0, stream>>>(RR, 524288, 2048, GSUM + 448, GSQ + 448);
  k_bnfin<<<1, 256, 0, stream>>>(GSUM + 448, GSQ + 448, rg_g, rg_be, 1.f / 524288.f,
                                 32, SC + 448, SH + 448);
  k_regconv<<<2048, 256, 0, stream>>>(RR, rg_w, rg_b, SC + 448, SH + 448, REG);
  // Decode
  k_argmax<<<64, 256, 0, stream>>>(HM, IDX);
  k_final<<<1, 64, 0, stream>>>(CLS, IDX, REG, out);
}